// Round 2
// baseline (254.945 us; speedup 1.0000x reference)
//
#include <hip/hip_runtime.h>
#include <math.h>

#define NN 65536
#define NE 1048576
#define KH 48
#define G3 144
#define DEGB 512

#define CAP_L1 8192
#define CAP_S1 4096
#define CAP_E2 65536
#define CAP_S2 8192

// ws byte offsets. First 524352 bytes (mark1|mark2|cnt) are zeroed by one
// hipMemsetAsync in kernel_launch.
#define OFF_MARK1  0u        // NN i32
#define OFF_MARK2  262144u   // NN i32
#define OFF_CNT    524288u   // 16 u32: [0]=cntL1 [1]=cntS1 [2]=cntE2 [3]=cntS2
#define OFF_L1R    524352u   // CAP_L1 i32
#define OFF_L1W    557120u   // CAP_L1 f32
#define OFF_S1G    589888u   // CAP_S1 i32 (S1 index -> global node id)
#define OFF_E2R    606272u   // CAP_E2 i32
#define OFF_E2S    868416u   // CAP_E2 i32
#define OFF_E2W    1130560u  // CAP_E2 f32 (raw weight; norm computed inline)
#define OFF_S2     1392704u  // CAP_S2 i32
#define OFF_DEG2   1425472u  // CAP_S2 f32 (compact degree, init 1.0)
#define OFF_STATE  1458240u  // CAP_S2*48 f32
#define OFF_X1     3031104u  // CAP_S1*48 f32
#define OFF_TPSF   3817536u  // 128 f32: [0..47]=target_past, [64..111]=state_fut

typedef _Float16 h2_t __attribute__((ext_vector_type(2)));

union u_h2 { unsigned u; h2_t h; };

__device__ __forceinline__ float sigmf(float x) { return 1.0f / (1.0f + expf(-x)); }

#if __has_builtin(__builtin_amdgcn_fdot2)
__device__ __forceinline__ float fdot2f(h2_t a, h2_t b, float c) {
    return __builtin_amdgcn_fdot2(a, b, c, false);
}
#else
__device__ __forceinline__ float fdot2f(h2_t a, h2_t b, float c) {
    return c + (float)a.x * (float)b.x + (float)a.y * (float)b.y;
}
#endif

// ---------------- K1: find edges into node 0 (4 edges/thread) --------------
__global__ void k_edges1(const int* ei, const float* ew,
                         int* mark1, unsigned* cnt, int* l1r, float* l1w) {
    int q = blockIdx.x * blockDim.x + threadIdx.x;
    if (q >= NE / 4) return;
    if (q == 0) mark1[0] = 1;   // node 0 always in S1
    int4 c4 = reinterpret_cast<const int4*>(ei + NE)[q];
    int e = q * 4;
    int cc[4] = {c4.x, c4.y, c4.z, c4.w};
#pragma unroll
    for (int j = 0; j < 4; ++j) {
        if (cc[j] == 0) {
            int r = ei[e + j];
            float w = ew[e + j];
            unsigned s = atomicAdd(&cnt[0], 1u);
            if (s < CAP_L1) { l1r[s] = r; l1w[s] = w; }
            mark1[r] = 1;
        }
    }
}

// ---------------- K2: compact S1; emit self-loop E2 entries; init x1 -------
__global__ void k_compact1(int* mark1, int* mark2, unsigned* cnt,
                           int* e2r, int* e2s, float* e2w, int* s1g,
                           float* x1, const float* g1b) {
    int i = blockIdx.x * blockDim.x + threadIdx.x;
    if (i >= NN) return;
    if (mark1[i]) {
        unsigned s = atomicAdd(&cnt[1], 1u);
        if (s < CAP_S1) {
            mark1[i] = (int)s + 1;
            mark2[i] = 1;               // needs GRU state (self loop row)
            s1g[s] = i;
            unsigned t = atomicAdd(&cnt[2], 1u);
            if (t < CAP_E2) { e2r[t] = i; e2s[t] = (int)s; e2w[t] = 1.0f; }
            for (int k = 0; k < KH; ++k) x1[s * KH + k] = g1b[k];
        } else {
            mark1[i] = 0;
        }
    }
}

// ---------------- K3: collect edges into S1 (4 edges/thread) ---------------
__global__ void k_edges2(const int* ei, const float* ew,
                         const int* mark1, int* mark2, unsigned* cnt,
                         int* e2r, int* e2s, float* e2w) {
    int q = blockIdx.x * blockDim.x + threadIdx.x;
    if (q >= NE / 4) return;
    int4 c4 = reinterpret_cast<const int4*>(ei + NE)[q];
    int e = q * 4;
    int cc[4] = {c4.x, c4.y, c4.z, c4.w};
#pragma unroll
    for (int j = 0; j < 4; ++j) {
        int m = mark1[cc[j]];
        if (m > 0) {
            int r = ei[e + j];
            float w = ew[e + j];
            unsigned s = atomicAdd(&cnt[2], 1u);
            if (s < CAP_E2) { e2r[s] = r; e2s[s] = m - 1; e2w[s] = w; }
            mark2[r] = 1;
        }
    }
}

// ---------------- K4: compact S2; init compact degree ----------------------
__global__ void k_compact2(int* mark2, unsigned* cnt, int* s2, float* deg2) {
    int i = blockIdx.x * blockDim.x + threadIdx.x;
    if (i >= NN) return;
    if (mark2[i]) {
        unsigned s = atomicAdd(&cnt[3], 1u);
        if (s < CAP_S2) { s2[s] = i; mark2[i] = (int)s + 1; deg2[s] = 1.0f; }
        else mark2[i] = 0;
    }
}

// ---------------- conv1d(pad=1,k=3) + GRU over one sequence ----------------
__device__ void gru_seq(const float* xseq, int T,
                        const float* cw, const float* cb,
                        const float* Wih, const float* Whh,
                        const float* bih, const float* bhh,
                        float* out48,
                        float* s_x, float* s_embed, float* s_giA,
                        float* s_h, float* s_gh) {
    int t = threadIdx.x;
    int nt = blockDim.x;
    for (int i = t; i < T * 2; i += nt) s_x[i] = xseq[i];
    __syncthreads();
    for (int idx = t; idx < T * KH; idx += nt) {
        int tt = idx / KH;
        int k = idx - tt * KH;
        float acc = cb[k];
#pragma unroll
        for (int d = 0; d < 3; ++d) {
            int tau = tt + d - 1;
            if (tau >= 0 && tau < T) {
                acc += cw[k * 6 + d] * s_x[tau * 2 + 0];
                acc += cw[k * 6 + 3 + d] * s_x[tau * 2 + 1];
            }
        }
        s_embed[tt * KH + k] = fmaxf(acc, 0.0f);
    }
    __syncthreads();
    // gi = Wih@embed + bih for all steps (parallel; not recurrent)
    for (int idx = t; idx < T * G3; idx += nt) {
        int step = idx / G3;
        int row = idx - step * G3;
        const float4* wp = reinterpret_cast<const float4*>(Wih + row * KH);
        const float4* em = reinterpret_cast<const float4*>(s_embed + step * KH);
        float g = bih[row];
#pragma unroll
        for (int j = 0; j < 12; ++j) {
            float4 w4 = wp[j]; float4 e4 = em[j];
            g += w4.x * e4.x + w4.y * e4.y + w4.z * e4.z + w4.w * e4.w;
        }
        s_giA[idx] = g;
    }
    float4 wh[12];
    float bh = 0.0f;
    if (t < G3) {
        const float4* q = reinterpret_cast<const float4*>(Whh + t * KH);
#pragma unroll
        for (int j = 0; j < 12; ++j) wh[j] = q[j];
        bh = bhh[t];
    }
    if (t < KH) s_h[t] = 0.0f;
    __syncthreads();
    for (int step = 0; step < T; ++step) {
        if (t < G3) {
            const float4* hp = reinterpret_cast<const float4*>(s_h);
            float g = bh;
#pragma unroll
            for (int j = 0; j < 12; ++j) {
                float4 h4 = hp[j];
                g += wh[j].x * h4.x + wh[j].y * h4.y + wh[j].z * h4.z + wh[j].w * h4.w;
            }
            s_gh[t] = g;
        }
        __syncthreads();
        if (t < KH) {
            const float* gi = s_giA + step * G3;
            float r = sigmf(gi[t] + s_gh[t]);
            float z = sigmf(gi[KH + t] + s_gh[KH + t]);
            float n = tanhf(gi[2 * KH + t] + r * s_gh[2 * KH + t]);
            s_h[t] = (1.0f - z) * n + z * s_h[t];
        }
        __syncthreads();
    }
    if (t < KH) out48[t] = s_h[t];
}

// ---------------- K5: deg scan + all GRUs (fused; independent outputs) -----
__global__ __launch_bounds__(192, 2) void k_gru(
    const float* x, const float* cpw, const float* cpb,
    const float* epWih, const float* epWhh, const float* epbih, const float* epbhh,
    const float* cfw, const float* cfb,
    const float* efWih, const float* efWhh, const float* efbih, const float* efbhh,
    const float* past, const float* future,
    const int* ei, const float* ew, const int* mark2, float* deg2,
    const int* s2, const unsigned* cnt, float* state, float* tpsf) {
    if (blockIdx.x < DEGB) {
        // degree accumulation for S2 nodes only (~5K atomics total)
        int per = NE / DEGB;
        int lo = blockIdx.x * per;
        for (int e = lo + threadIdx.x; e < lo + per; e += blockDim.x) {
            int c = ei[NE + e];
            int m = mark2[c];
            if (m > 0) atomicAdd(&deg2[m - 1], ew[e]);
        }
        return;
    }
    __shared__ __align__(16) float s_x[80];
    __shared__ __align__(16) float s_embed[40 * KH];
    __shared__ __align__(16) float s_giA[40 * G3];
    __shared__ __align__(16) float s_h[KH];
    __shared__ float s_gh[G3];
    if (blockIdx.x == DEGB) {
        gru_seq(past, 20, cpw, cpb, epWih, epWhh, epbih, epbhh,
                tpsf, s_x, s_embed, s_giA, s_h, s_gh);
        return;
    }
    if (blockIdx.x == DEGB + 1) {
        gru_seq(future, 40, cfw, cfb, efWih, efWhh, efbih, efbhh,
                tpsf + 64, s_x, s_embed, s_giA, s_h, s_gh);
        return;
    }
    int b0 = blockIdx.x - (DEGB + 2);
    int nw = gridDim.x - (DEGB + 2);
    int cnt2 = (int)min(cnt[3], (unsigned)CAP_S2);
    for (int b = b0; b < cnt2; b += nw) {
        int node = s2[b];
        gru_seq(x + (size_t)node * 40, 20, cpw, cpb, epWih, epWhh, epbih, epbhh,
                state + (size_t)b * KH, s_x, s_embed, s_giA, s_h, s_gh);
    }
}

// ---------------- K6: GCN layer 1 edge accumulation (norm inline) ----------
__global__ void k_acc1(const unsigned* cnt, const int* e2r, const int* e2s,
                       const float* e2w, const int* mark2, const float* deg2,
                       const int* s1g, const float* state,
                       const float* W1, float* x1) {
    int nE = (int)min(cnt[2], (unsigned)CAP_E2);
    int total = nE * KH;
    int stride = gridDim.x * blockDim.x;
    for (int idx = blockIdx.x * blockDim.x + threadIdx.x; idx < total; idx += stride) {
        int e = idx / KH;
        int k = idx - e * KH;
        int row = e2r[e];
        int s2i = mark2[row] - 1;
        if (s2i < 0) continue;
        int cglob = s1g[e2s[e]];
        int cs2 = mark2[cglob] - 1;
        float norm = e2w[e] * rsqrtf(deg2[s2i] * deg2[cs2]);
        const float* sp = state + (size_t)s2i * KH;
        const float* wp = W1 + k * KH;
        float acc = 0.0f;
#pragma unroll
        for (int m = 0; m < KH; ++m) acc += sp[m] * wp[m];
        atomicAdd(&x1[e2s[e] * KH + k], acc * norm);
    }
}

// ---------------- K7: GCN layer 2 @ node 0 + decoder -----------------------
// R1: fix the R0 spill (VGPR demand 108 wh regs > 128 alloc -> 48KB scratch,
// re-read every iter). Row now split across FOUR threads:
//   threads 0..575 : matvec. thread=(k=t>>2, q=t&3) owns 36 cols [q*36,q*36+36)
//                    of gate rows {k, 144+k, 288+k} as fp16 (54 h2 VGPRs).
//                    h quarter read as 9 ds_read_b64 (uniform addr per q ->
//                    broadcast, conflict-free). Reduce: shfl_xor 1 then 2.
//                    Gates on q==0 lanes; ONE barrier/iter; h in f32 reg.
//   threads 576..639: fc projection of the PREVIOUS step, overlapped via
//                    double-buffered h (readers buf i&1, writers (i&1)^1).
__global__ __launch_bounds__(640, 1) void k_dec(
    const unsigned* cnt, const int* l1r, const float* l1w,
    const int* mark1, const int* mark2, const float* deg2, const float* x1,
    const float* W2, const float* b2, const float* tpsf, const float* past,
    const float* dWih, const float* dWhh, const float* dbih, const float* dbhh,
    const float* fcw, const float* fcb, float* out) {
    __shared__ __align__(16) float s_conc[G3];
    __shared__ __align__(16) _Float16 s_h16[2][G3];   // fp16 h, double-buffered
    __shared__ __align__(16) float s_hf[2][G3];       // f32 h for fc
    int t = threadIdx.x;
    if (t < 48) s_conc[t] = b2[t];
    else if (t < 96) s_conc[t] = tpsf[t - 48];
    else if (t < 144) s_conc[t] = tpsf[64 + t - 96];
    if (t < G3) {
        s_h16[0][t] = (_Float16)0.0f;
        s_hf[0][t] = 0.0f;
    }
    __syncthreads();
    // layer-2 message accumulation into s_conc[0..47]
    int cl1 = (int)min(cnt[0], (unsigned)CAP_L1);
    float dinv0 = rsqrtf(deg2[mark2[0] - 1]);
    int items = (cl1 + 1) * KH;
    for (int idx = t; idx < items; idx += blockDim.x) {
        int e = idx / KH;
        int k = idx - e * KH;
        int row; float norm;
        if (e == cl1) { row = 0; norm = dinv0 * dinv0; }
        else {
            row = l1r[e];
            int rs2 = mark2[row] - 1;
            if (rs2 < 0) continue;
            norm = l1w[e] * rsqrtf(deg2[rs2]) * dinv0;
        }
        int s1 = mark1[row] - 1;
        if (s1 < 0) continue;
        const float* xp = x1 + (size_t)s1 * KH;
        const float* wp = W2 + k * KH;
        float acc = 0.0f;
#pragma unroll
        for (int m = 0; m < KH; ++m) acc += fmaxf(xp[m], 0.0f) * wp[m];
        atomicAdd(&s_conc[k], acc * norm);
    }
    // decoder weight preload: 3 gate rows x quarter-row (36 cols) per thread
    int k = t >> 2, q = t & 3;
    h2_t wh[3][18];
    float bh[3] = {0.0f, 0.0f, 0.0f};
    float bi[3] = {0.0f, 0.0f, 0.0f};
    if (t < 576) {
#pragma unroll
        for (int g = 0; g < 3; ++g) {
            const float4* wp = reinterpret_cast<const float4*>(
                dWhh + (size_t)(g * G3 + k) * G3 + q * 36);
#pragma unroll
            for (int jj = 0; jj < 9; ++jj) {
                float4 f = wp[jj];
                h2_t a, b;
                a.x = (_Float16)f.x; a.y = (_Float16)f.y;
                b.x = (_Float16)f.z; b.y = (_Float16)f.w;
                wh[g][2 * jj] = a; wh[g][2 * jj + 1] = b;
            }
            if (q == 0) {
                bh[g] = dbhh[g * G3 + k];
                bi[g] = dbih[g * G3 + k];
            }
        }
    }
    // fc wave preload (wave 9)
    float fw0[3] = {0, 0, 0}, fw1[3] = {0, 0, 0};
    float fcb0 = 0.0f, fcb1 = 0.0f, pres0 = 0.0f, pres1 = 0.0f;
    if (t >= 576) {
        int lane = t - 576;
#pragma unroll
        for (int j = 0; j < 3; ++j) {
            int m = lane + 64 * j;
            if (m < G3) { fw0[j] = fcw[m]; fw1[j] = fcw[G3 + m]; }
        }
        if (lane == 0) {
            fcb0 = fcb[0]; fcb1 = fcb[1];
            pres0 = past[38]; pres1 = past[39];
        }
    }
    __syncthreads();   // s_conc complete
    // gi at step 0 (steps >=1: input zeros -> gi = bih, kept in bi[] regs)
    float gi0[3] = {0.0f, 0.0f, 0.0f};
    if (t < 576) {
#pragma unroll
        for (int g = 0; g < 3; ++g) {
            const float4* p = reinterpret_cast<const float4*>(
                dWih + (size_t)(g * G3 + k) * G3 + q * 36);
            const float4* cc = reinterpret_cast<const float4*>(s_conc + q * 36);
            float acc = 0.0f;
#pragma unroll
            for (int j = 0; j < 9; ++j) {
                float4 w4 = p[j]; float4 c4 = cc[j];
                acc += w4.x * c4.x + w4.y * c4.y + w4.z * c4.z + w4.w * c4.w;
            }
            acc += __shfl_xor(acc, 1);
            acc += __shfl_xor(acc, 2);
            gi0[g] = acc;
        }
    }
    float hk = 0.0f;   // h[k] carried in f32 (q==0 lanes)
    for (int i = 0; i < 40; ++i) {
        __syncthreads();
        int cur = i & 1, nxt = cur ^ 1;
        if (t < 576) {
            // h quarter as 9 x ds_read_b64 (addr uniform within q-group)
            const uint2* hp = reinterpret_cast<const uint2*>(&s_h16[cur][0]) + q * 9;
            float a0 = bh[0], a1 = bh[1], a2 = bh[2];
#pragma unroll
            for (int j = 0; j < 9; ++j) {
                uint2 uv = hp[j];
                u_h2 lo, hi;
                lo.u = uv.x; hi.u = uv.y;
                a0 = fdot2f(wh[0][2 * j], lo.h, a0);
                a1 = fdot2f(wh[1][2 * j], lo.h, a1);
                a2 = fdot2f(wh[2][2 * j], lo.h, a2);
                a0 = fdot2f(wh[0][2 * j + 1], hi.h, a0);
                a1 = fdot2f(wh[1][2 * j + 1], hi.h, a1);
                a2 = fdot2f(wh[2][2 * j + 1], hi.h, a2);
            }
            a0 += __shfl_xor(a0, 1); a0 += __shfl_xor(a0, 2);
            a1 += __shfl_xor(a1, 1); a1 += __shfl_xor(a1, 2);
            a2 += __shfl_xor(a2, 1); a2 += __shfl_xor(a2, 2);
            if (q == 0) {
                float gr = ((i == 0) ? gi0[0] : 0.0f) + bi[0] + a0;
                float gz = ((i == 0) ? gi0[1] : 0.0f) + bi[1] + a1;
                float gn = ((i == 0) ? gi0[2] : 0.0f) + bi[2];
                float r = sigmf(gr);
                float z = sigmf(gz);
                float n = tanhf(gn + r * a2);
                hk = (1.0f - z) * n + z * hk;
                s_h16[nxt][k] = (_Float16)hk;
                s_hf[nxt][k] = hk;
            }
        } else if (i >= 1) {
            // fc for step i-1 (h_i lives in buffer cur), overlapped w/ matvec
            int lane = t - 576;
            const float* hsrc = s_hf[cur];
            float p0 = 0.0f, p1 = 0.0f;
#pragma unroll
            for (int j = 0; j < 3; ++j) {
                int m = lane + 64 * j;
                if (m < G3) { float h = hsrc[m]; p0 += h * fw0[j]; p1 += h * fw1[j]; }
            }
#pragma unroll
            for (int off = 32; off > 0; off >>= 1) {
                p0 += __shfl_down(p0, off);
                p1 += __shfl_down(p1, off);
            }
            if (lane == 0) {
                pres0 += p0 + fcb0; pres1 += p1 + fcb1;
                out[(i - 1) * 2 + 0] = pres0;
                out[(i - 1) * 2 + 1] = pres1;
            }
        }
    }
    __syncthreads();
    if (t >= 576) {   // final step's fc (h_40 in buffer 0)
        int lane = t - 576;
        const float* hsrc = s_hf[0];
        float p0 = 0.0f, p1 = 0.0f;
#pragma unroll
        for (int j = 0; j < 3; ++j) {
            int m = lane + 64 * j;
            if (m < G3) { float h = hsrc[m]; p0 += h * fw0[j]; p1 += h * fw1[j]; }
        }
#pragma unroll
        for (int off = 32; off > 0; off >>= 1) {
            p0 += __shfl_down(p0, off);
            p1 += __shfl_down(p1, off);
        }
        if (lane == 0) {
            pres0 += p0 + fcb0; pres1 += p1 + fcb1;
            out[39 * 2 + 0] = pres0;
            out[39 * 2 + 1] = pres1;
        }
    }
}

extern "C" void kernel_launch(void* const* d_in, const int* in_sizes, int n_in,
                              void* d_out, int out_size, void* d_ws, size_t ws_size,
                              hipStream_t stream) {
    (void)in_sizes; (void)n_in; (void)out_size; (void)ws_size;
    const float* past   = (const float*)d_in[0];
    const float* future = (const float*)d_in[1];
    const float* x      = (const float*)d_in[2];
    const int*   ei     = (const int*)d_in[3];
    const float* ew     = (const float*)d_in[4];
    const float* cpw    = (const float*)d_in[5];
    const float* cpb    = (const float*)d_in[6];
    const float* cfw    = (const float*)d_in[7];
    const float* cfb    = (const float*)d_in[8];
    const float* epWih  = (const float*)d_in[9];
    const float* epWhh  = (const float*)d_in[10];
    const float* epbih  = (const float*)d_in[11];
    const float* epbhh  = (const float*)d_in[12];
    const float* efWih  = (const float*)d_in[13];
    const float* efWhh  = (const float*)d_in[14];
    const float* efbih  = (const float*)d_in[15];
    const float* efbhh  = (const float*)d_in[16];
    const float* dWih   = (const float*)d_in[17];
    const float* dWhh   = (const float*)d_in[18];
    const float* dbih   = (const float*)d_in[19];
    const float* dbhh   = (const float*)d_in[20];
    const float* fcw    = (const float*)d_in[21];
    const float* fcb    = (const float*)d_in[22];
    const float* g1w    = (const float*)d_in[23];
    const float* g1b    = (const float*)d_in[24];
    const float* g2w    = (const float*)d_in[25];
    const float* g2b    = (const float*)d_in[26];

    char* ws = (char*)d_ws;
    int*      mark1 = (int*)(ws + OFF_MARK1);
    int*      mark2 = (int*)(ws + OFF_MARK2);
    unsigned* cnt   = (unsigned*)(ws + OFF_CNT);
    int*      l1r   = (int*)(ws + OFF_L1R);
    float*    l1w   = (float*)(ws + OFF_L1W);
    int*      s1g   = (int*)(ws + OFF_S1G);
    int*      e2r   = (int*)(ws + OFF_E2R);
    int*      e2s   = (int*)(ws + OFF_E2S);
    float*    e2w   = (float*)(ws + OFF_E2W);
    int*      s2    = (int*)(ws + OFF_S2);
    float*    deg2  = (float*)(ws + OFF_DEG2);
    float*    state = (float*)(ws + OFF_STATE);
    float*    x1    = (float*)(ws + OFF_X1);
    float*    tpsf  = (float*)(ws + OFF_TPSF);

    hipMemsetAsync(ws, 0, 524352, stream);  // mark1 | mark2 | cnt
    k_edges1<<<NE / 4 / 256, 256, 0, stream>>>(ei, ew, mark1, cnt, l1r, l1w);
    k_compact1<<<NN / 256, 256, 0, stream>>>(mark1, mark2, cnt, e2r, e2s, e2w, s1g, x1, g1b);
    k_edges2<<<NE / 4 / 256, 256, 0, stream>>>(ei, ew, mark1, mark2, cnt, e2r, e2s, e2w);
    k_compact2<<<NN / 256, 256, 0, stream>>>(mark2, cnt, s2, deg2);
    k_gru<<<DEGB + 2 + 512, 192, 0, stream>>>(x, cpw, cpb, epWih, epWhh, epbih, epbhh,
                                              cfw, cfb, efWih, efWhh, efbih, efbhh,
                                              past, future, ei, ew, mark2, deg2,
                                              s2, cnt, state, tpsf);
    k_acc1<<<128, 256, 0, stream>>>(cnt, e2r, e2s, e2w, mark2, deg2, s1g, state, g1w, x1);
    k_dec<<<1, 640, 0, stream>>>(cnt, l1r, l1w, mark1, mark2, deg2, x1, g2w, g2b,
                                 tpsf, past, dWih, dWhh, dbih, dbhh, fcw, fcb,
                                 (float*)d_out);
}

// Round 3
// 253.400 us; speedup vs baseline: 1.0061x; 1.0061x over previous
//
#include <hip/hip_runtime.h>
#include <math.h>

#define NN 65536
#define NE 1048576
#define KH 48
#define G3 144
#define DEGB 512

#define CAP_L1 8192
#define CAP_S1 4096
#define CAP_E2 65536
#define CAP_S2 8192

// ws byte offsets. First 524352 bytes (mark1|mark2|cnt) are zeroed by one
// hipMemsetAsync in kernel_launch.
#define OFF_MARK1  0u        // NN i32
#define OFF_MARK2  262144u   // NN i32
#define OFF_CNT    524288u   // 16 u32: [0]=cntL1 [1]=cntS1 [2]=cntE2 [3]=cntS2
#define OFF_L1R    524352u   // CAP_L1 i32
#define OFF_L1W    557120u   // CAP_L1 f32
#define OFF_S1G    589888u   // CAP_S1 i32 (S1 index -> global node id)
#define OFF_E2R    606272u   // CAP_E2 i32
#define OFF_E2S    868416u   // CAP_E2 i32
#define OFF_E2W    1130560u  // CAP_E2 f32 (raw weight; norm computed inline)
#define OFF_S2     1392704u  // CAP_S2 i32
#define OFF_DEG2   1425472u  // CAP_S2 f32 (compact degree, init 1.0)
#define OFF_STATE  1458240u  // CAP_S2*48 f32
#define OFF_X1     3031104u  // CAP_S1*48 f32
#define OFF_TPSF   3817536u  // 128 f32: [0..47]=target_past, [64..111]=state_fut

typedef _Float16 h2_t __attribute__((ext_vector_type(2)));
typedef _Float16 h4_t __attribute__((ext_vector_type(4)));

__device__ __forceinline__ float sigmf(float x) { return 1.0f / (1.0f + expf(-x)); }

#if __has_builtin(__builtin_amdgcn_fdot2)
__device__ __forceinline__ float fdot2f(h2_t a, h2_t b, float c) {
    return __builtin_amdgcn_fdot2(a, b, c, false);
}
#else
__device__ __forceinline__ float fdot2f(h2_t a, h2_t b, float c) {
    return c + (float)a.x * (float)b.x + (float)a.y * (float)b.y;
}
#endif

// ---------------- K1: find edges into node 0 (4 edges/thread) --------------
__global__ void k_edges1(const int* ei, const float* ew,
                         int* mark1, unsigned* cnt, int* l1r, float* l1w) {
    int q = blockIdx.x * blockDim.x + threadIdx.x;
    if (q >= NE / 4) return;
    if (q == 0) mark1[0] = 1;   // node 0 always in S1
    int4 c4 = reinterpret_cast<const int4*>(ei + NE)[q];
    int e = q * 4;
    int cc[4] = {c4.x, c4.y, c4.z, c4.w};
#pragma unroll
    for (int j = 0; j < 4; ++j) {
        if (cc[j] == 0) {
            int r = ei[e + j];
            float w = ew[e + j];
            unsigned s = atomicAdd(&cnt[0], 1u);
            if (s < CAP_L1) { l1r[s] = r; l1w[s] = w; }
            mark1[r] = 1;
        }
    }
}

// ---------------- K2: compact S1; emit self-loop E2 entries; init x1 -------
__global__ void k_compact1(int* mark1, int* mark2, unsigned* cnt,
                           int* e2r, int* e2s, float* e2w, int* s1g,
                           float* x1, const float* g1b) {
    int i = blockIdx.x * blockDim.x + threadIdx.x;
    if (i >= NN) return;
    if (mark1[i]) {
        unsigned s = atomicAdd(&cnt[1], 1u);
        if (s < CAP_S1) {
            mark1[i] = (int)s + 1;
            mark2[i] = 1;               // needs GRU state (self loop row)
            s1g[s] = i;
            unsigned t = atomicAdd(&cnt[2], 1u);
            if (t < CAP_E2) { e2r[t] = i; e2s[t] = (int)s; e2w[t] = 1.0f; }
            for (int k = 0; k < KH; ++k) x1[s * KH + k] = g1b[k];
        } else {
            mark1[i] = 0;
        }
    }
}

// ---------------- K3: collect edges into S1 (4 edges/thread) ---------------
__global__ void k_edges2(const int* ei, const float* ew,
                         const int* mark1, int* mark2, unsigned* cnt,
                         int* e2r, int* e2s, float* e2w) {
    int q = blockIdx.x * blockDim.x + threadIdx.x;
    if (q >= NE / 4) return;
    int4 c4 = reinterpret_cast<const int4*>(ei + NE)[q];
    int e = q * 4;
    int cc[4] = {c4.x, c4.y, c4.z, c4.w};
#pragma unroll
    for (int j = 0; j < 4; ++j) {
        int m = mark1[cc[j]];
        if (m > 0) {
            int r = ei[e + j];
            float w = ew[e + j];
            unsigned s = atomicAdd(&cnt[2], 1u);
            if (s < CAP_E2) { e2r[s] = r; e2s[s] = m - 1; e2w[s] = w; }
            mark2[r] = 1;
        }
    }
}

// ---------------- K4: compact S2; init compact degree ----------------------
__global__ void k_compact2(int* mark2, unsigned* cnt, int* s2, float* deg2) {
    int i = blockIdx.x * blockDim.x + threadIdx.x;
    if (i >= NN) return;
    if (mark2[i]) {
        unsigned s = atomicAdd(&cnt[3], 1u);
        if (s < CAP_S2) { s2[s] = i; mark2[i] = (int)s + 1; deg2[s] = 1.0f; }
        else mark2[i] = 0;
    }
}

// ---------------- conv1d(pad=1,k=3) + GRU over one sequence ----------------
__device__ void gru_seq(const float* xseq, int T,
                        const float* cw, const float* cb,
                        const float* Wih, const float* Whh,
                        const float* bih, const float* bhh,
                        float* out48,
                        float* s_x, float* s_embed, float* s_giA,
                        float* s_h, float* s_gh) {
    int t = threadIdx.x;
    int nt = blockDim.x;
    for (int i = t; i < T * 2; i += nt) s_x[i] = xseq[i];
    __syncthreads();
    for (int idx = t; idx < T * KH; idx += nt) {
        int tt = idx / KH;
        int k = idx - tt * KH;
        float acc = cb[k];
#pragma unroll
        for (int d = 0; d < 3; ++d) {
            int tau = tt + d - 1;
            if (tau >= 0 && tau < T) {
                acc += cw[k * 6 + d] * s_x[tau * 2 + 0];
                acc += cw[k * 6 + 3 + d] * s_x[tau * 2 + 1];
            }
        }
        s_embed[tt * KH + k] = fmaxf(acc, 0.0f);
    }
    __syncthreads();
    // gi = Wih@embed + bih for all steps (parallel; not recurrent)
    for (int idx = t; idx < T * G3; idx += nt) {
        int step = idx / G3;
        int row = idx - step * G3;
        const float4* wp = reinterpret_cast<const float4*>(Wih + row * KH);
        const float4* em = reinterpret_cast<const float4*>(s_embed + step * KH);
        float g = bih[row];
#pragma unroll
        for (int j = 0; j < 12; ++j) {
            float4 w4 = wp[j]; float4 e4 = em[j];
            g += w4.x * e4.x + w4.y * e4.y + w4.z * e4.z + w4.w * e4.w;
        }
        s_giA[idx] = g;
    }
    float4 wh[12];
    float bh = 0.0f;
    if (t < G3) {
        const float4* q = reinterpret_cast<const float4*>(Whh + t * KH);
#pragma unroll
        for (int j = 0; j < 12; ++j) wh[j] = q[j];
        bh = bhh[t];
    }
    if (t < KH) s_h[t] = 0.0f;
    __syncthreads();
    for (int step = 0; step < T; ++step) {
        if (t < G3) {
            const float4* hp = reinterpret_cast<const float4*>(s_h);
            float g = bh;
#pragma unroll
            for (int j = 0; j < 12; ++j) {
                float4 h4 = hp[j];
                g += wh[j].x * h4.x + wh[j].y * h4.y + wh[j].z * h4.z + wh[j].w * h4.w;
            }
            s_gh[t] = g;
        }
        __syncthreads();
        if (t < KH) {
            const float* gi = s_giA + step * G3;
            float r = sigmf(gi[t] + s_gh[t]);
            float z = sigmf(gi[KH + t] + s_gh[KH + t]);
            float n = tanhf(gi[2 * KH + t] + r * s_gh[2 * KH + t]);
            s_h[t] = (1.0f - z) * n + z * s_h[t];
        }
        __syncthreads();
    }
    if (t < KH) out48[t] = s_h[t];
}

// ---------------- K5: deg scan + all GRUs (fused; independent outputs) -----
__global__ __launch_bounds__(192, 2) void k_gru(
    const float* x, const float* cpw, const float* cpb,
    const float* epWih, const float* epWhh, const float* epbih, const float* epbhh,
    const float* cfw, const float* cfb,
    const float* efWih, const float* efWhh, const float* efbih, const float* efbhh,
    const float* past, const float* future,
    const int* ei, const float* ew, const int* mark2, float* deg2,
    const int* s2, const unsigned* cnt, float* state, float* tpsf) {
    if (blockIdx.x < DEGB) {
        // degree accumulation for S2 nodes only (~5K atomics total)
        int per = NE / DEGB;
        int lo = blockIdx.x * per;
        for (int e = lo + threadIdx.x; e < lo + per; e += blockDim.x) {
            int c = ei[NE + e];
            int m = mark2[c];
            if (m > 0) atomicAdd(&deg2[m - 1], ew[e]);
        }
        return;
    }
    __shared__ __align__(16) float s_x[80];
    __shared__ __align__(16) float s_embed[40 * KH];
    __shared__ __align__(16) float s_giA[40 * G3];
    __shared__ __align__(16) float s_h[KH];
    __shared__ float s_gh[G3];
    if (blockIdx.x == DEGB) {
        gru_seq(past, 20, cpw, cpb, epWih, epWhh, epbih, epbhh,
                tpsf, s_x, s_embed, s_giA, s_h, s_gh);
        return;
    }
    if (blockIdx.x == DEGB + 1) {
        gru_seq(future, 40, cfw, cfb, efWih, efWhh, efbih, efbhh,
                tpsf + 64, s_x, s_embed, s_giA, s_h, s_gh);
        return;
    }
    int b0 = blockIdx.x - (DEGB + 2);
    int nw = gridDim.x - (DEGB + 2);
    int cnt2 = (int)min(cnt[3], (unsigned)CAP_S2);
    for (int b = b0; b < cnt2; b += nw) {
        int node = s2[b];
        gru_seq(x + (size_t)node * 40, 20, cpw, cpb, epWih, epWhh, epbih, epbhh,
                state + (size_t)b * KH, s_x, s_embed, s_giA, s_h, s_gh);
    }
}

// ---------------- K6: GCN layer 1 edge accumulation (norm inline) ----------
__global__ void k_acc1(const unsigned* cnt, const int* e2r, const int* e2s,
                       const float* e2w, const int* mark2, const float* deg2,
                       const int* s1g, const float* state,
                       const float* W1, float* x1) {
    int nE = (int)min(cnt[2], (unsigned)CAP_E2);
    int total = nE * KH;
    int stride = gridDim.x * blockDim.x;
    for (int idx = blockIdx.x * blockDim.x + threadIdx.x; idx < total; idx += stride) {
        int e = idx / KH;
        int k = idx - e * KH;
        int row = e2r[e];
        int s2i = mark2[row] - 1;
        if (s2i < 0) continue;
        int cglob = s1g[e2s[e]];
        int cs2 = mark2[cglob] - 1;
        float norm = e2w[e] * rsqrtf(deg2[s2i] * deg2[cs2]);
        const float* sp = state + (size_t)s2i * KH;
        const float* wp = W1 + k * KH;
        float acc = 0.0f;
#pragma unroll
        for (int m = 0; m < KH; ++m) acc += sp[m] * wp[m];
        atomicAdd(&x1[e2s[e] * KH + k], acc * norm);
    }
}

// ---------------- K7: GCN layer 2 @ node 0 + decoder -----------------------
// R2: same (k,q) decomposition as R1 (576 matvec threads, thread=(k=t>>2,
// q=t&3) owns 36 cols of gate rows {k,144+k,288+k} as 54 h2 VGPRs), but ALL
// type-punning unions removed: R0/R1's f_h2/u_h2 unions defeated SROA ->
// stack slots -> per-iter scratch store/load storms (WRITE_SIZE 48-59KB vs
// baseline's 0.3KB). h is now read as h4_t (ds_read_b64) and split into h2
// pairs via __builtin_shufflevector (pure subregister ops, register-safe).
//   threads 576..639: fc projection of the PREVIOUS step, overlapped via
//   double-buffered h (readers buf i&1, writers (i&1)^1).
__global__ __launch_bounds__(640, 1) void k_dec(
    const unsigned* cnt, const int* l1r, const float* l1w,
    const int* mark1, const int* mark2, const float* deg2, const float* x1,
    const float* W2, const float* b2, const float* tpsf, const float* past,
    const float* dWih, const float* dWhh, const float* dbih, const float* dbhh,
    const float* fcw, const float* fcb, float* out) {
    __shared__ __align__(16) float s_conc[G3];
    __shared__ __align__(16) _Float16 s_h16[2][G3];   // fp16 h, double-buffered
    __shared__ __align__(16) float s_hf[2][G3];       // f32 h for fc
    int t = threadIdx.x;
    if (t < 48) s_conc[t] = b2[t];
    else if (t < 96) s_conc[t] = tpsf[t - 48];
    else if (t < 144) s_conc[t] = tpsf[64 + t - 96];
    if (t < G3) {
        s_h16[0][t] = (_Float16)0.0f;
        s_hf[0][t] = 0.0f;
    }
    __syncthreads();
    // layer-2 message accumulation into s_conc[0..47]
    int cl1 = (int)min(cnt[0], (unsigned)CAP_L1);
    float dinv0 = rsqrtf(deg2[mark2[0] - 1]);
    int items = (cl1 + 1) * KH;
    for (int idx = t; idx < items; idx += blockDim.x) {
        int e = idx / KH;
        int k = idx - e * KH;
        int row; float norm;
        if (e == cl1) { row = 0; norm = dinv0 * dinv0; }
        else {
            row = l1r[e];
            int rs2 = mark2[row] - 1;
            if (rs2 < 0) continue;
            norm = l1w[e] * rsqrtf(deg2[rs2]) * dinv0;
        }
        int s1 = mark1[row] - 1;
        if (s1 < 0) continue;
        const float* xp = x1 + (size_t)s1 * KH;
        const float* wp = W2 + k * KH;
        float acc = 0.0f;
#pragma unroll
        for (int m = 0; m < KH; ++m) acc += fmaxf(xp[m], 0.0f) * wp[m];
        atomicAdd(&s_conc[k], acc * norm);
    }
    // decoder weight preload: 3 gate rows x quarter-row (36 cols) per thread.
    // wh flat: wh[g*18 + c], c in [0,18) covering cols [q*36, q*36+36).
    int k = t >> 2, q = t & 3;
    h2_t wh[54];
    float bh[3] = {0.0f, 0.0f, 0.0f};
    float bi[3] = {0.0f, 0.0f, 0.0f};
    if (t < 576) {
#pragma unroll
        for (int g = 0; g < 3; ++g) {
            const float4* wp = reinterpret_cast<const float4*>(
                dWhh + (size_t)(g * G3 + k) * G3 + q * 36);
#pragma unroll
            for (int jj = 0; jj < 9; ++jj) {
                float4 f = wp[jj];
                h2_t a, b;
                a.x = (_Float16)f.x; a.y = (_Float16)f.y;
                b.x = (_Float16)f.z; b.y = (_Float16)f.w;
                wh[g * 18 + 2 * jj] = a; wh[g * 18 + 2 * jj + 1] = b;
            }
            if (q == 0) {
                bh[g] = dbhh[g * G3 + k];
                bi[g] = dbih[g * G3 + k];
            }
        }
    }
    // fc wave preload (wave 9)
    float fw0[3] = {0, 0, 0}, fw1[3] = {0, 0, 0};
    float fcb0 = 0.0f, fcb1 = 0.0f, pres0 = 0.0f, pres1 = 0.0f;
    if (t >= 576) {
        int lane = t - 576;
#pragma unroll
        for (int j = 0; j < 3; ++j) {
            int m = lane + 64 * j;
            if (m < G3) { fw0[j] = fcw[m]; fw1[j] = fcw[G3 + m]; }
        }
        if (lane == 0) {
            fcb0 = fcb[0]; fcb1 = fcb[1];
            pres0 = past[38]; pres1 = past[39];
        }
    }
    __syncthreads();   // s_conc complete
    // gi at step 0 (steps >=1: input zeros -> gi = bih, kept in bi[] regs)
    float gi0[3] = {0.0f, 0.0f, 0.0f};
    if (t < 576) {
#pragma unroll
        for (int g = 0; g < 3; ++g) {
            const float4* p = reinterpret_cast<const float4*>(
                dWih + (size_t)(g * G3 + k) * G3 + q * 36);
            const float4* cc = reinterpret_cast<const float4*>(s_conc + q * 36);
            float acc = 0.0f;
#pragma unroll
            for (int j = 0; j < 9; ++j) {
                float4 w4 = p[j]; float4 c4 = cc[j];
                acc += w4.x * c4.x + w4.y * c4.y + w4.z * c4.z + w4.w * c4.w;
            }
            acc += __shfl_xor(acc, 1);
            acc += __shfl_xor(acc, 2);
            gi0[g] = acc;
        }
    }
    float hk = 0.0f;   // h[k] carried in f32 (q==0 lanes)
    for (int i = 0; i < 40; ++i) {
        __syncthreads();
        int cur = i & 1, nxt = cur ^ 1;
        if (t < 576) {
            // h quarter: 9 x ds_read_b64, split to h2 via shufflevector
            const h4_t* hp = reinterpret_cast<const h4_t*>(&s_h16[cur][0]) + q * 9;
            float a0 = bh[0], a1 = bh[1], a2 = bh[2];
#pragma unroll
            for (int j = 0; j < 9; ++j) {
                h4_t hv = hp[j];
                h2_t lo = __builtin_shufflevector(hv, hv, 0, 1);
                h2_t hi = __builtin_shufflevector(hv, hv, 2, 3);
                a0 = fdot2f(wh[2 * j], lo, a0);
                a1 = fdot2f(wh[18 + 2 * j], lo, a1);
                a2 = fdot2f(wh[36 + 2 * j], lo, a2);
                a0 = fdot2f(wh[2 * j + 1], hi, a0);
                a1 = fdot2f(wh[18 + 2 * j + 1], hi, a1);
                a2 = fdot2f(wh[36 + 2 * j + 1], hi, a2);
            }
            a0 += __shfl_xor(a0, 1); a0 += __shfl_xor(a0, 2);
            a1 += __shfl_xor(a1, 1); a1 += __shfl_xor(a1, 2);
            a2 += __shfl_xor(a2, 1); a2 += __shfl_xor(a2, 2);
            if (q == 0) {
                float gr = ((i == 0) ? gi0[0] : 0.0f) + bi[0] + a0;
                float gz = ((i == 0) ? gi0[1] : 0.0f) + bi[1] + a1;
                float gn = ((i == 0) ? gi0[2] : 0.0f) + bi[2];
                float r = sigmf(gr);
                float z = sigmf(gz);
                float n = tanhf(gn + r * a2);
                hk = (1.0f - z) * n + z * hk;
                s_h16[nxt][k] = (_Float16)hk;
                s_hf[nxt][k] = hk;
            }
        } else if (i >= 1) {
            // fc for step i-1 (h_i lives in buffer cur), overlapped w/ matvec
            int lane = t - 576;
            const float* hsrc = s_hf[cur];
            float p0 = 0.0f, p1 = 0.0f;
#pragma unroll
            for (int j = 0; j < 3; ++j) {
                int m = lane + 64 * j;
                if (m < G3) { float h = hsrc[m]; p0 += h * fw0[j]; p1 += h * fw1[j]; }
            }
#pragma unroll
            for (int off = 32; off > 0; off >>= 1) {
                p0 += __shfl_down(p0, off);
                p1 += __shfl_down(p1, off);
            }
            if (lane == 0) {
                pres0 += p0 + fcb0; pres1 += p1 + fcb1;
                out[(i - 1) * 2 + 0] = pres0;
                out[(i - 1) * 2 + 1] = pres1;
            }
        }
    }
    __syncthreads();
    if (t >= 576) {   // final step's fc (h_40 in buffer 0)
        int lane = t - 576;
        const float* hsrc = s_hf[0];
        float p0 = 0.0f, p1 = 0.0f;
#pragma unroll
        for (int j = 0; j < 3; ++j) {
            int m = lane + 64 * j;
            if (m < G3) { float h = hsrc[m]; p0 += h * fw0[j]; p1 += h * fw1[j]; }
        }
#pragma unroll
        for (int off = 32; off > 0; off >>= 1) {
            p0 += __shfl_down(p0, off);
            p1 += __shfl_down(p1, off);
        }
        if (lane == 0) {
            pres0 += p0 + fcb0; pres1 += p1 + fcb1;
            out[39 * 2 + 0] = pres0;
            out[39 * 2 + 1] = pres1;
        }
    }
}

extern "C" void kernel_launch(void* const* d_in, const int* in_sizes, int n_in,
                              void* d_out, int out_size, void* d_ws, size_t ws_size,
                              hipStream_t stream) {
    (void)in_sizes; (void)n_in; (void)out_size; (void)ws_size;
    const float* past   = (const float*)d_in[0];
    const float* future = (const float*)d_in[1];
    const float* x      = (const float*)d_in[2];
    const int*   ei     = (const int*)d_in[3];
    const float* ew     = (const float*)d_in[4];
    const float* cpw    = (const float*)d_in[5];
    const float* cpb    = (const float*)d_in[6];
    const float* cfw    = (const float*)d_in[7];
    const float* cfb    = (const float*)d_in[8];
    const float* epWih  = (const float*)d_in[9];
    const float* epWhh  = (const float*)d_in[10];
    const float* epbih  = (const float*)d_in[11];
    const float* epbhh  = (const float*)d_in[12];
    const float* efWih  = (const float*)d_in[13];
    const float* efWhh  = (const float*)d_in[14];
    const float* efbih  = (const float*)d_in[15];
    const float* efbhh  = (const float*)d_in[16];
    const float* dWih   = (const float*)d_in[17];
    const float* dWhh   = (const float*)d_in[18];
    const float* dbih   = (const float*)d_in[19];
    const float* dbhh   = (const float*)d_in[20];
    const float* fcw    = (const float*)d_in[21];
    const float* fcb    = (const float*)d_in[22];
    const float* g1w    = (const float*)d_in[23];
    const float* g1b    = (const float*)d_in[24];
    const float* g2w    = (const float*)d_in[25];
    const float* g2b    = (const float*)d_in[26];

    char* ws = (char*)d_ws;
    int*      mark1 = (int*)(ws + OFF_MARK1);
    int*      mark2 = (int*)(ws + OFF_MARK2);
    unsigned* cnt   = (unsigned*)(ws + OFF_CNT);
    int*      l1r   = (int*)(ws + OFF_L1R);
    float*    l1w   = (float*)(ws + OFF_L1W);
    int*      s1g   = (int*)(ws + OFF_S1G);
    int*      e2r   = (int*)(ws + OFF_E2R);
    int*      e2s   = (int*)(ws + OFF_E2S);
    float*    e2w   = (float*)(ws + OFF_E2W);
    int*      s2    = (int*)(ws + OFF_S2);
    float*    deg2  = (float*)(ws + OFF_DEG2);
    float*    state = (float*)(ws + OFF_STATE);
    float*    x1    = (float*)(ws + OFF_X1);
    float*    tpsf  = (float*)(ws + OFF_TPSF);

    hipMemsetAsync(ws, 0, 524352, stream);  // mark1 | mark2 | cnt
    k_edges1<<<NE / 4 / 256, 256, 0, stream>>>(ei, ew, mark1, cnt, l1r, l1w);
    k_compact1<<<NN / 256, 256, 0, stream>>>(mark1, mark2, cnt, e2r, e2s, e2w, s1g, x1, g1b);
    k_edges2<<<NE / 4 / 256, 256, 0, stream>>>(ei, ew, mark1, mark2, cnt, e2r, e2s, e2w);
    k_compact2<<<NN / 256, 256, 0, stream>>>(mark2, cnt, s2, deg2);
    k_gru<<<DEGB + 2 + 512, 192, 0, stream>>>(x, cpw, cpb, epWih, epWhh, epbih, epbhh,
                                              cfw, cfb, efWih, efWhh, efbih, efbhh,
                                              past, future, ei, ew, mark2, deg2,
                                              s2, cnt, state, tpsf);
    k_acc1<<<128, 256, 0, stream>>>(cnt, e2r, e2s, e2w, mark2, deg2, s1g, state, g1w, x1);
    k_dec<<<1, 640, 0, stream>>>(cnt, l1r, l1w, mark1, mark2, deg2, x1, g2w, g2b,
                                 tpsf, past, dWih, dWhh, dbih, dbhh, fcw, fcb,
                                 (float*)d_out);
}

// Round 5
// 244.777 us; speedup vs baseline: 1.0415x; 1.0352x over previous
//
#include <hip/hip_runtime.h>
#include <math.h>

#define NN 65536
#define NE 1048576
#define KH 48
#define G3 144
#define DEGB 512

#define CAP_L1 8192
#define CAP_S1 4096
#define CAP_E2 65536
#define CAP_S2 8192

// ws byte offsets. First 524352 bytes (mark1|mark2|cnt) are zeroed by one
// hipMemsetAsync in kernel_launch.
#define OFF_MARK1  0u        // NN i32
#define OFF_MARK2  262144u   // NN i32
#define OFF_CNT    524288u   // 16 u32: [0]=cntL1 [1]=cntS1 [2]=cntE2 [3]=cntS2
#define OFF_L1R    524352u   // CAP_L1 i32
#define OFF_L1W    557120u   // CAP_L1 f32
#define OFF_S1G    589888u   // CAP_S1 i32 (S1 index -> global node id)
#define OFF_E2R    606272u   // CAP_E2 i32
#define OFF_E2S    868416u   // CAP_E2 i32
#define OFF_E2W    1130560u  // CAP_E2 f32 (raw weight; norm computed inline)
#define OFF_S2     1392704u  // CAP_S2 i32
#define OFF_DEG2   1425472u  // CAP_S2 f32 (compact degree, init 1.0)
#define OFF_STATE  1458240u  // CAP_S2*48 f32
#define OFF_X1     3031104u  // CAP_S1*48 f32
#define OFF_TPSF   3817536u  // 128 f32: [0..47]=target_past, [64..111]=state_fut
#define OFF_WHH16  3818048u  // 27*576 h4 (fp16 dWhh, swizzled) = 124416 B
#define OFF_GI0P   3942464u  // 432 f32: dWih[:,48:]@[tp;sf] + dbih

typedef _Float16 h2_t __attribute__((ext_vector_type(2)));
typedef _Float16 h4_t __attribute__((ext_vector_type(4)));

__device__ __forceinline__ float sigmf(float x) { return 1.0f / (1.0f + expf(-x)); }

#if __has_builtin(__builtin_amdgcn_fdot2)
__device__ __forceinline__ float fdot2f(h2_t a, h2_t b, float c) {
    return __builtin_amdgcn_fdot2(a, b, c, false);
}
#else
__device__ __forceinline__ float fdot2f(h2_t a, h2_t b, float c) {
    return c + (float)a.x * (float)b.x + (float)a.y * (float)b.y;
}
#endif

// ---------------- K1: find edges into node 0 (4 edges/thread) --------------
__global__ void k_edges1(const int* ei, const float* ew,
                         int* mark1, unsigned* cnt, int* l1r, float* l1w) {
    int q = blockIdx.x * blockDim.x + threadIdx.x;
    if (q >= NE / 4) return;
    if (q == 0) mark1[0] = 1;   // node 0 always in S1
    int4 c4 = reinterpret_cast<const int4*>(ei + NE)[q];
    int e = q * 4;
    int cc[4] = {c4.x, c4.y, c4.z, c4.w};
#pragma unroll
    for (int j = 0; j < 4; ++j) {
        if (cc[j] == 0) {
            int r = ei[e + j];
            float w = ew[e + j];
            unsigned s = atomicAdd(&cnt[0], 1u);
            if (s < CAP_L1) { l1r[s] = r; l1w[s] = w; }
            mark1[r] = 1;
        }
    }
}

// ---------------- K2: compact S1; emit self-loop E2 entries; init x1 -------
__global__ void k_compact1(int* mark1, int* mark2, unsigned* cnt,
                           int* e2r, int* e2s, float* e2w, int* s1g,
                           float* x1, const float* g1b) {
    int i = blockIdx.x * blockDim.x + threadIdx.x;
    if (i >= NN) return;
    if (mark1[i]) {
        unsigned s = atomicAdd(&cnt[1], 1u);
        if (s < CAP_S1) {
            mark1[i] = (int)s + 1;
            mark2[i] = 1;               // needs GRU state (self loop row)
            s1g[s] = i;
            unsigned t = atomicAdd(&cnt[2], 1u);
            if (t < CAP_E2) { e2r[t] = i; e2s[t] = (int)s; e2w[t] = 1.0f; }
            for (int k = 0; k < KH; ++k) x1[s * KH + k] = g1b[k];
        } else {
            mark1[i] = 0;
        }
    }
}

// ---------------- K3: collect edges into S1 (4 edges/thread) ---------------
__global__ void k_edges2(const int* ei, const float* ew,
                         const int* mark1, int* mark2, unsigned* cnt,
                         int* e2r, int* e2s, float* e2w) {
    int q = blockIdx.x * blockDim.x + threadIdx.x;
    if (q >= NE / 4) return;
    int4 c4 = reinterpret_cast<const int4*>(ei + NE)[q];
    int e = q * 4;
    int cc[4] = {c4.x, c4.y, c4.z, c4.w};
#pragma unroll
    for (int j = 0; j < 4; ++j) {
        int m = mark1[cc[j]];
        if (m > 0) {
            int r = ei[e + j];
            float w = ew[e + j];
            unsigned s = atomicAdd(&cnt[2], 1u);
            if (s < CAP_E2) { e2r[s] = r; e2s[s] = m - 1; e2w[s] = w; }
            mark2[r] = 1;
        }
    }
}

// ---------------- K4: compact S2; init compact degree ----------------------
__global__ void k_compact2(int* mark2, unsigned* cnt, int* s2, float* deg2) {
    int i = blockIdx.x * blockDim.x + threadIdx.x;
    if (i >= NN) return;
    if (mark2[i]) {
        unsigned s = atomicAdd(&cnt[3], 1u);
        if (s < CAP_S2) { s2[s] = i; mark2[i] = (int)s + 1; deg2[s] = 1.0f; }
        else mark2[i] = 0;
    }
}

// ---------------- conv1d(pad=1,k=3) + GRU over one sequence ----------------
__device__ void gru_seq(const float* xseq, int T,
                        const float* cw, const float* cb,
                        const float* Wih, const float* Whh,
                        const float* bih, const float* bhh,
                        float* out48,
                        float* s_x, float* s_embed, float* s_giA,
                        float* s_h, float* s_gh) {
    int t = threadIdx.x;
    int nt = blockDim.x;
    for (int i = t; i < T * 2; i += nt) s_x[i] = xseq[i];
    __syncthreads();
    for (int idx = t; idx < T * KH; idx += nt) {
        int tt = idx / KH;
        int k = idx - tt * KH;
        float acc = cb[k];
#pragma unroll
        for (int d = 0; d < 3; ++d) {
            int tau = tt + d - 1;
            if (tau >= 0 && tau < T) {
                acc += cw[k * 6 + d] * s_x[tau * 2 + 0];
                acc += cw[k * 6 + 3 + d] * s_x[tau * 2 + 1];
            }
        }
        s_embed[tt * KH + k] = fmaxf(acc, 0.0f);
    }
    __syncthreads();
    // gi = Wih@embed + bih for all steps (parallel; not recurrent)
    for (int idx = t; idx < T * G3; idx += nt) {
        int step = idx / G3;
        int row = idx - step * G3;
        const float4* wp = reinterpret_cast<const float4*>(Wih + row * KH);
        const float4* em = reinterpret_cast<const float4*>(s_embed + step * KH);
        float g = bih[row];
#pragma unroll
        for (int j = 0; j < 12; ++j) {
            float4 w4 = wp[j]; float4 e4 = em[j];
            g += w4.x * e4.x + w4.y * e4.y + w4.z * e4.z + w4.w * e4.w;
        }
        s_giA[idx] = g;
    }
    float4 wh[12];
    float bh = 0.0f;
    if (t < G3) {
        const float4* q = reinterpret_cast<const float4*>(Whh + t * KH);
#pragma unroll
        for (int j = 0; j < 12; ++j) wh[j] = q[j];
        bh = bhh[t];
    }
    if (t < KH) s_h[t] = 0.0f;
    __syncthreads();
    for (int step = 0; step < T; ++step) {
        if (t < G3) {
            const float4* hp = reinterpret_cast<const float4*>(s_h);
            float g = bh;
#pragma unroll
            for (int j = 0; j < 12; ++j) {
                float4 h4 = hp[j];
                g += wh[j].x * h4.x + wh[j].y * h4.y + wh[j].z * h4.z + wh[j].w * h4.w;
            }
            s_gh[t] = g;
        }
        __syncthreads();
        if (t < KH) {
            const float* gi = s_giA + step * G3;
            float r = sigmf(gi[t] + s_gh[t]);
            float z = sigmf(gi[KH + t] + s_gh[KH + t]);
            float n = tanhf(gi[2 * KH + t] + r * s_gh[2 * KH + t]);
            s_h[t] = (1.0f - z) * n + z * s_h[t];
        }
        __syncthreads();
    }
    if (t < KH) out48[t] = s_h[t];
}

// ---------------- K5: deg scan + all GRUs (fused; independent outputs) -----
__global__ __launch_bounds__(192, 2) void k_gru(
    const float* x, const float* cpw, const float* cpb,
    const float* epWih, const float* epWhh, const float* epbih, const float* epbhh,
    const float* cfw, const float* cfb,
    const float* efWih, const float* efWhh, const float* efbih, const float* efbhh,
    const float* past, const float* future,
    const int* ei, const float* ew, const int* mark2, float* deg2,
    const int* s2, const unsigned* cnt, float* state, float* tpsf) {
    if (blockIdx.x < DEGB) {
        // degree accumulation for S2 nodes only (~5K atomics total)
        int per = NE / DEGB;
        int lo = blockIdx.x * per;
        for (int e = lo + threadIdx.x; e < lo + per; e += blockDim.x) {
            int c = ei[NE + e];
            int m = mark2[c];
            if (m > 0) atomicAdd(&deg2[m - 1], ew[e]);
        }
        return;
    }
    __shared__ __align__(16) float s_x[80];
    __shared__ __align__(16) float s_embed[40 * KH];
    __shared__ __align__(16) float s_giA[40 * G3];
    __shared__ __align__(16) float s_h[KH];
    __shared__ float s_gh[G3];
    if (blockIdx.x == DEGB) {
        gru_seq(past, 20, cpw, cpb, epWih, epWhh, epbih, epbhh,
                tpsf, s_x, s_embed, s_giA, s_h, s_gh);
        return;
    }
    if (blockIdx.x == DEGB + 1) {
        gru_seq(future, 40, cfw, cfb, efWih, efWhh, efbih, efbhh,
                tpsf + 64, s_x, s_embed, s_giA, s_h, s_gh);
        return;
    }
    int b0 = blockIdx.x - (DEGB + 2);
    int nw = gridDim.x - (DEGB + 2);
    int cnt2 = (int)min(cnt[3], (unsigned)CAP_S2);
    for (int b = b0; b < cnt2; b += nw) {
        int node = s2[b];
        gru_seq(x + (size_t)node * 40, 20, cpw, cpb, epWih, epWhh, epbih, epbhh,
                state + (size_t)b * KH, s_x, s_embed, s_giA, s_h, s_gh);
    }
}

// ---------------- K5b: stage decoder weights (parallel, many CUs) ----------
// part A (ids 0..15551): dWhh -> fp16, swizzled to k_dec's per-thread layout:
//   matvec thread t=(k=t>>2,q=t&3), pair index c=g*9+u (g=gate, u=0..8):
//   whh16[c*576+t] = cols q*36+4u+0..3 of row g*144+k as h4.
//   -> k_dec loads h4 at (c*576+t): 8B/lane, perfectly coalesced, store-warm.
// part B (ids 15552..15983): gi0p[row] = dWih[row][48:144] @ [tp;sf] + dbih.
__global__ void k_stage(const float* dWhh, const float* dWih,
                        const float* dbih, const float* tpsf,
                        _Float16* whh16, float* gi0p) {
    int id = blockIdx.x * blockDim.x + threadIdx.x;
    if (id < 27 * 576) {
        int c = id / 576, t = id - c * 576;
        int k = t >> 2, q = t & 3;
        int g = c / 9, u = c - g * 9;
        const float* src = dWhh + (size_t)(g * G3 + k) * G3 + q * 36 + 4 * u;
        float4 f = *reinterpret_cast<const float4*>(src);
        h2_t a, b;
        a.x = (_Float16)f.x; a.y = (_Float16)f.y;
        b.x = (_Float16)f.z; b.y = (_Float16)f.w;
        h2_t* o = reinterpret_cast<h2_t*>(whh16);
        o[2 * id + 0] = a;
        o[2 * id + 1] = b;
        return;
    }
    int row = id - 27 * 576;
    if (row < 432) {
        const float* wr = dWih + (size_t)row * G3;
        float acc = dbih[row];
#pragma unroll
        for (int m = 0; m < 48; ++m) acc += wr[48 + m] * tpsf[m];
#pragma unroll
        for (int m = 0; m < 48; ++m) acc += wr[96 + m] * tpsf[64 + m];
        gi0p[row] = acc;
    }
}

// ---------------- K6: GCN layer 1 edge accumulation (norm inline) ----------
__global__ void k_acc1(const unsigned* cnt, const int* e2r, const int* e2s,
                       const float* e2w, const int* mark2, const float* deg2,
                       const int* s1g, const float* state,
                       const float* W1, float* x1) {
    int nE = (int)min(cnt[2], (unsigned)CAP_E2);
    int total = nE * KH;
    int stride = gridDim.x * blockDim.x;
    for (int idx = blockIdx.x * blockDim.x + threadIdx.x; idx < total; idx += stride) {
        int e = idx / KH;
        int k = idx - e * KH;
        int row = e2r[e];
        int s2i = mark2[row] - 1;
        if (s2i < 0) continue;
        int cglob = s1g[e2s[e]];
        int cs2 = mark2[cglob] - 1;
        float norm = e2w[e] * rsqrtf(deg2[s2i] * deg2[cs2]);
        const float* sp = state + (size_t)s2i * KH;
        const float* wp = W1 + k * KH;
        float acc = 0.0f;
#pragma unroll
        for (int m = 0; m < KH; ++m) acc += sp[m] * wp[m];
        atomicAdd(&x1[e2s[e] * KH + k], acc * norm);
    }
}

// ---------------- K7: GCN layer 2 @ node 0 + decoder -----------------------
// R3/R4: the serial-path bottleneck is streaming ~500KB of f32 weights
// through ONE CU (all R0-R2 variants ~67us regardless of inner loop). Now:
//   - dWhh comes from k_stage's fp16 swizzled buffer: 124KB, 27 coalesced
//     8B h4 loads/thread, no conversion VALU work, store-warm.
//   - dWih tail (cols 48:144, 166KB) folded into gi0p by k_stage; k_dec
//     reads only dWih[:, :48] (83KB) for the interact_past third.
// Loop structure identical to R2 (4-way split, 1 barrier/iter, fc wave).
__global__ __launch_bounds__(640, 1) void k_dec(
    const unsigned* cnt, const int* l1r, const float* l1w,
    const int* mark1, const int* mark2, const float* deg2, const float* x1,
    const float* W2, const float* b2, const float* tpsf, const float* past,
    const float* dWih, const _Float16* whh16, const float* gi0p,
    const float* dbih, const float* dbhh,
    const float* fcw, const float* fcb, float* out) {
    __shared__ __align__(16) float s_conc[G3];
    __shared__ __align__(16) _Float16 s_h16[2][G3];   // fp16 h, double-buffered
    __shared__ __align__(16) float s_hf[2][G3];       // f32 h for fc
    int t = threadIdx.x;
    if (t < 48) s_conc[t] = b2[t];
    else if (t < 96) s_conc[t] = tpsf[t - 48];
    else if (t < 144) s_conc[t] = tpsf[64 + t - 96];
    if (t < G3) {
        s_h16[0][t] = (_Float16)0.0f;
        s_hf[0][t] = 0.0f;
    }
    __syncthreads();
    // layer-2 message accumulation into s_conc[0..47]
    int cl1 = (int)min(cnt[0], (unsigned)CAP_L1);
    float dinv0 = rsqrtf(deg2[mark2[0] - 1]);
    int items = (cl1 + 1) * KH;
    for (int idx = t; idx < items; idx += blockDim.x) {
        int e = idx / KH;
        int k = idx - e * KH;
        int row; float norm;
        if (e == cl1) { row = 0; norm = dinv0 * dinv0; }
        else {
            row = l1r[e];
            int rs2 = mark2[row] - 1;
            if (rs2 < 0) continue;
            norm = l1w[e] * rsqrtf(deg2[rs2]) * dinv0;
        }
        int s1 = mark1[row] - 1;
        if (s1 < 0) continue;
        const float* xp = x1 + (size_t)s1 * KH;
        const float* wp = W2 + k * KH;
        float acc = 0.0f;
#pragma unroll
        for (int m = 0; m < KH; ++m) acc += fmaxf(xp[m], 0.0f) * wp[m];
        atomicAdd(&s_conc[k], acc * norm);
    }
    // decoder weight load: 27 coalesced h4 (8B) loads from staged buffer.
    // wh flat: wh[g*18 + 2u + parity] covers cols q*36 + 4u + {0,1}/{2,3}.
    int k = t >> 2, q = t & 3;
    h2_t wh[54];
    float bh[3] = {0.0f, 0.0f, 0.0f};
    float bi[3] = {0.0f, 0.0f, 0.0f};
    if (t < 576) {
        const h4_t* wp = reinterpret_cast<const h4_t*>(whh16);
#pragma unroll
        for (int c = 0; c < 27; ++c) {
            h4_t v = wp[c * 576 + t];
            wh[2 * c] = __builtin_shufflevector(v, v, 0, 1);
            wh[2 * c + 1] = __builtin_shufflevector(v, v, 2, 3);
        }
        if (q == 0) {
#pragma unroll
            for (int g = 0; g < 3; ++g) {
                bh[g] = dbhh[g * G3 + k];
                bi[g] = dbih[g * G3 + k];
            }
        }
    }
    // fc wave preload (wave 9)
    float fw0[3] = {0, 0, 0}, fw1[3] = {0, 0, 0};
    float fcb0 = 0.0f, fcb1 = 0.0f, pres0 = 0.0f, pres1 = 0.0f;
    if (t >= 576) {
        int lane = t - 576;
#pragma unroll
        for (int j = 0; j < 3; ++j) {
            int m = lane + 64 * j;
            if (m < G3) { fw0[j] = fcw[m]; fw1[j] = fcw[G3 + m]; }
        }
        if (lane == 0) {
            fcb0 = fcb[0]; fcb1 = fcb[1];
            pres0 = past[38]; pres1 = past[39];
        }
    }
    __syncthreads();   // s_conc complete
    // gi0 = dWih[:, :48] @ interact_past + gi0p (gi0p has bih + tail matvec)
    float gi0[3] = {0.0f, 0.0f, 0.0f};
    if (t < 576) {
#pragma unroll
        for (int g = 0; g < 3; ++g) {
            float acc = 0.0f;
            if (q == 0) {
                const float4* p = reinterpret_cast<const float4*>(
                    dWih + (size_t)(g * G3 + k) * G3);
                const float4* cc = reinterpret_cast<const float4*>(s_conc);
#pragma unroll
                for (int j = 0; j < 9; ++j) {
                    float4 w4 = p[j]; float4 c4 = cc[j];
                    acc += w4.x * c4.x + w4.y * c4.y + w4.z * c4.z + w4.w * c4.w;
                }
            } else if (q == 1) {
                const float4* p = reinterpret_cast<const float4*>(
                    dWih + (size_t)(g * G3 + k) * G3 + 36);
                const float4* cc = reinterpret_cast<const float4*>(s_conc + 36);
#pragma unroll
                for (int j = 0; j < 3; ++j) {
                    float4 w4 = p[j]; float4 c4 = cc[j];
                    acc += w4.x * c4.x + w4.y * c4.y + w4.z * c4.z + w4.w * c4.w;
                }
            }
            acc += __shfl_xor(acc, 1);
            acc += __shfl_xor(acc, 2);
            gi0[g] = acc + gi0p[g * G3 + k];
        }
    }
    float hk = 0.0f;   // h[k] carried in f32 (q==0 lanes)
    for (int i = 0; i < 40; ++i) {
        __syncthreads();
        int cur = i & 1, nxt = cur ^ 1;
        if (t < 576) {
            // h quarter: 9 x ds_read_b64, split to h2 via shufflevector
            const h4_t* hp = reinterpret_cast<const h4_t*>(&s_h16[cur][0]) + q * 9;
            float a0 = bh[0], a1 = bh[1], a2 = bh[2];
#pragma unroll
            for (int j = 0; j < 9; ++j) {
                h4_t hv = hp[j];
                h2_t lo = __builtin_shufflevector(hv, hv, 0, 1);
                h2_t hi = __builtin_shufflevector(hv, hv, 2, 3);
                a0 = fdot2f(wh[2 * j], lo, a0);
                a1 = fdot2f(wh[18 + 2 * j], lo, a1);
                a2 = fdot2f(wh[36 + 2 * j], lo, a2);
                a0 = fdot2f(wh[2 * j + 1], hi, a0);
                a1 = fdot2f(wh[18 + 2 * j + 1], hi, a1);
                a2 = fdot2f(wh[36 + 2 * j + 1], hi, a2);
            }
            a0 += __shfl_xor(a0, 1); a0 += __shfl_xor(a0, 2);
            a1 += __shfl_xor(a1, 1); a1 += __shfl_xor(a1, 2);
            a2 += __shfl_xor(a2, 1); a2 += __shfl_xor(a2, 2);
            if (q == 0) {
                float gr = ((i == 0) ? gi0[0] : bi[0]) + a0;
                float gz = ((i == 0) ? gi0[1] : bi[1]) + a1;
                float gn = ((i == 0) ? gi0[2] : bi[2]);
                float r = sigmf(gr);
                float z = sigmf(gz);
                float n = tanhf(gn + r * a2);
                hk = (1.0f - z) * n + z * hk;
                s_h16[nxt][k] = (_Float16)hk;
                s_hf[nxt][k] = hk;
            }
        } else if (i >= 1) {
            // fc for step i-1 (h_i lives in buffer cur), overlapped w/ matvec
            int lane = t - 576;
            const float* hsrc = s_hf[cur];
            float p0 = 0.0f, p1 = 0.0f;
#pragma unroll
            for (int j = 0; j < 3; ++j) {
                int m = lane + 64 * j;
                if (m < G3) { float h = hsrc[m]; p0 += h * fw0[j]; p1 += h * fw1[j]; }
            }
#pragma unroll
            for (int off = 32; off > 0; off >>= 1) {
                p0 += __shfl_down(p0, off);
                p1 += __shfl_down(p1, off);
            }
            if (lane == 0) {
                pres0 += p0 + fcb0; pres1 += p1 + fcb1;
                out[(i - 1) * 2 + 0] = pres0;
                out[(i - 1) * 2 + 1] = pres1;
            }
        }
    }
    __syncthreads();
    if (t >= 576) {   // final step's fc (h_40 in buffer 0)
        int lane = t - 576;
        const float* hsrc = s_hf[0];
        float p0 = 0.0f, p1 = 0.0f;
#pragma unroll
        for (int j = 0; j < 3; ++j) {
            int m = lane + 64 * j;
            if (m < G3) { float h = hsrc[m]; p0 += h * fw0[j]; p1 += h * fw1[j]; }
        }
#pragma unroll
        for (int off = 32; off > 0; off >>= 1) {
            p0 += __shfl_down(p0, off);
            p1 += __shfl_down(p1, off);
        }
        if (lane == 0) {
            pres0 += p0 + fcb0; pres1 += p1 + fcb1;
            out[39 * 2 + 0] = pres0;
            out[39 * 2 + 1] = pres1;
        }
    }
}

extern "C" void kernel_launch(void* const* d_in, const int* in_sizes, int n_in,
                              void* d_out, int out_size, void* d_ws, size_t ws_size,
                              hipStream_t stream) {
    (void)in_sizes; (void)n_in; (void)out_size; (void)ws_size;
    const float* past   = (const float*)d_in[0];
    const float* future = (const float*)d_in[1];
    const float* x      = (const float*)d_in[2];
    const int*   ei     = (const int*)d_in[3];
    const float* ew     = (const float*)d_in[4];
    const float* cpw    = (const float*)d_in[5];
    const float* cpb    = (const float*)d_in[6];
    const float* cfw    = (const float*)d_in[7];
    const float* cfb    = (const float*)d_in[8];
    const float* epWih  = (const float*)d_in[9];
    const float* epWhh  = (const float*)d_in[10];
    const float* epbih  = (const float*)d_in[11];
    const float* epbhh  = (const float*)d_in[12];
    const float* efWih  = (const float*)d_in[13];
    const float* efWhh  = (const float*)d_in[14];
    const float* efbih  = (const float*)d_in[15];
    const float* efbhh  = (const float*)d_in[16];
    const float* dWih   = (const float*)d_in[17];
    const float* dWhh   = (const float*)d_in[18];
    const float* dbih   = (const float*)d_in[19];
    const float* dbhh   = (const float*)d_in[20];
    const float* fcw    = (const float*)d_in[21];
    const float* fcb    = (const float*)d_in[22];
    const float* g1w    = (const float*)d_in[23];
    const float* g1b    = (const float*)d_in[24];
    const float* g2w    = (const float*)d_in[25];
    const float* g2b    = (const float*)d_in[26];

    char* ws = (char*)d_ws;
    int*      mark1 = (int*)(ws + OFF_MARK1);
    int*      mark2 = (int*)(ws + OFF_MARK2);
    unsigned* cnt   = (unsigned*)(ws + OFF_CNT);
    int*      l1r   = (int*)(ws + OFF_L1R);
    float*    l1w   = (float*)(ws + OFF_L1W);
    int*      s1g   = (int*)(ws + OFF_S1G);
    int*      e2r   = (int*)(ws + OFF_E2R);
    int*      e2s   = (int*)(ws + OFF_E2S);
    float*    e2w   = (float*)(ws + OFF_E2W);
    int*      s2    = (int*)(ws + OFF_S2);
    float*    deg2  = (float*)(ws + OFF_DEG2);
    float*    state = (float*)(ws + OFF_STATE);
    float*    x1    = (float*)(ws + OFF_X1);
    float*    tpsf  = (float*)(ws + OFF_TPSF);
    _Float16* whh16 = (_Float16*)(ws + OFF_WHH16);
    float*    gi0p  = (float*)(ws + OFF_GI0P);

    hipMemsetAsync(ws, 0, 524352, stream);  // mark1 | mark2 | cnt
    k_edges1<<<NE / 4 / 256, 256, 0, stream>>>(ei, ew, mark1, cnt, l1r, l1w);
    k_compact1<<<NN / 256, 256, 0, stream>>>(mark1, mark2, cnt, e2r, e2s, e2w, s1g, x1, g1b);
    k_edges2<<<NE / 4 / 256, 256, 0, stream>>>(ei, ew, mark1, mark2, cnt, e2r, e2s, e2w);
    k_compact2<<<NN / 256, 256, 0, stream>>>(mark2, cnt, s2, deg2);
    k_gru<<<DEGB + 2 + 512, 192, 0, stream>>>(x, cpw, cpb, epWih, epWhh, epbih, epbhh,
                                              cfw, cfb, efWih, efWhh, efbih, efbhh,
                                              past, future, ei, ew, mark2, deg2,
                                              s2, cnt, state, tpsf);
    k_stage<<<63, 256, 0, stream>>>(dWhh, dWih, dbih, tpsf, whh16, gi0p);
    k_acc1<<<128, 256, 0, stream>>>(cnt, e2r, e2s, e2w, mark2, deg2, s1g, state, g1w, x1);
    k_dec<<<1, 640, 0, stream>>>(cnt, l1r, l1w, mark1, mark2, deg2, x1, g2w, g2b,
                                 tpsf, past, dWih, whh16, gi0p, dbih, dbhh, fcw, fcb,
                                 (float*)d_out);
}

// Round 6
// 241.905 us; speedup vs baseline: 1.0539x; 1.0119x over previous
//
#include <hip/hip_runtime.h>
#include <math.h>

#define NN 65536
#define NE 1048576
#define KH 48
#define G3 144
#define DEGB 512

#define CAP_L1 8192
#define CAP_S1 4096
#define CAP_E2 65536
#define CAP_S2 8192

// ws byte offsets. First 524352 bytes (mark1|mark2|cnt) are zeroed by one
// hipMemsetAsync in kernel_launch.
#define OFF_MARK1  0u        // NN i32
#define OFF_MARK2  262144u   // NN i32
#define OFF_CNT    524288u   // 16 u32: [0]=cntL1 [1]=cntS1 [2]=cntE2 [3]=cntS2
#define OFF_L1R    524352u   // CAP_L1 i32
#define OFF_L1W    557120u   // CAP_L1 f32
#define OFF_S1G    589888u   // CAP_S1 i32 (S1 index -> global node id)
#define OFF_E2R    606272u   // CAP_E2 i32
#define OFF_E2S    868416u   // CAP_E2 i32
#define OFF_E2W    1130560u  // CAP_E2 f32 (raw weight; norm computed inline)
#define OFF_S2     1392704u  // CAP_S2 i32
#define OFF_DEG2   1425472u  // CAP_S2 f32 (compact degree, init 1.0)
#define OFF_STATE  1458240u  // CAP_S2*48 f32
#define OFF_X1     3031104u  // CAP_S1*48 f32
#define OFF_TPSF   3817536u  // 128 f32: [0..47]=target_past, [64..111]=state_fut
#define OFF_WHH16  3818048u  // 27*576 h4 (fp16 dWhh, swizzled) = 124416 B
#define OFF_GI0P   3942464u  // 432 f32: dWih[:,48:]@[tp;sf] + dbih

typedef _Float16 h2_t __attribute__((ext_vector_type(2)));
typedef _Float16 h4_t __attribute__((ext_vector_type(4)));

__device__ __forceinline__ float sigmf(float x) { return 1.0f / (1.0f + expf(-x)); }

#if __has_builtin(__builtin_amdgcn_fdot2)
__device__ __forceinline__ float fdot2f(h2_t a, h2_t b, float c) {
    return __builtin_amdgcn_fdot2(a, b, c, false);
}
#else
__device__ __forceinline__ float fdot2f(h2_t a, h2_t b, float c) {
    return c + (float)a.x * (float)b.x + (float)a.y * (float)b.y;
}
#endif

// ---------------- K1: find edges into node 0 (4 edges/thread) --------------
__global__ void k_edges1(const int* ei, const float* ew,
                         int* mark1, unsigned* cnt, int* l1r, float* l1w) {
    int q = blockIdx.x * blockDim.x + threadIdx.x;
    if (q >= NE / 4) return;
    if (q == 0) mark1[0] = 1;   // node 0 always in S1
    int4 c4 = reinterpret_cast<const int4*>(ei + NE)[q];
    int e = q * 4;
    int cc[4] = {c4.x, c4.y, c4.z, c4.w};
#pragma unroll
    for (int j = 0; j < 4; ++j) {
        if (cc[j] == 0) {
            int r = ei[e + j];
            float w = ew[e + j];
            unsigned s = atomicAdd(&cnt[0], 1u);
            if (s < CAP_L1) { l1r[s] = r; l1w[s] = w; }
            mark1[r] = 1;
        }
    }
}

// ---------------- K2: compact S1; emit self-loop E2 entries; init x1 -------
__global__ void k_compact1(int* mark1, int* mark2, unsigned* cnt,
                           int* e2r, int* e2s, float* e2w, int* s1g,
                           float* x1, const float* g1b) {
    int i = blockIdx.x * blockDim.x + threadIdx.x;
    if (i >= NN) return;
    if (mark1[i]) {
        unsigned s = atomicAdd(&cnt[1], 1u);
        if (s < CAP_S1) {
            mark1[i] = (int)s + 1;
            mark2[i] = 1;               // needs GRU state (self loop row)
            s1g[s] = i;
            unsigned t = atomicAdd(&cnt[2], 1u);
            if (t < CAP_E2) { e2r[t] = i; e2s[t] = (int)s; e2w[t] = 1.0f; }
            for (int k = 0; k < KH; ++k) x1[s * KH + k] = g1b[k];
        } else {
            mark1[i] = 0;
        }
    }
}

// ---------------- K3: collect edges into S1 (4 edges/thread) ---------------
__global__ void k_edges2(const int* ei, const float* ew,
                         const int* mark1, int* mark2, unsigned* cnt,
                         int* e2r, int* e2s, float* e2w) {
    int q = blockIdx.x * blockDim.x + threadIdx.x;
    if (q >= NE / 4) return;
    int4 c4 = reinterpret_cast<const int4*>(ei + NE)[q];
    int e = q * 4;
    int cc[4] = {c4.x, c4.y, c4.z, c4.w};
#pragma unroll
    for (int j = 0; j < 4; ++j) {
        int m = mark1[cc[j]];
        if (m > 0) {
            int r = ei[e + j];
            float w = ew[e + j];
            unsigned s = atomicAdd(&cnt[2], 1u);
            if (s < CAP_E2) { e2r[s] = r; e2s[s] = m - 1; e2w[s] = w; }
            mark2[r] = 1;
        }
    }
}

// ---------------- K4: compact S2; init compact degree ----------------------
__global__ void k_compact2(int* mark2, unsigned* cnt, int* s2, float* deg2) {
    int i = blockIdx.x * blockDim.x + threadIdx.x;
    if (i >= NN) return;
    if (mark2[i]) {
        unsigned s = atomicAdd(&cnt[3], 1u);
        if (s < CAP_S2) { s2[s] = i; mark2[i] = (int)s + 1; deg2[s] = 1.0f; }
        else mark2[i] = 0;
    }
}

// ---------------- conv1d(pad=1,k=3) + GRU over one sequence ----------------
// R5: recurrent loop restructured k_dec-style. Lane pair (k=t>>1, hf=t&1)
// owns all 3 gate rows {k,48+k,96+k} of Whh, half hf (24 cols, 18 float4,
// f32 -> no precision change). Halves combined via shfl_xor(1); gates fused
// into hf==0 lane; h[k] carried in register; s_h double-buffered ->
// ONE barrier per step (was 2 + s_gh LDS round-trip + 48-deep dep chain).
__device__ void gru_seq(const float* xseq, int T,
                        const float* cw, const float* cb,
                        const float* Wih, const float* Whh,
                        const float* bih, const float* bhh,
                        float* out48,
                        float* s_x, float* s_embed, float* s_giA,
                        float* s_h /* [2][KH] */) {
    int t = threadIdx.x;
    int nt = blockDim.x;
    for (int i = t; i < T * 2; i += nt) s_x[i] = xseq[i];
    __syncthreads();
    for (int idx = t; idx < T * KH; idx += nt) {
        int tt = idx / KH;
        int k = idx - tt * KH;
        float acc = cb[k];
#pragma unroll
        for (int d = 0; d < 3; ++d) {
            int tau = tt + d - 1;
            if (tau >= 0 && tau < T) {
                acc += cw[k * 6 + d] * s_x[tau * 2 + 0];
                acc += cw[k * 6 + 3 + d] * s_x[tau * 2 + 1];
            }
        }
        s_embed[tt * KH + k] = fmaxf(acc, 0.0f);
    }
    __syncthreads();
    // gi = Wih@embed + bih for all steps (parallel; not recurrent)
    for (int idx = t; idx < T * G3; idx += nt) {
        int step = idx / G3;
        int row = idx - step * G3;
        const float4* wp = reinterpret_cast<const float4*>(Wih + row * KH);
        const float4* em = reinterpret_cast<const float4*>(s_embed + step * KH);
        float g = bih[row];
#pragma unroll
        for (int j = 0; j < 12; ++j) {
            float4 w4 = wp[j]; float4 e4 = em[j];
            g += w4.x * e4.x + w4.y * e4.y + w4.z * e4.z + w4.w * e4.w;
        }
        s_giA[idx] = g;
    }
    // recurrent weights: lane pair (k, hf) -> 3 gate rows, half each (f32).
    // Loaded after the gi phase to keep peak VGPR pressure low (no spill).
    int k = t >> 1, hf = t & 1;
    float4 wr[18];
    float bh0 = 0.0f, bh1 = 0.0f, bh2 = 0.0f;
    if (t < 96) {
#pragma unroll
        for (int g = 0; g < 3; ++g) {
            const float4* q = reinterpret_cast<const float4*>(
                Whh + (g * KH + k) * KH + hf * 24);
#pragma unroll
            for (int j = 0; j < 6; ++j) wr[g * 6 + j] = q[j];
        }
        if (hf == 0) { bh0 = bhh[k]; bh1 = bhh[KH + k]; bh2 = bhh[2 * KH + k]; }
    }
    if (t < KH) s_h[t] = 0.0f;   // buffer 0
    float hk = 0.0f;             // h[k] in register (hf==0 lanes)
    for (int step = 0; step < T; ++step) {
        __syncthreads();         // first iter: covers gi + s_h init too
        int cur = step & 1, nxt = cur ^ 1;
        if (t < 96) {
            const float4* hp = reinterpret_cast<const float4*>(s_h + cur * KH)
                               + hf * 6;
            float a0 = bh0, a1 = bh1, a2 = bh2;
#pragma unroll
            for (int j = 0; j < 6; ++j) {
                float4 hv = hp[j];
                float4 w0 = wr[j], w1 = wr[6 + j], w2 = wr[12 + j];
                a0 += w0.x * hv.x + w0.y * hv.y + w0.z * hv.z + w0.w * hv.w;
                a1 += w1.x * hv.x + w1.y * hv.y + w1.z * hv.z + w1.w * hv.w;
                a2 += w2.x * hv.x + w2.y * hv.y + w2.z * hv.z + w2.w * hv.w;
            }
            a0 += __shfl_xor(a0, 1);
            a1 += __shfl_xor(a1, 1);
            a2 += __shfl_xor(a2, 1);
            if (hf == 0) {
                const float* gi = s_giA + step * G3;
                float r = sigmf(gi[k] + a0);
                float z = sigmf(gi[KH + k] + a1);
                float n = tanhf(gi[2 * KH + k] + r * a2);
                hk = (1.0f - z) * n + z * hk;
                s_h[nxt * KH + k] = hk;
            }
        }
    }
    __syncthreads();
    if (t < KH) out48[t] = s_h[(T & 1) * KH + t];
}

// ---------------- K5: deg scan + all GRUs (fused; independent outputs) -----
__global__ __launch_bounds__(192, 2) void k_gru(
    const float* x, const float* cpw, const float* cpb,
    const float* epWih, const float* epWhh, const float* epbih, const float* epbhh,
    const float* cfw, const float* cfb,
    const float* efWih, const float* efWhh, const float* efbih, const float* efbhh,
    const float* past, const float* future,
    const int* ei, const float* ew, const int* mark2, float* deg2,
    const int* s2, const unsigned* cnt, float* state, float* tpsf) {
    if (blockIdx.x < DEGB) {
        // degree accumulation for S2 nodes only (~5K atomics total)
        int per = NE / DEGB;
        int lo = blockIdx.x * per;
        for (int e = lo + threadIdx.x; e < lo + per; e += blockDim.x) {
            int c = ei[NE + e];
            int m = mark2[c];
            if (m > 0) atomicAdd(&deg2[m - 1], ew[e]);
        }
        return;
    }
    __shared__ __align__(16) float s_x[80];
    __shared__ __align__(16) float s_embed[40 * KH];
    __shared__ __align__(16) float s_giA[40 * G3];
    __shared__ __align__(16) float s_h[2 * KH];
    if (blockIdx.x == DEGB) {
        gru_seq(past, 20, cpw, cpb, epWih, epWhh, epbih, epbhh,
                tpsf, s_x, s_embed, s_giA, s_h);
        return;
    }
    if (blockIdx.x == DEGB + 1) {
        gru_seq(future, 40, cfw, cfb, efWih, efWhh, efbih, efbhh,
                tpsf + 64, s_x, s_embed, s_giA, s_h);
        return;
    }
    int b0 = blockIdx.x - (DEGB + 2);
    int nw = gridDim.x - (DEGB + 2);
    int cnt2 = (int)min(cnt[3], (unsigned)CAP_S2);
    for (int b = b0; b < cnt2; b += nw) {
        int node = s2[b];
        gru_seq(x + (size_t)node * 40, 20, cpw, cpb, epWih, epWhh, epbih, epbhh,
                state + (size_t)b * KH, s_x, s_embed, s_giA, s_h);
    }
}

// ---------------- K6: staging (blocks 0..63) + GCN layer 1 edge acc --------
// Staging part A (ids 0..15551): dWhh -> fp16, swizzled to k_dec layout:
//   whh16[c*576+t] = cols q*36+4u+0..3 of row g*144+k as h4 (c=g*9+u).
// part B (ids 15552..15983): gi0p[row] = dWih[row][48:144] @ [tp;sf] + dbih.
// Blocks 64..191: original edge accumulation (norm inline).
__global__ void k_acc1(const unsigned* cnt, const int* e2r, const int* e2s,
                       const float* e2w, const int* mark2, const float* deg2,
                       const int* s1g, const float* state,
                       const float* W1, float* x1,
                       const float* dWhh, const float* dWih,
                       const float* dbih, const float* tpsf,
                       _Float16* whh16, float* gi0p) {
    if (blockIdx.x < 64) {
        int id = blockIdx.x * blockDim.x + threadIdx.x;
        if (id < 27 * 576) {
            int c = id / 576, t = id - c * 576;
            int k = t >> 2, q = t & 3;
            int g = c / 9, u = c - g * 9;
            const float* src = dWhh + (size_t)(g * G3 + k) * G3 + q * 36 + 4 * u;
            float4 f = *reinterpret_cast<const float4*>(src);
            h2_t a, b;
            a.x = (_Float16)f.x; a.y = (_Float16)f.y;
            b.x = (_Float16)f.z; b.y = (_Float16)f.w;
            h2_t* o = reinterpret_cast<h2_t*>(whh16);
            o[2 * id + 0] = a;
            o[2 * id + 1] = b;
            return;
        }
        int row = id - 27 * 576;
        if (row < 432) {
            const float* wr = dWih + (size_t)row * G3;
            float acc = dbih[row];
#pragma unroll
            for (int m = 0; m < 48; ++m) acc += wr[48 + m] * tpsf[m];
#pragma unroll
            for (int m = 0; m < 48; ++m) acc += wr[96 + m] * tpsf[64 + m];
            gi0p[row] = acc;
        }
        return;
    }
    int nE = (int)min(cnt[2], (unsigned)CAP_E2);
    int total = nE * KH;
    int stride = (gridDim.x - 64) * blockDim.x;
    for (int idx = (blockIdx.x - 64) * blockDim.x + threadIdx.x; idx < total;
         idx += stride) {
        int e = idx / KH;
        int k = idx - e * KH;
        int row = e2r[e];
        int s2i = mark2[row] - 1;
        if (s2i < 0) continue;
        int cglob = s1g[e2s[e]];
        int cs2 = mark2[cglob] - 1;
        float norm = e2w[e] * rsqrtf(deg2[s2i] * deg2[cs2]);
        const float* sp = state + (size_t)s2i * KH;
        const float* wp = W1 + k * KH;
        float acc = 0.0f;
#pragma unroll
        for (int m = 0; m < KH; ++m) acc += sp[m] * wp[m];
        atomicAdd(&x1[e2s[e] * KH + k], acc * norm);
    }
}

// ---------------- K7: GCN layer 2 @ node 0 + decoder -----------------------
// dWhh from staged fp16 swizzled buffer (124KB, coalesced); dWih tail folded
// into gi0p; loop: 4-way split, 1 barrier/iter, fc wave (R2 structure).
__global__ __launch_bounds__(640, 1) void k_dec(
    const unsigned* cnt, const int* l1r, const float* l1w,
    const int* mark1, const int* mark2, const float* deg2, const float* x1,
    const float* W2, const float* b2, const float* tpsf, const float* past,
    const float* dWih, const _Float16* whh16, const float* gi0p,
    const float* dbih, const float* dbhh,
    const float* fcw, const float* fcb, float* out) {
    __shared__ __align__(16) float s_conc[G3];
    __shared__ __align__(16) _Float16 s_h16[2][G3];   // fp16 h, double-buffered
    __shared__ __align__(16) float s_hf[2][G3];       // f32 h for fc
    int t = threadIdx.x;
    if (t < 48) s_conc[t] = b2[t];
    else if (t < 96) s_conc[t] = tpsf[t - 48];
    else if (t < 144) s_conc[t] = tpsf[64 + t - 96];
    if (t < G3) {
        s_h16[0][t] = (_Float16)0.0f;
        s_hf[0][t] = 0.0f;
    }
    __syncthreads();
    // layer-2 message accumulation into s_conc[0..47]
    int cl1 = (int)min(cnt[0], (unsigned)CAP_L1);
    float dinv0 = rsqrtf(deg2[mark2[0] - 1]);
    int items = (cl1 + 1) * KH;
    for (int idx = t; idx < items; idx += blockDim.x) {
        int e = idx / KH;
        int k = idx - e * KH;
        int row; float norm;
        if (e == cl1) { row = 0; norm = dinv0 * dinv0; }
        else {
            row = l1r[e];
            int rs2 = mark2[row] - 1;
            if (rs2 < 0) continue;
            norm = l1w[e] * rsqrtf(deg2[rs2]) * dinv0;
        }
        int s1 = mark1[row] - 1;
        if (s1 < 0) continue;
        const float* xp = x1 + (size_t)s1 * KH;
        const float* wp = W2 + k * KH;
        float acc = 0.0f;
#pragma unroll
        for (int m = 0; m < KH; ++m) acc += fmaxf(xp[m], 0.0f) * wp[m];
        atomicAdd(&s_conc[k], acc * norm);
    }
    // decoder weight load: 27 coalesced h4 (8B) loads from staged buffer.
    int k = t >> 2, q = t & 3;
    h2_t wh[54];
    float bh[3] = {0.0f, 0.0f, 0.0f};
    float bi[3] = {0.0f, 0.0f, 0.0f};
    if (t < 576) {
        const h4_t* wp = reinterpret_cast<const h4_t*>(whh16);
#pragma unroll
        for (int c = 0; c < 27; ++c) {
            h4_t v = wp[c * 576 + t];
            wh[2 * c] = __builtin_shufflevector(v, v, 0, 1);
            wh[2 * c + 1] = __builtin_shufflevector(v, v, 2, 3);
        }
        if (q == 0) {
#pragma unroll
            for (int g = 0; g < 3; ++g) {
                bh[g] = dbhh[g * G3 + k];
                bi[g] = dbih[g * G3 + k];
            }
        }
    }
    // fc wave preload (wave 9)
    float fw0[3] = {0, 0, 0}, fw1[3] = {0, 0, 0};
    float fcb0 = 0.0f, fcb1 = 0.0f, pres0 = 0.0f, pres1 = 0.0f;
    if (t >= 576) {
        int lane = t - 576;
#pragma unroll
        for (int j = 0; j < 3; ++j) {
            int m = lane + 64 * j;
            if (m < G3) { fw0[j] = fcw[m]; fw1[j] = fcw[G3 + m]; }
        }
        if (lane == 0) {
            fcb0 = fcb[0]; fcb1 = fcb[1];
            pres0 = past[38]; pres1 = past[39];
        }
    }
    __syncthreads();   // s_conc complete
    // gi0 = dWih[:, :48] @ interact_past + gi0p (gi0p has bih + tail matvec)
    float gi0[3] = {0.0f, 0.0f, 0.0f};
    if (t < 576) {
#pragma unroll
        for (int g = 0; g < 3; ++g) {
            float acc = 0.0f;
            if (q == 0) {
                const float4* p = reinterpret_cast<const float4*>(
                    dWih + (size_t)(g * G3 + k) * G3);
                const float4* cc = reinterpret_cast<const float4*>(s_conc);
#pragma unroll
                for (int j = 0; j < 9; ++j) {
                    float4 w4 = p[j]; float4 c4 = cc[j];
                    acc += w4.x * c4.x + w4.y * c4.y + w4.z * c4.z + w4.w * c4.w;
                }
            } else if (q == 1) {
                const float4* p = reinterpret_cast<const float4*>(
                    dWih + (size_t)(g * G3 + k) * G3 + 36);
                const float4* cc = reinterpret_cast<const float4*>(s_conc + 36);
#pragma unroll
                for (int j = 0; j < 3; ++j) {
                    float4 w4 = p[j]; float4 c4 = cc[j];
                    acc += w4.x * c4.x + w4.y * c4.y + w4.z * c4.z + w4.w * c4.w;
                }
            }
            acc += __shfl_xor(acc, 1);
            acc += __shfl_xor(acc, 2);
            gi0[g] = acc + gi0p[g * G3 + k];
        }
    }
    float hk = 0.0f;   // h[k] carried in f32 (q==0 lanes)
    for (int i = 0; i < 40; ++i) {
        __syncthreads();
        int cur = i & 1, nxt = cur ^ 1;
        if (t < 576) {
            // h quarter: 9 x ds_read_b64, split to h2 via shufflevector
            const h4_t* hp = reinterpret_cast<const h4_t*>(&s_h16[cur][0]) + q * 9;
            float a0 = bh[0], a1 = bh[1], a2 = bh[2];
#pragma unroll
            for (int j = 0; j < 9; ++j) {
                h4_t hv = hp[j];
                h2_t lo = __builtin_shufflevector(hv, hv, 0, 1);
                h2_t hi = __builtin_shufflevector(hv, hv, 2, 3);
                a0 = fdot2f(wh[2 * j], lo, a0);
                a1 = fdot2f(wh[18 + 2 * j], lo, a1);
                a2 = fdot2f(wh[36 + 2 * j], lo, a2);
                a0 = fdot2f(wh[2 * j + 1], hi, a0);
                a1 = fdot2f(wh[18 + 2 * j + 1], hi, a1);
                a2 = fdot2f(wh[36 + 2 * j + 1], hi, a2);
            }
            a0 += __shfl_xor(a0, 1); a0 += __shfl_xor(a0, 2);
            a1 += __shfl_xor(a1, 1); a1 += __shfl_xor(a1, 2);
            a2 += __shfl_xor(a2, 1); a2 += __shfl_xor(a2, 2);
            if (q == 0) {
                float gr = ((i == 0) ? gi0[0] : bi[0]) + a0;
                float gz = ((i == 0) ? gi0[1] : bi[1]) + a1;
                float gn = ((i == 0) ? gi0[2] : bi[2]);
                float r = sigmf(gr);
                float z = sigmf(gz);
                float n = tanhf(gn + r * a2);
                hk = (1.0f - z) * n + z * hk;
                s_h16[nxt][k] = (_Float16)hk;
                s_hf[nxt][k] = hk;
            }
        } else if (i >= 1) {
            // fc for step i-1 (h_i lives in buffer cur), overlapped w/ matvec
            int lane = t - 576;
            const float* hsrc = s_hf[cur];
            float p0 = 0.0f, p1 = 0.0f;
#pragma unroll
            for (int j = 0; j < 3; ++j) {
                int m = lane + 64 * j;
                if (m < G3) { float h = hsrc[m]; p0 += h * fw0[j]; p1 += h * fw1[j]; }
            }
#pragma unroll
            for (int off = 32; off > 0; off >>= 1) {
                p0 += __shfl_down(p0, off);
                p1 += __shfl_down(p1, off);
            }
            if (lane == 0) {
                pres0 += p0 + fcb0; pres1 += p1 + fcb1;
                out[(i - 1) * 2 + 0] = pres0;
                out[(i - 1) * 2 + 1] = pres1;
            }
        }
    }
    __syncthreads();
    if (t >= 576) {   // final step's fc (h_40 in buffer 0)
        int lane = t - 576;
        const float* hsrc = s_hf[0];
        float p0 = 0.0f, p1 = 0.0f;
#pragma unroll
        for (int j = 0; j < 3; ++j) {
            int m = lane + 64 * j;
            if (m < G3) { float h = hsrc[m]; p0 += h * fw0[j]; p1 += h * fw1[j]; }
        }
#pragma unroll
        for (int off = 32; off > 0; off >>= 1) {
            p0 += __shfl_down(p0, off);
            p1 += __shfl_down(p1, off);
        }
        if (lane == 0) {
            pres0 += p0 + fcb0; pres1 += p1 + fcb1;
            out[39 * 2 + 0] = pres0;
            out[39 * 2 + 1] = pres1;
        }
    }
}

extern "C" void kernel_launch(void* const* d_in, const int* in_sizes, int n_in,
                              void* d_out, int out_size, void* d_ws, size_t ws_size,
                              hipStream_t stream) {
    (void)in_sizes; (void)n_in; (void)out_size; (void)ws_size;
    const float* past   = (const float*)d_in[0];
    const float* future = (const float*)d_in[1];
    const float* x      = (const float*)d_in[2];
    const int*   ei     = (const int*)d_in[3];
    const float* ew     = (const float*)d_in[4];
    const float* cpw    = (const float*)d_in[5];
    const float* cpb    = (const float*)d_in[6];
    const float* cfw    = (const float*)d_in[7];
    const float* cfb    = (const float*)d_in[8];
    const float* epWih  = (const float*)d_in[9];
    const float* epWhh  = (const float*)d_in[10];
    const float* epbih  = (const float*)d_in[11];
    const float* epbhh  = (const float*)d_in[12];
    const float* efWih  = (const float*)d_in[13];
    const float* efWhh  = (const float*)d_in[14];
    const float* efbih  = (const float*)d_in[15];
    const float* efbhh  = (const float*)d_in[16];
    const float* dWih   = (const float*)d_in[17];
    const float* dWhh   = (const float*)d_in[18];
    const float* dbih   = (const float*)d_in[19];
    const float* dbhh   = (const float*)d_in[20];
    const float* fcw    = (const float*)d_in[21];
    const float* fcb    = (const float*)d_in[22];
    const float* g1w    = (const float*)d_in[23];
    const float* g1b    = (const float*)d_in[24];
    const float* g2w    = (const float*)d_in[25];
    const float* g2b    = (const float*)d_in[26];

    char* ws = (char*)d_ws;
    int*      mark1 = (int*)(ws + OFF_MARK1);
    int*      mark2 = (int*)(ws + OFF_MARK2);
    unsigned* cnt   = (unsigned*)(ws + OFF_CNT);
    int*      l1r   = (int*)(ws + OFF_L1R);
    float*    l1w   = (float*)(ws + OFF_L1W);
    int*      s1g   = (int*)(ws + OFF_S1G);
    int*      e2r   = (int*)(ws + OFF_E2R);
    int*      e2s   = (int*)(ws + OFF_E2S);
    float*    e2w   = (float*)(ws + OFF_E2W);
    int*      s2    = (int*)(ws + OFF_S2);
    float*    deg2  = (float*)(ws + OFF_DEG2);
    float*    state = (float*)(ws + OFF_STATE);
    float*    x1    = (float*)(ws + OFF_X1);
    float*    tpsf  = (float*)(ws + OFF_TPSF);
    _Float16* whh16 = (_Float16*)(ws + OFF_WHH16);
    float*    gi0p  = (float*)(ws + OFF_GI0P);

    hipMemsetAsync(ws, 0, 524352, stream);  // mark1 | mark2 | cnt
    k_edges1<<<NE / 4 / 256, 256, 0, stream>>>(ei, ew, mark1, cnt, l1r, l1w);
    k_compact1<<<NN / 256, 256, 0, stream>>>(mark1, mark2, cnt, e2r, e2s, e2w, s1g, x1, g1b);
    k_edges2<<<NE / 4 / 256, 256, 0, stream>>>(ei, ew, mark1, mark2, cnt, e2r, e2s, e2w);
    k_compact2<<<NN / 256, 256, 0, stream>>>(mark2, cnt, s2, deg2);
    k_gru<<<DEGB + 2 + 512, 192, 0, stream>>>(x, cpw, cpb, epWih, epWhh, epbih, epbhh,
                                              cfw, cfb, efWih, efWhh, efbih, efbhh,
                                              past, future, ei, ew, mark2, deg2,
                                              s2, cnt, state, tpsf);
    k_acc1<<<64 + 128, 256, 0, stream>>>(cnt, e2r, e2s, e2w, mark2, deg2, s1g,
                                         state, g1w, x1,
                                         dWhh, dWih, dbih, tpsf, whh16, gi0p);
    k_dec<<<1, 640, 0, stream>>>(cnt, l1r, l1w, mark1, mark2, deg2, x1, g2w, g2b,
                                 tpsf, past, dWih, whh16, gi0p, dbih, dbhh, fcw, fcb,
                                 (float*)d_out);
}

// Round 7
// 224.746 us; speedup vs baseline: 1.1344x; 1.0763x over previous
//
#include <hip/hip_runtime.h>
#include <math.h>

#define NN 65536
#define NE 1048576
#define KH 48
#define G3 144
#define DEGB 512
#define PREPB 15

#define CAP_L1 8192
#define CAP_S1 4096
#define CAP_E2 65536
#define CAP_S2 8192

// ws byte offsets. First 524352 bytes (mark1|mark2|cnt) are zeroed by one
// hipMemsetAsync in kernel_launch.
#define OFF_MARK1  0u        // NN i32
#define OFF_MARK2  262144u   // NN i32
#define OFF_CNT    524288u   // 16 u32: [0]=cntL1 [1]=cntS1 [2]=cntE2 [3]=cntS2
#define OFF_L1R    524352u   // CAP_L1 i32
#define OFF_L1W    557120u   // CAP_L1 f32
#define OFF_S1G    589888u   // CAP_S1 i32 (S1 index -> global node id)
#define OFF_E2R    606272u   // CAP_E2 i32
#define OFF_E2S    868416u   // CAP_E2 i32
#define OFF_E2W    1130560u  // CAP_E2 f32 (raw weight; norm computed inline)
#define OFF_S2     1392704u  // CAP_S2 i32
#define OFF_DEG2   1425472u  // CAP_S2 f32 (compact degree, init 1.0)
#define OFF_STATE  1458240u  // CAP_S2*48 f32
#define OFF_X1     3031104u  // CAP_S1*48 f32
#define OFF_TPSF   3817536u  // 128 f32: [0..47]=target_past, [64..111]=state_fut
#define OFF_WHH16  3818048u  // 27*576 h4 (fp16 dWhh, swizzled) = 124416 B
#define OFF_GI0P   3942464u  // 432 f32: dWih[:,48:]@[tp;sf] + dbih
#define OFF_GIP    3944192u  // 20*144 f32: past-encoder gi (precomputed)
#define OFF_GIF    3955712u  // 40*144 f32: future-encoder gi (precomputed)

typedef _Float16 h2_t __attribute__((ext_vector_type(2)));
typedef _Float16 h4_t __attribute__((ext_vector_type(4)));

__device__ __forceinline__ float sigmf(float x) { return 1.0f / (1.0f + expf(-x)); }

#if __has_builtin(__builtin_amdgcn_fdot2)
__device__ __forceinline__ float fdot2f(h2_t a, h2_t b, float c) {
    return __builtin_amdgcn_fdot2(a, b, c, false);
}
#else
__device__ __forceinline__ float fdot2f(h2_t a, h2_t b, float c) {
    return c + (float)a.x * (float)b.x + (float)a.y * (float)b.y;
}
#endif

// ---------------- K1: edges into node 0 (blocks < 1024) + encoder-gi prep --
// Prep blocks (last PREPB): conv1d + gi = Wih@embed + bih for the past/future
// encoder sequences, written to ws. Removes ~170KB of weight streaming +
// conv+gi latency from k_gru's serial single-block tail (R6 post-mortem:
// that tail was the whole 58us).
__global__ void k_edges1(const int* ei, const float* ew,
                         int* mark1, unsigned* cnt, int* l1r, float* l1w,
                         const float* past, const float* future,
                         const float* cpw, const float* cpb,
                         const float* cfw, const float* cfb,
                         const float* epWih, const float* epbih,
                         const float* efWih, const float* efbih,
                         float* giP, float* giF) {
    if (blockIdx.x >= NE / 4 / 256) {
        int p = blockIdx.x - NE / 4 / 256;   // 0..14
        const float* xs; const float* cw; const float* cb;
        const float* Wih; const float* bih; float* gout;
        int T, s0;
        if (p < 5) { xs = past;   cw = cpw; cb = cpb; Wih = epWih; bih = epbih;
                     gout = giP; T = 20; s0 = p * 4; }
        else       { xs = future; cw = cfw; cb = cfb; Wih = efWih; bih = efbih;
                     gout = giF; T = 40; s0 = (p - 5) * 4; }
        __shared__ __align__(16) float s_x[80];
        __shared__ __align__(16) float s_e[4 * KH];
        int t = threadIdx.x;
        if (t < T * 2) s_x[t] = xs[t];
        __syncthreads();
        for (int idx = t; idx < 4 * KH; idx += 256) {
            int lt = idx / KH;
            int k = idx - lt * KH;
            int tt = s0 + lt;
            float acc = cb[k];
#pragma unroll
            for (int d = 0; d < 3; ++d) {
                int tau = tt + d - 1;
                if (tau >= 0 && tau < T) {
                    acc += cw[k * 6 + d] * s_x[tau * 2 + 0];
                    acc += cw[k * 6 + 3 + d] * s_x[tau * 2 + 1];
                }
            }
            s_e[lt * KH + k] = fmaxf(acc, 0.0f);
        }
        __syncthreads();
        for (int idx = t; idx < 4 * G3; idx += 256) {
            int lt = idx / G3;
            int row = idx - lt * G3;
            const float4* wp = reinterpret_cast<const float4*>(Wih + row * KH);
            const float4* em = reinterpret_cast<const float4*>(s_e + lt * KH);
            float g = bih[row];
#pragma unroll
            for (int j = 0; j < 12; ++j) {
                float4 w4 = wp[j]; float4 e4 = em[j];
                g += w4.x * e4.x + w4.y * e4.y + w4.z * e4.z + w4.w * e4.w;
            }
            gout[(s0 + lt) * G3 + row] = g;
        }
        return;
    }
    int q = blockIdx.x * blockDim.x + threadIdx.x;
    if (q >= NE / 4) return;
    if (q == 0) mark1[0] = 1;   // node 0 always in S1
    int4 c4 = reinterpret_cast<const int4*>(ei + NE)[q];
    int e = q * 4;
    int cc[4] = {c4.x, c4.y, c4.z, c4.w};
#pragma unroll
    for (int j = 0; j < 4; ++j) {
        if (cc[j] == 0) {
            int r = ei[e + j];
            float w = ew[e + j];
            unsigned s = atomicAdd(&cnt[0], 1u);
            if (s < CAP_L1) { l1r[s] = r; l1w[s] = w; }
            mark1[r] = 1;
        }
    }
}

// ---------------- K2: compact S1; emit self-loop E2 entries; init x1 -------
__global__ void k_compact1(int* mark1, int* mark2, unsigned* cnt,
                           int* e2r, int* e2s, float* e2w, int* s1g,
                           float* x1, const float* g1b) {
    int i = blockIdx.x * blockDim.x + threadIdx.x;
    if (i >= NN) return;
    if (mark1[i]) {
        unsigned s = atomicAdd(&cnt[1], 1u);
        if (s < CAP_S1) {
            mark1[i] = (int)s + 1;
            mark2[i] = 1;               // needs GRU state (self loop row)
            s1g[s] = i;
            unsigned t = atomicAdd(&cnt[2], 1u);
            if (t < CAP_E2) { e2r[t] = i; e2s[t] = (int)s; e2w[t] = 1.0f; }
            for (int k = 0; k < KH; ++k) x1[s * KH + k] = g1b[k];
        } else {
            mark1[i] = 0;
        }
    }
}

// ---------------- K3: collect edges into S1 (4 edges/thread) ---------------
__global__ void k_edges2(const int* ei, const float* ew,
                         const int* mark1, int* mark2, unsigned* cnt,
                         int* e2r, int* e2s, float* e2w) {
    int q = blockIdx.x * blockDim.x + threadIdx.x;
    if (q >= NE / 4) return;
    int4 c4 = reinterpret_cast<const int4*>(ei + NE)[q];
    int e = q * 4;
    int cc[4] = {c4.x, c4.y, c4.z, c4.w};
#pragma unroll
    for (int j = 0; j < 4; ++j) {
        int m = mark1[cc[j]];
        if (m > 0) {
            int r = ei[e + j];
            float w = ew[e + j];
            unsigned s = atomicAdd(&cnt[2], 1u);
            if (s < CAP_E2) { e2r[s] = r; e2s[s] = m - 1; e2w[s] = w; }
            mark2[r] = 1;
        }
    }
}

// ---------------- K4: compact S2; init compact degree ----------------------
__global__ void k_compact2(int* mark2, unsigned* cnt, int* s2, float* deg2) {
    int i = blockIdx.x * blockDim.x + threadIdx.x;
    if (i >= NN) return;
    if (mark2[i]) {
        unsigned s = atomicAdd(&cnt[3], 1u);
        if (s < CAP_S2) { s2[s] = i; mark2[i] = (int)s + 1; deg2[s] = 1.0f; }
        else mark2[i] = 0;
    }
}

// ---------------- conv1d(pad=1,k=3) + GRU over one sequence (S2 path) ------
__device__ void gru_seq(const float* xseq, int T,
                        const float* cw, const float* cb,
                        const float* Wih, const float* Whh,
                        const float* bih, const float* bhh,
                        float* out48,
                        float* s_x, float* s_embed, float* s_giA,
                        float* s_h /* [2][KH] */) {
    int t = threadIdx.x;
    int nt = blockDim.x;
    for (int i = t; i < T * 2; i += nt) s_x[i] = xseq[i];
    __syncthreads();
    for (int idx = t; idx < T * KH; idx += nt) {
        int tt = idx / KH;
        int k = idx - tt * KH;
        float acc = cb[k];
#pragma unroll
        for (int d = 0; d < 3; ++d) {
            int tau = tt + d - 1;
            if (tau >= 0 && tau < T) {
                acc += cw[k * 6 + d] * s_x[tau * 2 + 0];
                acc += cw[k * 6 + 3 + d] * s_x[tau * 2 + 1];
            }
        }
        s_embed[tt * KH + k] = fmaxf(acc, 0.0f);
    }
    __syncthreads();
    // gi = Wih@embed + bih for all steps (parallel; not recurrent)
    for (int idx = t; idx < T * G3; idx += nt) {
        int step = idx / G3;
        int row = idx - step * G3;
        const float4* wp = reinterpret_cast<const float4*>(Wih + row * KH);
        const float4* em = reinterpret_cast<const float4*>(s_embed + step * KH);
        float g = bih[row];
#pragma unroll
        for (int j = 0; j < 12; ++j) {
            float4 w4 = wp[j]; float4 e4 = em[j];
            g += w4.x * e4.x + w4.y * e4.y + w4.z * e4.z + w4.w * e4.w;
        }
        s_giA[idx] = g;
    }
    // recurrent weights: lane pair (k, hf) -> 3 gate rows, half each (f32)
    int k = t >> 1, hf = t & 1;
    float4 wr[18];
    float bh0 = 0.0f, bh1 = 0.0f, bh2 = 0.0f;
    if (t < 96) {
#pragma unroll
        for (int g = 0; g < 3; ++g) {
            const float4* q = reinterpret_cast<const float4*>(
                Whh + (g * KH + k) * KH + hf * 24);
#pragma unroll
            for (int j = 0; j < 6; ++j) wr[g * 6 + j] = q[j];
        }
        if (hf == 0) { bh0 = bhh[k]; bh1 = bhh[KH + k]; bh2 = bhh[2 * KH + k]; }
    }
    if (t < KH) s_h[t] = 0.0f;   // buffer 0
    float hk = 0.0f;             // h[k] in register (hf==0 lanes)
    for (int step = 0; step < T; ++step) {
        __syncthreads();
        int cur = step & 1, nxt = cur ^ 1;
        if (t < 96) {
            const float4* hp = reinterpret_cast<const float4*>(s_h + cur * KH)
                               + hf * 6;
            float a0 = bh0, a1 = bh1, a2 = bh2;
#pragma unroll
            for (int j = 0; j < 6; ++j) {
                float4 hv = hp[j];
                float4 w0 = wr[j], w1 = wr[6 + j], w2 = wr[12 + j];
                a0 += w0.x * hv.x + w0.y * hv.y + w0.z * hv.z + w0.w * hv.w;
                a1 += w1.x * hv.x + w1.y * hv.y + w1.z * hv.z + w1.w * hv.w;
                a2 += w2.x * hv.x + w2.y * hv.y + w2.z * hv.z + w2.w * hv.w;
            }
            a0 += __shfl_xor(a0, 1);
            a1 += __shfl_xor(a1, 1);
            a2 += __shfl_xor(a2, 1);
            if (hf == 0) {
                const float* gi = s_giA + step * G3;
                float r = sigmf(gi[k] + a0);
                float z = sigmf(gi[KH + k] + a1);
                float n = tanhf(gi[2 * KH + k] + r * a2);
                hk = (1.0f - z) * n + z * hk;
                s_h[nxt * KH + k] = hk;
            }
        }
    }
    __syncthreads();
    if (t < KH) out48[t] = s_h[(T & 1) * KH + t];
}

// -------- recurrent-only GRU (gi precomputed in ws by k_edges1 prep) -------
__device__ void gru_rec(const float* giA /* [T][G3] global */, int T,
                        const float* Whh, const float* bhh,
                        float* out48, float* s_h /* [2][KH] */) {
    int t = threadIdx.x;
    int k = t >> 1, hf = t & 1;
    float4 wr[18];
    float bh0 = 0.0f, bh1 = 0.0f, bh2 = 0.0f;
    if (t < 96) {
#pragma unroll
        for (int g = 0; g < 3; ++g) {
            const float4* q = reinterpret_cast<const float4*>(
                Whh + (g * KH + k) * KH + hf * 24);
#pragma unroll
            for (int j = 0; j < 6; ++j) wr[g * 6 + j] = q[j];
        }
        if (hf == 0) { bh0 = bhh[k]; bh1 = bhh[KH + k]; bh2 = bhh[2 * KH + k]; }
    }
    if (t < KH) s_h[t] = 0.0f;
    float hk = 0.0f;
    for (int step = 0; step < T; ++step) {
        __syncthreads();
        int cur = step & 1, nxt = cur ^ 1;
        if (t < 96) {
            const float4* hp = reinterpret_cast<const float4*>(s_h + cur * KH)
                               + hf * 6;
            float a0 = bh0, a1 = bh1, a2 = bh2;
#pragma unroll
            for (int j = 0; j < 6; ++j) {
                float4 hv = hp[j];
                float4 w0 = wr[j], w1 = wr[6 + j], w2 = wr[12 + j];
                a0 += w0.x * hv.x + w0.y * hv.y + w0.z * hv.z + w0.w * hv.w;
                a1 += w1.x * hv.x + w1.y * hv.y + w1.z * hv.z + w1.w * hv.w;
                a2 += w2.x * hv.x + w2.y * hv.y + w2.z * hv.z + w2.w * hv.w;
            }
            a0 += __shfl_xor(a0, 1);
            a1 += __shfl_xor(a1, 1);
            a2 += __shfl_xor(a2, 1);
            if (hf == 0) {
                const float* gi = giA + step * G3;
                float r = sigmf(gi[k] + a0);
                float z = sigmf(gi[KH + k] + a1);
                float n = tanhf(gi[2 * KH + k] + r * a2);
                hk = (1.0f - z) * n + z * hk;
                s_h[nxt * KH + k] = hk;
            }
        }
    }
    __syncthreads();
    if (t < KH) out48[t] = s_h[(T & 1) * KH + t];
}

// ---------------- K5: deg scan + all GRUs (fused; independent outputs) -----
__global__ __launch_bounds__(192, 2) void k_gru(
    const float* x, const float* cpw, const float* cpb,
    const float* epWih, const float* epWhh, const float* epbih, const float* epbhh,
    const float* efWhh, const float* efbhh,
    const float* giP, const float* giF,
    const int* ei, const float* ew, const int* mark2, float* deg2,
    const int* s2, const unsigned* cnt, float* state, float* tpsf) {
    if (blockIdx.x < DEGB) {
        // degree accumulation for S2 nodes only
        int per = NE / DEGB;
        int lo = blockIdx.x * per;
        for (int e = lo + threadIdx.x; e < lo + per; e += blockDim.x) {
            int c = ei[NE + e];
            int m = mark2[c];
            if (m > 0) atomicAdd(&deg2[m - 1], ew[e]);
        }
        return;
    }
    __shared__ __align__(16) float s_x[80];
    __shared__ __align__(16) float s_embed[40 * KH];
    __shared__ __align__(16) float s_giA[40 * G3];
    __shared__ __align__(16) float s_h[2 * KH];
    if (blockIdx.x == DEGB) {
        gru_rec(giP, 20, epWhh, epbhh, tpsf, s_h);
        return;
    }
    if (blockIdx.x == DEGB + 1) {
        gru_rec(giF, 40, efWhh, efbhh, tpsf + 64, s_h);
        return;
    }
    int b0 = blockIdx.x - (DEGB + 2);
    int nw = gridDim.x - (DEGB + 2);
    int cnt2 = (int)min(cnt[3], (unsigned)CAP_S2);
    for (int b = b0; b < cnt2; b += nw) {
        int node = s2[b];
        gru_seq(x + (size_t)node * 40, 20, cpw, cpb, epWih, epWhh, epbih, epbhh,
                state + (size_t)b * KH, s_x, s_embed, s_giA, s_h);
    }
}

// ---------------- K6: staging (blocks 0..63) + GCN layer 1 edge acc --------
__global__ void k_acc1(const unsigned* cnt, const int* e2r, const int* e2s,
                       const float* e2w, const int* mark2, const float* deg2,
                       const int* s1g, const float* state,
                       const float* W1, float* x1,
                       const float* dWhh, const float* dWih,
                       const float* dbih, const float* tpsf,
                       _Float16* whh16, float* gi0p) {
    if (blockIdx.x < 64) {
        int id = blockIdx.x * blockDim.x + threadIdx.x;
        if (id < 27 * 576) {
            int c = id / 576, t = id - c * 576;
            int k = t >> 2, q = t & 3;
            int g = c / 9, u = c - g * 9;
            const float* src = dWhh + (size_t)(g * G3 + k) * G3 + q * 36 + 4 * u;
            float4 f = *reinterpret_cast<const float4*>(src);
            h2_t a, b;
            a.x = (_Float16)f.x; a.y = (_Float16)f.y;
            b.x = (_Float16)f.z; b.y = (_Float16)f.w;
            h2_t* o = reinterpret_cast<h2_t*>(whh16);
            o[2 * id + 0] = a;
            o[2 * id + 1] = b;
            return;
        }
        int row = id - 27 * 576;
        if (row < 432) {
            const float* wr = dWih + (size_t)row * G3;
            float acc = dbih[row];
#pragma unroll
            for (int m = 0; m < 48; ++m) acc += wr[48 + m] * tpsf[m];
#pragma unroll
            for (int m = 0; m < 48; ++m) acc += wr[96 + m] * tpsf[64 + m];
            gi0p[row] = acc;
        }
        return;
    }
    int nE = (int)min(cnt[2], (unsigned)CAP_E2);
    int total = nE * KH;
    int stride = (gridDim.x - 64) * blockDim.x;
    for (int idx = (blockIdx.x - 64) * blockDim.x + threadIdx.x; idx < total;
         idx += stride) {
        int e = idx / KH;
        int k = idx - e * KH;
        int row = e2r[e];
        int s2i = mark2[row] - 1;
        if (s2i < 0) continue;
        int cglob = s1g[e2s[e]];
        int cs2 = mark2[cglob] - 1;
        float norm = e2w[e] * rsqrtf(deg2[s2i] * deg2[cs2]);
        const float* sp = state + (size_t)s2i * KH;
        const float* wp = W1 + k * KH;
        float acc = 0.0f;
#pragma unroll
        for (int m = 0; m < KH; ++m) acc += sp[m] * wp[m];
        atomicAdd(&x1[e2s[e] * KH + k], acc * norm);
    }
}

// ---------------- K7: GCN layer 2 @ node 0 + decoder -----------------------
__global__ __launch_bounds__(640, 1) void k_dec(
    const unsigned* cnt, const int* l1r, const float* l1w,
    const int* mark1, const int* mark2, const float* deg2, const float* x1,
    const float* W2, const float* b2, const float* tpsf, const float* past,
    const float* dWih, const _Float16* whh16, const float* gi0p,
    const float* dbih, const float* dbhh,
    const float* fcw, const float* fcb, float* out) {
    __shared__ __align__(16) float s_conc[G3];
    __shared__ __align__(16) _Float16 s_h16[2][G3];   // fp16 h, double-buffered
    __shared__ __align__(16) float s_hf[2][G3];       // f32 h for fc
    int t = threadIdx.x;
    if (t < 48) s_conc[t] = b2[t];
    else if (t < 96) s_conc[t] = tpsf[t - 48];
    else if (t < 144) s_conc[t] = tpsf[64 + t - 96];
    if (t < G3) {
        s_h16[0][t] = (_Float16)0.0f;
        s_hf[0][t] = 0.0f;
    }
    __syncthreads();
    // layer-2 message accumulation into s_conc[0..47]
    int cl1 = (int)min(cnt[0], (unsigned)CAP_L1);
    float dinv0 = rsqrtf(deg2[mark2[0] - 1]);
    int items = (cl1 + 1) * KH;
    for (int idx = t; idx < items; idx += blockDim.x) {
        int e = idx / KH;
        int k = idx - e * KH;
        int row; float norm;
        if (e == cl1) { row = 0; norm = dinv0 * dinv0; }
        else {
            row = l1r[e];
            int rs2 = mark2[row] - 1;
            if (rs2 < 0) continue;
            norm = l1w[e] * rsqrtf(deg2[rs2]) * dinv0;
        }
        int s1 = mark1[row] - 1;
        if (s1 < 0) continue;
        const float* xp = x1 + (size_t)s1 * KH;
        const float* wp = W2 + k * KH;
        float acc = 0.0f;
#pragma unroll
        for (int m = 0; m < KH; ++m) acc += fmaxf(xp[m], 0.0f) * wp[m];
        atomicAdd(&s_conc[k], acc * norm);
    }
    // decoder weight load: 27 coalesced h4 (8B) loads from staged buffer.
    int k = t >> 2, q = t & 3;
    h2_t wh[54];
    float bh[3] = {0.0f, 0.0f, 0.0f};
    float bi[3] = {0.0f, 0.0f, 0.0f};
    if (t < 576) {
        const h4_t* wp = reinterpret_cast<const h4_t*>(whh16);
#pragma unroll
        for (int c = 0; c < 27; ++c) {
            h4_t v = wp[c * 576 + t];
            wh[2 * c] = __builtin_shufflevector(v, v, 0, 1);
            wh[2 * c + 1] = __builtin_shufflevector(v, v, 2, 3);
        }
        if (q == 0) {
#pragma unroll
            for (int g = 0; g < 3; ++g) {
                bh[g] = dbhh[g * G3 + k];
                bi[g] = dbih[g * G3 + k];
            }
        }
    }
    // fc wave preload (wave 9)
    float fw0[3] = {0, 0, 0}, fw1[3] = {0, 0, 0};
    float fcb0 = 0.0f, fcb1 = 0.0f, pres0 = 0.0f, pres1 = 0.0f;
    if (t >= 576) {
        int lane = t - 576;
#pragma unroll
        for (int j = 0; j < 3; ++j) {
            int m = lane + 64 * j;
            if (m < G3) { fw0[j] = fcw[m]; fw1[j] = fcw[G3 + m]; }
        }
        if (lane == 0) {
            fcb0 = fcb[0]; fcb1 = fcb[1];
            pres0 = past[38]; pres1 = past[39];
        }
    }
    __syncthreads();   // s_conc complete
    // gi0 = dWih[:, :48] @ interact_past + gi0p (gi0p has bih + tail matvec)
    float gi0[3] = {0.0f, 0.0f, 0.0f};
    if (t < 576) {
#pragma unroll
        for (int g = 0; g < 3; ++g) {
            float acc = 0.0f;
            if (q == 0) {
                const float4* p = reinterpret_cast<const float4*>(
                    dWih + (size_t)(g * G3 + k) * G3);
                const float4* cc = reinterpret_cast<const float4*>(s_conc);
#pragma unroll
                for (int j = 0; j < 9; ++j) {
                    float4 w4 = p[j]; float4 c4 = cc[j];
                    acc += w4.x * c4.x + w4.y * c4.y + w4.z * c4.z + w4.w * c4.w;
                }
            } else if (q == 1) {
                const float4* p = reinterpret_cast<const float4*>(
                    dWih + (size_t)(g * G3 + k) * G3 + 36);
                const float4* cc = reinterpret_cast<const float4*>(s_conc + 36);
#pragma unroll
                for (int j = 0; j < 3; ++j) {
                    float4 w4 = p[j]; float4 c4 = cc[j];
                    acc += w4.x * c4.x + w4.y * c4.y + w4.z * c4.z + w4.w * c4.w;
                }
            }
            acc += __shfl_xor(acc, 1);
            acc += __shfl_xor(acc, 2);
            gi0[g] = acc + gi0p[g * G3 + k];
        }
    }
    float hk = 0.0f;   // h[k] carried in f32 (q==0 lanes)
    for (int i = 0; i < 40; ++i) {
        __syncthreads();
        int cur = i & 1, nxt = cur ^ 1;
        if (t < 576) {
            // h quarter: 9 x ds_read_b64, split to h2 via shufflevector
            const h4_t* hp = reinterpret_cast<const h4_t*>(&s_h16[cur][0]) + q * 9;
            float a0 = bh[0], a1 = bh[1], a2 = bh[2];
#pragma unroll
            for (int j = 0; j < 9; ++j) {
                h4_t hv = hp[j];
                h2_t lo = __builtin_shufflevector(hv, hv, 0, 1);
                h2_t hi = __builtin_shufflevector(hv, hv, 2, 3);
                a0 = fdot2f(wh[2 * j], lo, a0);
                a1 = fdot2f(wh[18 + 2 * j], lo, a1);
                a2 = fdot2f(wh[36 + 2 * j], lo, a2);
                a0 = fdot2f(wh[2 * j + 1], hi, a0);
                a1 = fdot2f(wh[18 + 2 * j + 1], hi, a1);
                a2 = fdot2f(wh[36 + 2 * j + 1], hi, a2);
            }
            a0 += __shfl_xor(a0, 1); a0 += __shfl_xor(a0, 2);
            a1 += __shfl_xor(a1, 1); a1 += __shfl_xor(a1, 2);
            a2 += __shfl_xor(a2, 1); a2 += __shfl_xor(a2, 2);
            if (q == 0) {
                float gr = ((i == 0) ? gi0[0] : bi[0]) + a0;
                float gz = ((i == 0) ? gi0[1] : bi[1]) + a1;
                float gn = ((i == 0) ? gi0[2] : bi[2]);
                float r = sigmf(gr);
                float z = sigmf(gz);
                float n = tanhf(gn + r * a2);
                hk = (1.0f - z) * n + z * hk;
                s_h16[nxt][k] = (_Float16)hk;
                s_hf[nxt][k] = hk;
            }
        } else if (i >= 1) {
            // fc for step i-1 (h_i lives in buffer cur), overlapped w/ matvec
            int lane = t - 576;
            const float* hsrc = s_hf[cur];
            float p0 = 0.0f, p1 = 0.0f;
#pragma unroll
            for (int j = 0; j < 3; ++j) {
                int m = lane + 64 * j;
                if (m < G3) { float h = hsrc[m]; p0 += h * fw0[j]; p1 += h * fw1[j]; }
            }
#pragma unroll
            for (int off = 32; off > 0; off >>= 1) {
                p0 += __shfl_down(p0, off);
                p1 += __shfl_down(p1, off);
            }
            if (lane == 0) {
                pres0 += p0 + fcb0; pres1 += p1 + fcb1;
                out[(i - 1) * 2 + 0] = pres0;
                out[(i - 1) * 2 + 1] = pres1;
            }
        }
    }
    __syncthreads();
    if (t >= 576) {   // final step's fc (h_40 in buffer 0)
        int lane = t - 576;
        const float* hsrc = s_hf[0];
        float p0 = 0.0f, p1 = 0.0f;
#pragma unroll
        for (int j = 0; j < 3; ++j) {
            int m = lane + 64 * j;
            if (m < G3) { float h = hsrc[m]; p0 += h * fw0[j]; p1 += h * fw1[j]; }
        }
#pragma unroll
        for (int off = 32; off > 0; off >>= 1) {
            p0 += __shfl_down(p0, off);
            p1 += __shfl_down(p1, off);
        }
        if (lane == 0) {
            pres0 += p0 + fcb0; pres1 += p1 + fcb1;
            out[39 * 2 + 0] = pres0;
            out[39 * 2 + 1] = pres1;
        }
    }
}

extern "C" void kernel_launch(void* const* d_in, const int* in_sizes, int n_in,
                              void* d_out, int out_size, void* d_ws, size_t ws_size,
                              hipStream_t stream) {
    (void)in_sizes; (void)n_in; (void)out_size; (void)ws_size;
    const float* past   = (const float*)d_in[0];
    const float* future = (const float*)d_in[1];
    const float* x      = (const float*)d_in[2];
    const int*   ei     = (const int*)d_in[3];
    const float* ew     = (const float*)d_in[4];
    const float* cpw    = (const float*)d_in[5];
    const float* cpb    = (const float*)d_in[6];
    const float* cfw    = (const float*)d_in[7];
    const float* cfb    = (const float*)d_in[8];
    const float* epWih  = (const float*)d_in[9];
    const float* epWhh  = (const float*)d_in[10];
    const float* epbih  = (const float*)d_in[11];
    const float* epbhh  = (const float*)d_in[12];
    const float* efWih  = (const float*)d_in[13];
    const float* efWhh  = (const float*)d_in[14];
    const float* efbih  = (const float*)d_in[15];
    const float* efbhh  = (const float*)d_in[16];
    const float* dWih   = (const float*)d_in[17];
    const float* dWhh   = (const float*)d_in[18];
    const float* dbih   = (const float*)d_in[19];
    const float* dbhh   = (const float*)d_in[20];
    const float* fcw    = (const float*)d_in[21];
    const float* fcb    = (const float*)d_in[22];
    const float* g1w    = (const float*)d_in[23];
    const float* g1b    = (const float*)d_in[24];
    const float* g2w    = (const float*)d_in[25];
    const float* g2b    = (const float*)d_in[26];

    char* ws = (char*)d_ws;
    int*      mark1 = (int*)(ws + OFF_MARK1);
    int*      mark2 = (int*)(ws + OFF_MARK2);
    unsigned* cnt   = (unsigned*)(ws + OFF_CNT);
    int*      l1r   = (int*)(ws + OFF_L1R);
    float*    l1w   = (float*)(ws + OFF_L1W);
    int*      s1g   = (int*)(ws + OFF_S1G);
    int*      e2r   = (int*)(ws + OFF_E2R);
    int*      e2s   = (int*)(ws + OFF_E2S);
    float*    e2w   = (float*)(ws + OFF_E2W);
    int*      s2    = (int*)(ws + OFF_S2);
    float*    deg2  = (float*)(ws + OFF_DEG2);
    float*    state = (float*)(ws + OFF_STATE);
    float*    x1    = (float*)(ws + OFF_X1);
    float*    tpsf  = (float*)(ws + OFF_TPSF);
    _Float16* whh16 = (_Float16*)(ws + OFF_WHH16);
    float*    gi0p  = (float*)(ws + OFF_GI0P);
    float*    giP   = (float*)(ws + OFF_GIP);
    float*    giF   = (float*)(ws + OFF_GIF);

    hipMemsetAsync(ws, 0, 524352, stream);  // mark1 | mark2 | cnt
    k_edges1<<<NE / 4 / 256 + PREPB, 256, 0, stream>>>(
        ei, ew, mark1, cnt, l1r, l1w,
        past, future, cpw, cpb, cfw, cfb,
        epWih, epbih, efWih, efbih, giP, giF);
    k_compact1<<<NN / 256, 256, 0, stream>>>(mark1, mark2, cnt, e2r, e2s, e2w, s1g, x1, g1b);
    k_edges2<<<NE / 4 / 256, 256, 0, stream>>>(ei, ew, mark1, mark2, cnt, e2r, e2s, e2w);
    k_compact2<<<NN / 256, 256, 0, stream>>>(mark2, cnt, s2, deg2);
    k_gru<<<DEGB + 2 + 512, 192, 0, stream>>>(x, cpw, cpb, epWih, epWhh, epbih, epbhh,
                                              efWhh, efbhh, giP, giF,
                                              ei, ew, mark2, deg2,
                                              s2, cnt, state, tpsf);
    k_acc1<<<64 + 128, 256, 0, stream>>>(cnt, e2r, e2s, e2w, mark2, deg2, s1g,
                                         state, g1w, x1,
                                         dWhh, dWih, dbih, tpsf, whh16, gi0p);
    k_dec<<<1, 640, 0, stream>>>(cnt, l1r, l1w, mark1, mark2, deg2, x1, g2w, g2b,
                                 tpsf, past, dWih, whh16, gi0p, dbih, dbhh, fcw, fcb,
                                 (float*)d_out);
}

// Round 8
// 217.389 us; speedup vs baseline: 1.1728x; 1.0338x over previous
//
#include <hip/hip_runtime.h>
#include <math.h>

#define NN 65536
#define NE 1048576
#define KH 48
#define G3 144
#define DEGB 512
#define PREPB 15
#define STAGEB 83

#define CAP_L1 8192
#define CAP_S1 4096
#define CAP_E2 65536
#define CAP_S2 8192

// ws byte offsets. First 524352 bytes (mark1|mark2|cnt) are zeroed by one
// hipMemsetAsync in kernel_launch.
#define OFF_MARK1  0u        // NN i32
#define OFF_MARK2  262144u   // NN i32
#define OFF_CNT    524288u   // 16 u32
#define OFF_L1R    524352u   // CAP_L1 i32
#define OFF_L1W    557120u   // CAP_L1 f32
#define OFF_S1G    589888u   // CAP_S1 i32
#define OFF_E2R    606272u   // CAP_E2 i32
#define OFF_E2S    868416u   // CAP_E2 i32
#define OFF_E2W    1130560u  // CAP_E2 f32
#define OFF_S2     1392704u  // CAP_S2 i32
#define OFF_DEG2   1425472u  // CAP_S2 f32
#define OFF_STATE  1458240u  // CAP_S2*48 f32
#define OFF_X1     3031104u  // CAP_S1*48 f32
#define OFF_TPSF   3817536u  // 128 f32
#define OFF_WHH16  3818048u  // paired fp16 dWhh: 14*576*2 h4 = 129024 B
#define OFF_GI0P   3947072u  // 432 f32
#define OFF_GIP    3948800u  // 20*144 f32
#define OFF_GIF    3960320u  // 40*144 f32
#define OFF_DWH4   3983360u  // 9*576 float4 (f32 dWih[:, :48] re-layout) = 82944 B

typedef _Float16 h2_t __attribute__((ext_vector_type(2)));
typedef _Float16 h4_t __attribute__((ext_vector_type(4)));
typedef _Float16 h8_t __attribute__((ext_vector_type(8)));

// fast gates: v_exp_f32-based; error ~1e-6 rel, negligible vs fp16 weights
__device__ __forceinline__ float sigmf(float x) { return 1.0f / (1.0f + __expf(-x)); }
__device__ __forceinline__ float tanhfast(float x) {
    float e = __expf(2.0f * x);
    return 1.0f - 2.0f / (e + 1.0f);
}

#if __has_builtin(__builtin_amdgcn_fdot2)
__device__ __forceinline__ float fdot2f(h2_t a, h2_t b, float c) {
    return __builtin_amdgcn_fdot2(a, b, c, false);
}
#else
__device__ __forceinline__ float fdot2f(h2_t a, h2_t b, float c) {
    return c + (float)a.x * (float)b.x + (float)a.y * (float)b.y;
}
#endif

// ---------------- K1: edges into node 0 + encoder-gi prep ------------------
__global__ void k_edges1(const int* ei, const float* ew,
                         int* mark1, unsigned* cnt, int* l1r, float* l1w,
                         const float* past, const float* future,
                         const float* cpw, const float* cpb,
                         const float* cfw, const float* cfb,
                         const float* epWih, const float* epbih,
                         const float* efWih, const float* efbih,
                         float* giP, float* giF) {
    if (blockIdx.x >= NE / 4 / 256) {
        int p = blockIdx.x - NE / 4 / 256;   // 0..14
        const float* xs; const float* cw; const float* cb;
        const float* Wih; const float* bih; float* gout;
        int T, s0;
        if (p < 5) { xs = past;   cw = cpw; cb = cpb; Wih = epWih; bih = epbih;
                     gout = giP; T = 20; s0 = p * 4; }
        else       { xs = future; cw = cfw; cb = cfb; Wih = efWih; bih = efbih;
                     gout = giF; T = 40; s0 = (p - 5) * 4; }
        __shared__ __align__(16) float s_x[80];
        __shared__ __align__(16) float s_e[4 * KH];
        int t = threadIdx.x;
        if (t < T * 2) s_x[t] = xs[t];
        __syncthreads();
        for (int idx = t; idx < 4 * KH; idx += 256) {
            int lt = idx / KH;
            int k = idx - lt * KH;
            int tt = s0 + lt;
            float acc = cb[k];
#pragma unroll
            for (int d = 0; d < 3; ++d) {
                int tau = tt + d - 1;
                if (tau >= 0 && tau < T) {
                    acc += cw[k * 6 + d] * s_x[tau * 2 + 0];
                    acc += cw[k * 6 + 3 + d] * s_x[tau * 2 + 1];
                }
            }
            s_e[lt * KH + k] = fmaxf(acc, 0.0f);
        }
        __syncthreads();
        for (int idx = t; idx < 4 * G3; idx += 256) {
            int lt = idx / G3;
            int row = idx - lt * G3;
            const float4* wp = reinterpret_cast<const float4*>(Wih + row * KH);
            const float4* em = reinterpret_cast<const float4*>(s_e + lt * KH);
            float g = bih[row];
#pragma unroll
            for (int j = 0; j < 12; ++j) {
                float4 w4 = wp[j]; float4 e4 = em[j];
                g += w4.x * e4.x + w4.y * e4.y + w4.z * e4.z + w4.w * e4.w;
            }
            gout[(s0 + lt) * G3 + row] = g;
        }
        return;
    }
    int q = blockIdx.x * blockDim.x + threadIdx.x;
    if (q >= NE / 4) return;
    if (q == 0) mark1[0] = 1;   // node 0 always in S1
    int4 c4 = reinterpret_cast<const int4*>(ei + NE)[q];
    int e = q * 4;
    int cc[4] = {c4.x, c4.y, c4.z, c4.w};
#pragma unroll
    for (int j = 0; j < 4; ++j) {
        if (cc[j] == 0) {
            int r = ei[e + j];
            float w = ew[e + j];
            unsigned s = atomicAdd(&cnt[0], 1u);
            if (s < CAP_L1) { l1r[s] = r; l1w[s] = w; }
            mark1[r] = 1;
        }
    }
}

// ---------------- K2: compact S1; emit self-loop E2 entries; init x1 -------
__global__ void k_compact1(int* mark1, int* mark2, unsigned* cnt,
                           int* e2r, int* e2s, float* e2w, int* s1g,
                           float* x1, const float* g1b) {
    int i = blockIdx.x * blockDim.x + threadIdx.x;
    if (i >= NN) return;
    if (mark1[i]) {
        unsigned s = atomicAdd(&cnt[1], 1u);
        if (s < CAP_S1) {
            mark1[i] = (int)s + 1;
            mark2[i] = 1;               // needs GRU state (self loop row)
            s1g[s] = i;
            unsigned t = atomicAdd(&cnt[2], 1u);
            if (t < CAP_E2) { e2r[t] = i; e2s[t] = (int)s; e2w[t] = 1.0f; }
            for (int k = 0; k < KH; ++k) x1[s * KH + k] = g1b[k];
        } else {
            mark1[i] = 0;
        }
    }
}

// ---------------- K3: collect edges into S1 (4 edges/thread) ---------------
__global__ void k_edges2(const int* ei, const float* ew,
                         const int* mark1, int* mark2, unsigned* cnt,
                         int* e2r, int* e2s, float* e2w) {
    int q = blockIdx.x * blockDim.x + threadIdx.x;
    if (q >= NE / 4) return;
    int4 c4 = reinterpret_cast<const int4*>(ei + NE)[q];
    int e = q * 4;
    int cc[4] = {c4.x, c4.y, c4.z, c4.w};
#pragma unroll
    for (int j = 0; j < 4; ++j) {
        int m = mark1[cc[j]];
        if (m > 0) {
            int r = ei[e + j];
            float w = ew[e + j];
            unsigned s = atomicAdd(&cnt[2], 1u);
            if (s < CAP_E2) { e2r[s] = r; e2s[s] = m - 1; e2w[s] = w; }
            mark2[r] = 1;
        }
    }
}

// ---------------- K4: compact S2; init compact degree ----------------------
__global__ void k_compact2(int* mark2, unsigned* cnt, int* s2, float* deg2) {
    int i = blockIdx.x * blockDim.x + threadIdx.x;
    if (i >= NN) return;
    if (mark2[i]) {
        unsigned s = atomicAdd(&cnt[3], 1u);
        if (s < CAP_S2) { s2[s] = i; mark2[i] = (int)s + 1; deg2[s] = 1.0f; }
        else mark2[i] = 0;
    }
}

// ---------------- conv1d(pad=1,k=3) + GRU over one sequence (S2 path) ------
__device__ void gru_seq(const float* xseq, int T,
                        const float* cw, const float* cb,
                        const float* Wih, const float* Whh,
                        const float* bih, const float* bhh,
                        float* out48,
                        float* s_x, float* s_embed, float* s_giA,
                        float* s_h /* [2][KH] */) {
    int t = threadIdx.x;
    int nt = blockDim.x;
    for (int i = t; i < T * 2; i += nt) s_x[i] = xseq[i];
    __syncthreads();
    for (int idx = t; idx < T * KH; idx += nt) {
        int tt = idx / KH;
        int k = idx - tt * KH;
        float acc = cb[k];
#pragma unroll
        for (int d = 0; d < 3; ++d) {
            int tau = tt + d - 1;
            if (tau >= 0 && tau < T) {
                acc += cw[k * 6 + d] * s_x[tau * 2 + 0];
                acc += cw[k * 6 + 3 + d] * s_x[tau * 2 + 1];
            }
        }
        s_embed[tt * KH + k] = fmaxf(acc, 0.0f);
    }
    __syncthreads();
    for (int idx = t; idx < T * G3; idx += nt) {
        int step = idx / G3;
        int row = idx - step * G3;
        const float4* wp = reinterpret_cast<const float4*>(Wih + row * KH);
        const float4* em = reinterpret_cast<const float4*>(s_embed + step * KH);
        float g = bih[row];
#pragma unroll
        for (int j = 0; j < 12; ++j) {
            float4 w4 = wp[j]; float4 e4 = em[j];
            g += w4.x * e4.x + w4.y * e4.y + w4.z * e4.z + w4.w * e4.w;
        }
        s_giA[idx] = g;
    }
    int k = t >> 1, hf = t & 1;
    float4 wr[18];
    float bh0 = 0.0f, bh1 = 0.0f, bh2 = 0.0f;
    if (t < 96) {
#pragma unroll
        for (int g = 0; g < 3; ++g) {
            const float4* q = reinterpret_cast<const float4*>(
                Whh + (g * KH + k) * KH + hf * 24);
#pragma unroll
            for (int j = 0; j < 6; ++j) wr[g * 6 + j] = q[j];
        }
        if (hf == 0) { bh0 = bhh[k]; bh1 = bhh[KH + k]; bh2 = bhh[2 * KH + k]; }
    }
    if (t < KH) s_h[t] = 0.0f;   // buffer 0
    float hk = 0.0f;
    for (int step = 0; step < T; ++step) {
        __syncthreads();
        int cur = step & 1, nxt = cur ^ 1;
        if (t < 96) {
            const float4* hp = reinterpret_cast<const float4*>(s_h + cur * KH)
                               + hf * 6;
            float a0 = bh0, a1 = bh1, a2 = bh2;
#pragma unroll
            for (int j = 0; j < 6; ++j) {
                float4 hv = hp[j];
                float4 w0 = wr[j], w1 = wr[6 + j], w2 = wr[12 + j];
                a0 += w0.x * hv.x + w0.y * hv.y + w0.z * hv.z + w0.w * hv.w;
                a1 += w1.x * hv.x + w1.y * hv.y + w1.z * hv.z + w1.w * hv.w;
                a2 += w2.x * hv.x + w2.y * hv.y + w2.z * hv.z + w2.w * hv.w;
            }
            a0 += __shfl_xor(a0, 1);
            a1 += __shfl_xor(a1, 1);
            a2 += __shfl_xor(a2, 1);
            if (hf == 0) {
                const float* gi = s_giA + step * G3;
                float r = sigmf(gi[k] + a0);
                float z = sigmf(gi[KH + k] + a1);
                float n = tanhfast(gi[2 * KH + k] + r * a2);
                hk = (1.0f - z) * n + z * hk;
                s_h[nxt * KH + k] = hk;
            }
        }
    }
    __syncthreads();
    if (t < KH) out48[t] = s_h[(T & 1) * KH + t];
}

// -------- recurrent-only GRU (gi precomputed in ws by k_edges1 prep) -------
__device__ void gru_rec(const float* giA /* [T][G3] global */, int T,
                        const float* Whh, const float* bhh,
                        float* out48, float* s_h /* [2][KH] */) {
    int t = threadIdx.x;
    int k = t >> 1, hf = t & 1;
    float4 wr[18];
    float bh0 = 0.0f, bh1 = 0.0f, bh2 = 0.0f;
    if (t < 96) {
#pragma unroll
        for (int g = 0; g < 3; ++g) {
            const float4* q = reinterpret_cast<const float4*>(
                Whh + (g * KH + k) * KH + hf * 24);
#pragma unroll
            for (int j = 0; j < 6; ++j) wr[g * 6 + j] = q[j];
        }
        if (hf == 0) { bh0 = bhh[k]; bh1 = bhh[KH + k]; bh2 = bhh[2 * KH + k]; }
    }
    if (t < KH) s_h[t] = 0.0f;
    float hk = 0.0f;
    for (int step = 0; step < T; ++step) {
        __syncthreads();
        int cur = step & 1, nxt = cur ^ 1;
        if (t < 96) {
            const float4* hp = reinterpret_cast<const float4*>(s_h + cur * KH)
                               + hf * 6;
            float a0 = bh0, a1 = bh1, a2 = bh2;
#pragma unroll
            for (int j = 0; j < 6; ++j) {
                float4 hv = hp[j];
                float4 w0 = wr[j], w1 = wr[6 + j], w2 = wr[12 + j];
                a0 += w0.x * hv.x + w0.y * hv.y + w0.z * hv.z + w0.w * hv.w;
                a1 += w1.x * hv.x + w1.y * hv.y + w1.z * hv.z + w1.w * hv.w;
                a2 += w2.x * hv.x + w2.y * hv.y + w2.z * hv.z + w2.w * hv.w;
            }
            a0 += __shfl_xor(a0, 1);
            a1 += __shfl_xor(a1, 1);
            a2 += __shfl_xor(a2, 1);
            if (hf == 0) {
                const float* gi = giA + step * G3;
                float r = sigmf(gi[k] + a0);
                float z = sigmf(gi[KH + k] + a1);
                float n = tanhfast(gi[2 * KH + k] + r * a2);
                hk = (1.0f - z) * n + z * hk;
                s_h[nxt * KH + k] = hk;
            }
        }
    }
    __syncthreads();
    if (t < KH) out48[t] = s_h[(T & 1) * KH + t];
}

// ---------------- K5: deg scan + all GRUs ----------------------------------
__global__ __launch_bounds__(192, 2) void k_gru(
    const float* x, const float* cpw, const float* cpb,
    const float* epWih, const float* epWhh, const float* epbih, const float* epbhh,
    const float* efWhh, const float* efbhh,
    const float* giP, const float* giF,
    const int* ei, const float* ew, const int* mark2, float* deg2,
    const int* s2, const unsigned* cnt, float* state, float* tpsf) {
    if (blockIdx.x < DEGB) {
        int per = NE / DEGB;
        int lo = blockIdx.x * per;
        for (int e = lo + threadIdx.x; e < lo + per; e += blockDim.x) {
            int c = ei[NE + e];
            int m = mark2[c];
            if (m > 0) atomicAdd(&deg2[m - 1], ew[e]);
        }
        return;
    }
    __shared__ __align__(16) float s_x[80];
    __shared__ __align__(16) float s_embed[40 * KH];
    __shared__ __align__(16) float s_giA[40 * G3];
    __shared__ __align__(16) float s_h[2 * KH];
    if (blockIdx.x == DEGB) {
        gru_rec(giP, 20, epWhh, epbhh, tpsf, s_h);
        return;
    }
    if (blockIdx.x == DEGB + 1) {
        gru_rec(giF, 40, efWhh, efbhh, tpsf + 64, s_h);
        return;
    }
    int b0 = blockIdx.x - (DEGB + 2);
    int nw = gridDim.x - (DEGB + 2);
    int cnt2 = (int)min(cnt[3], (unsigned)CAP_S2);
    for (int b = b0; b < cnt2; b += nw) {
        int node = s2[b];
        gru_seq(x + (size_t)node * 40, 20, cpw, cpb, epWih, epWhh, epbih, epbhh,
                state + (size_t)b * KH, s_x, s_embed, s_giA, s_h);
    }
}

// ---------------- K6: staging (blocks 0..82) + GCN layer 1 edge acc --------
// Staging ids:
//   [0, 15552)        : dWhh -> fp16 PAIRED layout: h4 for (c,t) at h4-index
//                       ((c>>1)*576 + t)*2 + (c&1); k_dec loads h8 (16B) per
//                       c-pair -> 13x16B + 1x8B coalesced, deep-MLP.
//   [15552, 20736)    : dWih[:, :48] f32 re-layout: float4 for (c=g*3+j, t) at
//                       index c*576+t = dWih[(g*144+k)*144 + q*12 + 4j ..+3].
//   [20736, 21168)    : gi0p[row] = dWih[row][48:144] @ [tp;sf] + dbih.
__global__ void k_acc1(const unsigned* cnt, const int* e2r, const int* e2s,
                       const float* e2w, const int* mark2, const float* deg2,
                       const int* s1g, const float* state,
                       const float* W1, float* x1,
                       const float* dWhh, const float* dWih,
                       const float* dbih, const float* tpsf,
                       _Float16* whh16, float* dwh4, float* gi0p) {
    if (blockIdx.x < STAGEB) {
        int id = blockIdx.x * blockDim.x + threadIdx.x;
        if (id < 27 * 576) {
            int c = id / 576, t = id - c * 576;
            int k = t >> 2, q = t & 3;
            int g = c / 9, u = c - g * 9;
            const float* src = dWhh + (size_t)(g * G3 + k) * G3 + q * 36 + 4 * u;
            float4 f = *reinterpret_cast<const float4*>(src);
            h2_t a, b;
            a.x = (_Float16)f.x; a.y = (_Float16)f.y;
            b.x = (_Float16)f.z; b.y = (_Float16)f.w;
            int pid = ((c >> 1) * 576 + t) * 2 + (c & 1);
            h2_t* o = reinterpret_cast<h2_t*>(whh16);
            o[2 * pid + 0] = a;
            o[2 * pid + 1] = b;
            return;
        }
        if (id < 27 * 576 + 9 * 576) {
            int id2 = id - 27 * 576;
            int c = id2 / 576, t = id2 - c * 576;
            int k = t >> 2, q = t & 3;
            int g = c / 3, j = c - g * 3;
            const float* src = dWih + (size_t)(g * G3 + k) * G3 + q * 12 + 4 * j;
            reinterpret_cast<float4*>(dwh4)[id2] =
                *reinterpret_cast<const float4*>(src);
            return;
        }
        int row = id - (27 * 576 + 9 * 576);
        if (row < 432) {
            const float* wr = dWih + (size_t)row * G3;
            float acc = dbih[row];
#pragma unroll
            for (int m = 0; m < 48; ++m) acc += wr[48 + m] * tpsf[m];
#pragma unroll
            for (int m = 0; m < 48; ++m) acc += wr[96 + m] * tpsf[64 + m];
            gi0p[row] = acc;
        }
        return;
    }
    int nE = (int)min(cnt[2], (unsigned)CAP_E2);
    int total = nE * KH;
    int stride = (gridDim.x - STAGEB) * blockDim.x;
    for (int idx = (blockIdx.x - STAGEB) * blockDim.x + threadIdx.x; idx < total;
         idx += stride) {
        int e = idx / KH;
        int k = idx - e * KH;
        int row = e2r[e];
        int s2i = mark2[row] - 1;
        if (s2i < 0) continue;
        int cglob = s1g[e2s[e]];
        int cs2 = mark2[cglob] - 1;
        float norm = e2w[e] * rsqrtf(deg2[s2i] * deg2[cs2]);
        const float* sp = state + (size_t)s2i * KH;
        const float* wp = W1 + k * KH;
        float acc = 0.0f;
#pragma unroll
        for (int m = 0; m < KH; ++m) acc += sp[m] * wp[m];
        atomicAdd(&x1[e2s[e] * KH + k], acc * norm);
    }
}

// ---------------- K7: GCN layer 2 @ node 0 + decoder -----------------------
__global__ __launch_bounds__(640, 1) void k_dec(
    const unsigned* cnt, const int* l1r, const float* l1w,
    const int* mark1, const int* mark2, const float* deg2, const float* x1,
    const float* W2, const float* b2, const float* tpsf, const float* past,
    const _Float16* whh16, const float* dwh4, const float* gi0p,
    const float* dbih, const float* dbhh,
    const float* fcw, const float* fcb, float* out) {
    __shared__ __align__(16) float s_conc[G3];
    __shared__ __align__(16) _Float16 s_h16[2][G3];   // fp16 h, double-buffered
    __shared__ __align__(16) float s_hf[2][G3];       // f32 h for fc
    int t = threadIdx.x;
    if (t < 48) s_conc[t] = b2[t];
    else if (t < 96) s_conc[t] = tpsf[t - 48];
    else if (t < 144) s_conc[t] = tpsf[64 + t - 96];
    if (t < G3) {
        s_h16[0][t] = (_Float16)0.0f;
        s_hf[0][t] = 0.0f;
    }
    __syncthreads();
    // layer-2 message accumulation into s_conc[0..47]
    int cl1 = (int)min(cnt[0], (unsigned)CAP_L1);
    float dinv0 = rsqrtf(deg2[mark2[0] - 1]);
    int items = (cl1 + 1) * KH;
    for (int idx = t; idx < items; idx += blockDim.x) {
        int e = idx / KH;
        int k = idx - e * KH;
        int row; float norm;
        if (e == cl1) { row = 0; norm = dinv0 * dinv0; }
        else {
            row = l1r[e];
            int rs2 = mark2[row] - 1;
            if (rs2 < 0) continue;
            norm = l1w[e] * rsqrtf(deg2[rs2]) * dinv0;
        }
        int s1 = mark1[row] - 1;
        if (s1 < 0) continue;
        const float* xp = x1 + (size_t)s1 * KH;
        const float* wp = W2 + k * KH;
        float acc = 0.0f;
#pragma unroll
        for (int m = 0; m < KH; ++m) acc += fmaxf(xp[m], 0.0f) * wp[m];
        atomicAdd(&s_conc[k], acc * norm);
    }
    // decoder weight load: 13 x 16B + 1 x 8B coalesced from paired buffer.
    int k = t >> 2, q = t & 3;
    h2_t wh[54];
    float bh[3] = {0.0f, 0.0f, 0.0f};
    float bi[3] = {0.0f, 0.0f, 0.0f};
    if (t < 576) {
        const h8_t* wp8 = reinterpret_cast<const h8_t*>(whh16);
#pragma unroll
        for (int c2 = 0; c2 < 13; ++c2) {
            h8_t v = wp8[c2 * 576 + t];
            int c0 = 2 * c2, c1 = 2 * c2 + 1;
            int g0 = c0 / 9, u0 = c0 - g0 * 9;
            int g1 = c1 / 9, u1 = c1 - g1 * 9;
            wh[g0 * 18 + 2 * u0]     = __builtin_shufflevector(v, v, 0, 1);
            wh[g0 * 18 + 2 * u0 + 1] = __builtin_shufflevector(v, v, 2, 3);
            wh[g1 * 18 + 2 * u1]     = __builtin_shufflevector(v, v, 4, 5);
            wh[g1 * 18 + 2 * u1 + 1] = __builtin_shufflevector(v, v, 6, 7);
        }
        const h4_t* wp4 = reinterpret_cast<const h4_t*>(whh16);
        h4_t v26 = wp4[(13 * 576 + t) * 2];   // c=26 -> g=2,u=8
        wh[2 * 18 + 2 * 8]     = __builtin_shufflevector(v26, v26, 0, 1);
        wh[2 * 18 + 2 * 8 + 1] = __builtin_shufflevector(v26, v26, 2, 3);
        if (q == 0) {
#pragma unroll
            for (int g = 0; g < 3; ++g) {
                bh[g] = dbhh[g * G3 + k];
                bi[g] = dbih[g * G3 + k];
            }
        }
    }
    // fc wave preload (wave 9)
    float fw0[3] = {0, 0, 0}, fw1[3] = {0, 0, 0};
    float fcb0 = 0.0f, fcb1 = 0.0f, pres0 = 0.0f, pres1 = 0.0f;
    if (t >= 576) {
        int lane = t - 576;
#pragma unroll
        for (int j = 0; j < 3; ++j) {
            int m = lane + 64 * j;
            if (m < G3) { fw0[j] = fcw[m]; fw1[j] = fcw[G3 + m]; }
        }
        if (lane == 0) {
            fcb0 = fcb[0]; fcb1 = fcb[1];
            pres0 = past[38]; pres1 = past[39];
        }
    }
    __syncthreads();   // s_conc complete
    // gi0 head: cols [q*12, q*12+12) x 3 gates from staged dwh4 (all lanes)
    float gi0[3] = {0.0f, 0.0f, 0.0f};
    if (t < 576) {
        const float4* dp = reinterpret_cast<const float4*>(dwh4);
        const float4* cc = reinterpret_cast<const float4*>(s_conc) + q * 3;
        float4 c0 = cc[0], c1 = cc[1], c2v = cc[2];
#pragma unroll
        for (int g = 0; g < 3; ++g) {
            float4 w0 = dp[(g * 3 + 0) * 576 + t];
            float4 w1 = dp[(g * 3 + 1) * 576 + t];
            float4 w2 = dp[(g * 3 + 2) * 576 + t];
            float acc = w0.x * c0.x + w0.y * c0.y + w0.z * c0.z + w0.w * c0.w;
            acc += w1.x * c1.x + w1.y * c1.y + w1.z * c1.z + w1.w * c1.w;
            acc += w2.x * c2v.x + w2.y * c2v.y + w2.z * c2v.z + w2.w * c2v.w;
            acc += __shfl_xor(acc, 1);
            acc += __shfl_xor(acc, 2);
            gi0[g] = acc + gi0p[g * G3 + k];
        }
    }
    float hk = 0.0f;   // h[k] carried in f32 (q==0 lanes)
    for (int i = 0; i < 40; ++i) {
        __syncthreads();
        int cur = i & 1, nxt = cur ^ 1;
        if (t < 576) {
            const h4_t* hp = reinterpret_cast<const h4_t*>(&s_h16[cur][0]) + q * 9;
            float a0 = bh[0], a1 = bh[1], a2 = bh[2];
#pragma unroll
            for (int j = 0; j < 9; ++j) {
                h4_t hv = hp[j];
                h2_t lo = __builtin_shufflevector(hv, hv, 0, 1);
                h2_t hi = __builtin_shufflevector(hv, hv, 2, 3);
                a0 = fdot2f(wh[2 * j], lo, a0);
                a1 = fdot2f(wh[18 + 2 * j], lo, a1);
                a2 = fdot2f(wh[36 + 2 * j], lo, a2);
                a0 = fdot2f(wh[2 * j + 1], hi, a0);
                a1 = fdot2f(wh[18 + 2 * j + 1], hi, a1);
                a2 = fdot2f(wh[36 + 2 * j + 1], hi, a2);
            }
            a0 += __shfl_xor(a0, 1); a0 += __shfl_xor(a0, 2);
            a1 += __shfl_xor(a1, 1); a1 += __shfl_xor(a1, 2);
            a2 += __shfl_xor(a2, 1); a2 += __shfl_xor(a2, 2);
            if (q == 0) {
                float gr = ((i == 0) ? gi0[0] : bi[0]) + a0;
                float gz = ((i == 0) ? gi0[1] : bi[1]) + a1;
                float gn = ((i == 0) ? gi0[2] : bi[2]);
                float r = sigmf(gr);
                float z = sigmf(gz);
                float n = tanhfast(gn + r * a2);
                hk = (1.0f - z) * n + z * hk;
                s_h16[nxt][k] = (_Float16)hk;
                s_hf[nxt][k] = hk;
            }
        } else if (i >= 1) {
            int lane = t - 576;
            const float* hsrc = s_hf[cur];
            float p0 = 0.0f, p1 = 0.0f;
#pragma unroll
            for (int j = 0; j < 3; ++j) {
                int m = lane + 64 * j;
                if (m < G3) { float h = hsrc[m]; p0 += h * fw0[j]; p1 += h * fw1[j]; }
            }
#pragma unroll
            for (int off = 32; off > 0; off >>= 1) {
                p0 += __shfl_down(p0, off);
                p1 += __shfl_down(p1, off);
            }
            if (lane == 0) {
                pres0 += p0 + fcb0; pres1 += p1 + fcb1;
                out[(i - 1) * 2 + 0] = pres0;
                out[(i - 1) * 2 + 1] = pres1;
            }
        }
    }
    __syncthreads();
    if (t >= 576) {   // final step's fc (h_40 in buffer 0)
        int lane = t - 576;
        const float* hsrc = s_hf[0];
        float p0 = 0.0f, p1 = 0.0f;
#pragma unroll
        for (int j = 0; j < 3; ++j) {
            int m = lane + 64 * j;
            if (m < G3) { float h = hsrc[m]; p0 += h * fw0[j]; p1 += h * fw1[j]; }
        }
#pragma unroll
        for (int off = 32; off > 0; off >>= 1) {
            p0 += __shfl_down(p0, off);
            p1 += __shfl_down(p1, off);
        }
        if (lane == 0) {
            pres0 += p0 + fcb0; pres1 += p1 + fcb1;
            out[39 * 2 + 0] = pres0;
            out[39 * 2 + 1] = pres1;
        }
    }
}

extern "C" void kernel_launch(void* const* d_in, const int* in_sizes, int n_in,
                              void* d_out, int out_size, void* d_ws, size_t ws_size,
                              hipStream_t stream) {
    (void)in_sizes; (void)n_in; (void)out_size; (void)ws_size;
    const float* past   = (const float*)d_in[0];
    const float* future = (const float*)d_in[1];
    const float* x      = (const float*)d_in[2];
    const int*   ei     = (const int*)d_in[3];
    const float* ew     = (const float*)d_in[4];
    const float* cpw    = (const float*)d_in[5];
    const float* cpb    = (const float*)d_in[6];
    const float* cfw    = (const float*)d_in[7];
    const float* cfb    = (const float*)d_in[8];
    const float* epWih  = (const float*)d_in[9];
    const float* epWhh  = (const float*)d_in[10];
    const float* epbih  = (const float*)d_in[11];
    const float* epbhh  = (const float*)d_in[12];
    const float* efWih  = (const float*)d_in[13];
    const float* efWhh  = (const float*)d_in[14];
    const float* efbih  = (const float*)d_in[15];
    const float* efbhh  = (const float*)d_in[16];
    const float* dWih   = (const float*)d_in[17];
    const float* dWhh   = (const float*)d_in[18];
    const float* dbih   = (const float*)d_in[19];
    const float* dbhh   = (const float*)d_in[20];
    const float* fcw    = (const float*)d_in[21];
    const float* fcb    = (const float*)d_in[22];
    const float* g1w    = (const float*)d_in[23];
    const float* g1b    = (const float*)d_in[24];
    const float* g2w    = (const float*)d_in[25];
    const float* g2b    = (const float*)d_in[26];

    char* ws = (char*)d_ws;
    int*      mark1 = (int*)(ws + OFF_MARK1);
    int*      mark2 = (int*)(ws + OFF_MARK2);
    unsigned* cnt   = (unsigned*)(ws + OFF_CNT);
    int*      l1r   = (int*)(ws + OFF_L1R);
    float*    l1w   = (float*)(ws + OFF_L1W);
    int*      s1g   = (int*)(ws + OFF_S1G);
    int*      e2r   = (int*)(ws + OFF_E2R);
    int*      e2s   = (int*)(ws + OFF_E2S);
    float*    e2w   = (float*)(ws + OFF_E2W);
    int*      s2    = (int*)(ws + OFF_S2);
    float*    deg2  = (float*)(ws + OFF_DEG2);
    float*    state = (float*)(ws + OFF_STATE);
    float*    x1    = (float*)(ws + OFF_X1);
    float*    tpsf  = (float*)(ws + OFF_TPSF);
    _Float16* whh16 = (_Float16*)(ws + OFF_WHH16);
    float*    gi0p  = (float*)(ws + OFF_GI0P);
    float*    giP   = (float*)(ws + OFF_GIP);
    float*    giF   = (float*)(ws + OFF_GIF);
    float*    dwh4  = (float*)(ws + OFF_DWH4);

    hipMemsetAsync(ws, 0, 524352, stream);  // mark1 | mark2 | cnt
    k_edges1<<<NE / 4 / 256 + PREPB, 256, 0, stream>>>(
        ei, ew, mark1, cnt, l1r, l1w,
        past, future, cpw, cpb, cfw, cfb,
        epWih, epbih, efWih, efbih, giP, giF);
    k_compact1<<<NN / 256, 256, 0, stream>>>(mark1, mark2, cnt, e2r, e2s, e2w, s1g, x1, g1b);
    k_edges2<<<NE / 4 / 256, 256, 0, stream>>>(ei, ew, mark1, mark2, cnt, e2r, e2s, e2w);
    k_compact2<<<NN / 256, 256, 0, stream>>>(mark2, cnt, s2, deg2);
    k_gru<<<DEGB + 2 + 512, 192, 0, stream>>>(x, cpw, cpb, epWih, epWhh, epbih, epbhh,
                                              efWhh, efbhh, giP, giF,
                                              ei, ew, mark2, deg2,
                                              s2, cnt, state, tpsf);
    k_acc1<<<STAGEB + 128, 256, 0, stream>>>(cnt, e2r, e2s, e2w, mark2, deg2, s1g,
                                             state, g1w, x1,
                                             dWhh, dWih, dbih, tpsf,
                                             whh16, dwh4, gi0p);
    k_dec<<<1, 640, 0, stream>>>(cnt, l1r, l1w, mark1, mark2, deg2, x1, g2w, g2b,
                                 tpsf, past, whh16, dwh4, gi0p, dbih, dbhh, fcw, fcb,
                                 (float*)d_out);
}

// Round 9
// 213.009 us; speedup vs baseline: 1.1969x; 1.0206x over previous
//
#include <hip/hip_runtime.h>
#include <math.h>

#define NN 65536
#define NE 1048576
#define KH 48
#define G3 144
#define DEGB 512
#define PREPB 15
#define STAGEB 83

#define CAP_L1 8192
#define CAP_S1 4096
#define CAP_E2 65536
#define CAP_S2 8192

// ws byte offsets. First 524352 bytes (mark1|mark2|cnt) are zeroed by one
// hipMemsetAsync in kernel_launch.
#define OFF_MARK1  0u        // NN i32
#define OFF_MARK2  262144u   // NN i32
#define OFF_CNT    524288u   // 16 u32
#define OFF_L1R    524352u   // CAP_L1 i32
#define OFF_L1W    557120u   // CAP_L1 f32
#define OFF_S1G    589888u   // CAP_S1 i32
#define OFF_E2R    606272u   // CAP_E2 i32
#define OFF_E2S    868416u   // CAP_E2 i32
#define OFF_E2W    1130560u  // CAP_E2 f32
#define OFF_S2     1392704u  // CAP_S2 i32
#define OFF_DEG2   1425472u  // CAP_S2 f32
#define OFF_STATE  1458240u  // CAP_S2*48 f32
#define OFF_X1     3031104u  // CAP_S1*48 f32
#define OFF_TPSF   3817536u  // 128 f32
#define OFF_WHH16  3818048u  // paired fp16 dWhh: 14*576*2 h4 = 129024 B
#define OFF_GI0P   3947072u  // 432 f32
#define OFF_GIP    3948800u  // 20*144 f32
#define OFF_GIF    3960320u  // 40*144 f32
#define OFF_DWH4   3983360u  // 9*576 float4 (f32 dWih[:, :48] re-layout) = 82944 B

typedef _Float16 h2_t __attribute__((ext_vector_type(2)));
typedef _Float16 h4_t __attribute__((ext_vector_type(4)));
typedef _Float16 h8_t __attribute__((ext_vector_type(8)));

// fast gates: v_exp_f32-based; error ~1e-6 rel, negligible vs fp16 weights
__device__ __forceinline__ float sigmf(float x) { return 1.0f / (1.0f + __expf(-x)); }
__device__ __forceinline__ float tanhfast(float x) {
    float e = __expf(2.0f * x);
    return 1.0f - 2.0f / (e + 1.0f);
}

#if __has_builtin(__builtin_amdgcn_fdot2)
__device__ __forceinline__ float fdot2f(h2_t a, h2_t b, float c) {
    return __builtin_amdgcn_fdot2(a, b, c, false);
}
#else
__device__ __forceinline__ float fdot2f(h2_t a, h2_t b, float c) {
    return c + (float)a.x * (float)b.x + (float)a.y * (float)b.y;
}
#endif

// ---------------- K1: edges into node 0 + encoder-gi prep ------------------
__global__ void k_edges1(const int* ei, const float* ew,
                         int* mark1, unsigned* cnt, int* l1r, float* l1w,
                         const float* past, const float* future,
                         const float* cpw, const float* cpb,
                         const float* cfw, const float* cfb,
                         const float* epWih, const float* epbih,
                         const float* efWih, const float* efbih,
                         float* giP, float* giF) {
    if (blockIdx.x >= NE / 4 / 256) {
        int p = blockIdx.x - NE / 4 / 256;   // 0..14
        const float* xs; const float* cw; const float* cb;
        const float* Wih; const float* bih; float* gout;
        int T, s0;
        if (p < 5) { xs = past;   cw = cpw; cb = cpb; Wih = epWih; bih = epbih;
                     gout = giP; T = 20; s0 = p * 4; }
        else       { xs = future; cw = cfw; cb = cfb; Wih = efWih; bih = efbih;
                     gout = giF; T = 40; s0 = (p - 5) * 4; }
        __shared__ __align__(16) float s_x[80];
        __shared__ __align__(16) float s_e[4 * KH];
        int t = threadIdx.x;
        if (t < T * 2) s_x[t] = xs[t];
        __syncthreads();
        for (int idx = t; idx < 4 * KH; idx += 256) {
            int lt = idx / KH;
            int k = idx - lt * KH;
            int tt = s0 + lt;
            float acc = cb[k];
#pragma unroll
            for (int d = 0; d < 3; ++d) {
                int tau = tt + d - 1;
                if (tau >= 0 && tau < T) {
                    acc += cw[k * 6 + d] * s_x[tau * 2 + 0];
                    acc += cw[k * 6 + 3 + d] * s_x[tau * 2 + 1];
                }
            }
            s_e[lt * KH + k] = fmaxf(acc, 0.0f);
        }
        __syncthreads();
        for (int idx = t; idx < 4 * G3; idx += 256) {
            int lt = idx / G3;
            int row = idx - lt * G3;
            const float4* wp = reinterpret_cast<const float4*>(Wih + row * KH);
            const float4* em = reinterpret_cast<const float4*>(s_e + lt * KH);
            float g = bih[row];
#pragma unroll
            for (int j = 0; j < 12; ++j) {
                float4 w4 = wp[j]; float4 e4 = em[j];
                g += w4.x * e4.x + w4.y * e4.y + w4.z * e4.z + w4.w * e4.w;
            }
            gout[(s0 + lt) * G3 + row] = g;
        }
        return;
    }
    int q = blockIdx.x * blockDim.x + threadIdx.x;
    if (q >= NE / 4) return;
    if (q == 0) mark1[0] = 1;   // node 0 always in S1
    int4 c4 = reinterpret_cast<const int4*>(ei + NE)[q];
    int e = q * 4;
    int cc[4] = {c4.x, c4.y, c4.z, c4.w};
#pragma unroll
    for (int j = 0; j < 4; ++j) {
        if (cc[j] == 0) {
            int r = ei[e + j];
            float w = ew[e + j];
            unsigned s = atomicAdd(&cnt[0], 1u);
            if (s < CAP_L1) { l1r[s] = r; l1w[s] = w; }
            mark1[r] = 1;
        }
    }
}

// ---------------- K2: compact S1; emit self-loop E2 entries; init x1 -------
__global__ void k_compact1(int* mark1, int* mark2, unsigned* cnt,
                           int* e2r, int* e2s, float* e2w, int* s1g,
                           float* x1, const float* g1b) {
    int i = blockIdx.x * blockDim.x + threadIdx.x;
    if (i >= NN) return;
    if (mark1[i]) {
        unsigned s = atomicAdd(&cnt[1], 1u);
        if (s < CAP_S1) {
            mark1[i] = (int)s + 1;
            mark2[i] = 1;               // needs GRU state (self loop row)
            s1g[s] = i;
            unsigned t = atomicAdd(&cnt[2], 1u);
            if (t < CAP_E2) { e2r[t] = i; e2s[t] = (int)s; e2w[t] = 1.0f; }
            for (int k = 0; k < KH; ++k) x1[s * KH + k] = g1b[k];
        } else {
            mark1[i] = 0;
        }
    }
}

// ---------------- K3: collect edges into S1 (4 edges/thread) ---------------
__global__ void k_edges2(const int* ei, const float* ew,
                         const int* mark1, int* mark2, unsigned* cnt,
                         int* e2r, int* e2s, float* e2w) {
    int q = blockIdx.x * blockDim.x + threadIdx.x;
    if (q >= NE / 4) return;
    int4 c4 = reinterpret_cast<const int4*>(ei + NE)[q];
    int e = q * 4;
    int cc[4] = {c4.x, c4.y, c4.z, c4.w};
#pragma unroll
    for (int j = 0; j < 4; ++j) {
        int m = mark1[cc[j]];
        if (m > 0) {
            int r = ei[e + j];
            float w = ew[e + j];
            unsigned s = atomicAdd(&cnt[2], 1u);
            if (s < CAP_E2) { e2r[s] = r; e2s[s] = m - 1; e2w[s] = w; }
            mark2[r] = 1;
        }
    }
}

// ---------------- K4: compact S2; init compact degree ----------------------
__global__ void k_compact2(int* mark2, unsigned* cnt, int* s2, float* deg2) {
    int i = blockIdx.x * blockDim.x + threadIdx.x;
    if (i >= NN) return;
    if (mark2[i]) {
        unsigned s = atomicAdd(&cnt[3], 1u);
        if (s < CAP_S2) { s2[s] = i; mark2[i] = (int)s + 1; deg2[s] = 1.0f; }
        else mark2[i] = 0;
    }
}

// ---------------- conv1d(pad=1,k=3) + GRU over one sequence (S2 path) ------
__device__ void gru_seq(const float* xseq, int T,
                        const float* cw, const float* cb,
                        const float* Wih, const float* Whh,
                        const float* bih, const float* bhh,
                        float* out48,
                        float* s_x, float* s_embed, float* s_giA,
                        float* s_h /* [2][KH] */) {
    int t = threadIdx.x;
    int nt = blockDim.x;
    for (int i = t; i < T * 2; i += nt) s_x[i] = xseq[i];
    __syncthreads();
    for (int idx = t; idx < T * KH; idx += nt) {
        int tt = idx / KH;
        int k = idx - tt * KH;
        float acc = cb[k];
#pragma unroll
        for (int d = 0; d < 3; ++d) {
            int tau = tt + d - 1;
            if (tau >= 0 && tau < T) {
                acc += cw[k * 6 + d] * s_x[tau * 2 + 0];
                acc += cw[k * 6 + 3 + d] * s_x[tau * 2 + 1];
            }
        }
        s_embed[tt * KH + k] = fmaxf(acc, 0.0f);
    }
    __syncthreads();
    for (int idx = t; idx < T * G3; idx += nt) {
        int step = idx / G3;
        int row = idx - step * G3;
        const float4* wp = reinterpret_cast<const float4*>(Wih + row * KH);
        const float4* em = reinterpret_cast<const float4*>(s_embed + step * KH);
        float g = bih[row];
#pragma unroll
        for (int j = 0; j < 12; ++j) {
            float4 w4 = wp[j]; float4 e4 = em[j];
            g += w4.x * e4.x + w4.y * e4.y + w4.z * e4.z + w4.w * e4.w;
        }
        s_giA[idx] = g;
    }
    int k = t >> 1, hf = t & 1;
    float4 wr[18];
    float bh0 = 0.0f, bh1 = 0.0f, bh2 = 0.0f;
    if (t < 96) {
#pragma unroll
        for (int g = 0; g < 3; ++g) {
            const float4* q = reinterpret_cast<const float4*>(
                Whh + (g * KH + k) * KH + hf * 24);
#pragma unroll
            for (int j = 0; j < 6; ++j) wr[g * 6 + j] = q[j];
        }
        if (hf == 0) { bh0 = bhh[k]; bh1 = bhh[KH + k]; bh2 = bhh[2 * KH + k]; }
    }
    if (t < KH) s_h[t] = 0.0f;   // buffer 0
    float hk = 0.0f;
    for (int step = 0; step < T; ++step) {
        __syncthreads();
        int cur = step & 1, nxt = cur ^ 1;
        if (t < 96) {
            const float4* hp = reinterpret_cast<const float4*>(s_h + cur * KH)
                               + hf * 6;
            float a0 = bh0, a1 = bh1, a2 = bh2;
#pragma unroll
            for (int j = 0; j < 6; ++j) {
                float4 hv = hp[j];
                float4 w0 = wr[j], w1 = wr[6 + j], w2 = wr[12 + j];
                a0 += w0.x * hv.x + w0.y * hv.y + w0.z * hv.z + w0.w * hv.w;
                a1 += w1.x * hv.x + w1.y * hv.y + w1.z * hv.z + w1.w * hv.w;
                a2 += w2.x * hv.x + w2.y * hv.y + w2.z * hv.z + w2.w * hv.w;
            }
            a0 += __shfl_xor(a0, 1);
            a1 += __shfl_xor(a1, 1);
            a2 += __shfl_xor(a2, 1);
            if (hf == 0) {
                const float* gi = s_giA + step * G3;
                float r = sigmf(gi[k] + a0);
                float z = sigmf(gi[KH + k] + a1);
                float n = tanhfast(gi[2 * KH + k] + r * a2);
                hk = (1.0f - z) * n + z * hk;
                s_h[nxt * KH + k] = hk;
            }
        }
    }
    __syncthreads();
    if (t < KH) out48[t] = s_h[(T & 1) * KH + t];
}

// -------- recurrent-only GRU (gi precomputed in ws by k_edges1 prep) -------
__device__ void gru_rec(const float* giA /* [T][G3] global */, int T,
                        const float* Whh, const float* bhh,
                        float* out48, float* s_h /* [2][KH] */) {
    int t = threadIdx.x;
    int k = t >> 1, hf = t & 1;
    float4 wr[18];
    float bh0 = 0.0f, bh1 = 0.0f, bh2 = 0.0f;
    if (t < 96) {
#pragma unroll
        for (int g = 0; g < 3; ++g) {
            const float4* q = reinterpret_cast<const float4*>(
                Whh + (g * KH + k) * KH + hf * 24);
#pragma unroll
            for (int j = 0; j < 6; ++j) wr[g * 6 + j] = q[j];
        }
        if (hf == 0) { bh0 = bhh[k]; bh1 = bhh[KH + k]; bh2 = bhh[2 * KH + k]; }
    }
    if (t < KH) s_h[t] = 0.0f;
    float hk = 0.0f;
    for (int step = 0; step < T; ++step) {
        __syncthreads();
        int cur = step & 1, nxt = cur ^ 1;
        if (t < 96) {
            const float4* hp = reinterpret_cast<const float4*>(s_h + cur * KH)
                               + hf * 6;
            float a0 = bh0, a1 = bh1, a2 = bh2;
#pragma unroll
            for (int j = 0; j < 6; ++j) {
                float4 hv = hp[j];
                float4 w0 = wr[j], w1 = wr[6 + j], w2 = wr[12 + j];
                a0 += w0.x * hv.x + w0.y * hv.y + w0.z * hv.z + w0.w * hv.w;
                a1 += w1.x * hv.x + w1.y * hv.y + w1.z * hv.z + w1.w * hv.w;
                a2 += w2.x * hv.x + w2.y * hv.y + w2.z * hv.z + w2.w * hv.w;
            }
            a0 += __shfl_xor(a0, 1);
            a1 += __shfl_xor(a1, 1);
            a2 += __shfl_xor(a2, 1);
            if (hf == 0) {
                const float* gi = giA + step * G3;
                float r = sigmf(gi[k] + a0);
                float z = sigmf(gi[KH + k] + a1);
                float n = tanhfast(gi[2 * KH + k] + r * a2);
                hk = (1.0f - z) * n + z * hk;
                s_h[nxt * KH + k] = hk;
            }
        }
    }
    __syncthreads();
    if (t < KH) out48[t] = s_h[(T & 1) * KH + t];
}

// ---------------- K5: deg scan + all GRUs ----------------------------------
__global__ __launch_bounds__(192, 2) void k_gru(
    const float* x, const float* cpw, const float* cpb,
    const float* epWih, const float* epWhh, const float* epbih, const float* epbhh,
    const float* efWhh, const float* efbhh,
    const float* giP, const float* giF,
    const int* ei, const float* ew, const int* mark2, float* deg2,
    const int* s2, const unsigned* cnt, float* state, float* tpsf) {
    if (blockIdx.x < DEGB) {
        int per = NE / DEGB;
        int lo = blockIdx.x * per;
        for (int e = lo + threadIdx.x; e < lo + per; e += blockDim.x) {
            int c = ei[NE + e];
            int m = mark2[c];
            if (m > 0) atomicAdd(&deg2[m - 1], ew[e]);
        }
        return;
    }
    __shared__ __align__(16) float s_x[80];
    __shared__ __align__(16) float s_embed[40 * KH];
    __shared__ __align__(16) float s_giA[40 * G3];
    __shared__ __align__(16) float s_h[2 * KH];
    if (blockIdx.x == DEGB) {
        gru_rec(giP, 20, epWhh, epbhh, tpsf, s_h);
        return;
    }
    if (blockIdx.x == DEGB + 1) {
        gru_rec(giF, 40, efWhh, efbhh, tpsf + 64, s_h);
        return;
    }
    int b0 = blockIdx.x - (DEGB + 2);
    int nw = gridDim.x - (DEGB + 2);
    int cnt2 = (int)min(cnt[3], (unsigned)CAP_S2);
    for (int b = b0; b < cnt2; b += nw) {
        int node = s2[b];
        gru_seq(x + (size_t)node * 40, 20, cpw, cpb, epWih, epWhh, epbih, epbhh,
                state + (size_t)b * KH, s_x, s_embed, s_giA, s_h);
    }
}

// ---------------- K6: staging (blocks 0..82) + GCN layer 1 edge acc --------
__global__ void k_acc1(const unsigned* cnt, const int* e2r, const int* e2s,
                       const float* e2w, const int* mark2, const float* deg2,
                       const int* s1g, const float* state,
                       const float* W1, float* x1,
                       const float* dWhh, const float* dWih,
                       const float* dbih, const float* tpsf,
                       _Float16* whh16, float* dwh4, float* gi0p) {
    if (blockIdx.x < STAGEB) {
        int id = blockIdx.x * blockDim.x + threadIdx.x;
        if (id < 27 * 576) {
            int c = id / 576, t = id - c * 576;
            int k = t >> 2, q = t & 3;
            int g = c / 9, u = c - g * 9;
            const float* src = dWhh + (size_t)(g * G3 + k) * G3 + q * 36 + 4 * u;
            float4 f = *reinterpret_cast<const float4*>(src);
            h2_t a, b;
            a.x = (_Float16)f.x; a.y = (_Float16)f.y;
            b.x = (_Float16)f.z; b.y = (_Float16)f.w;
            int pid = ((c >> 1) * 576 + t) * 2 + (c & 1);
            h2_t* o = reinterpret_cast<h2_t*>(whh16);
            o[2 * pid + 0] = a;
            o[2 * pid + 1] = b;
            return;
        }
        if (id < 27 * 576 + 9 * 576) {
            int id2 = id - 27 * 576;
            int c = id2 / 576, t = id2 - c * 576;
            int k = t >> 2, q = t & 3;
            int g = c / 3, j = c - g * 3;
            const float* src = dWih + (size_t)(g * G3 + k) * G3 + q * 12 + 4 * j;
            reinterpret_cast<float4*>(dwh4)[id2] =
                *reinterpret_cast<const float4*>(src);
            return;
        }
        int row = id - (27 * 576 + 9 * 576);
        if (row < 432) {
            const float* wr = dWih + (size_t)row * G3;
            float acc = dbih[row];
#pragma unroll
            for (int m = 0; m < 48; ++m) acc += wr[48 + m] * tpsf[m];
#pragma unroll
            for (int m = 0; m < 48; ++m) acc += wr[96 + m] * tpsf[64 + m];
            gi0p[row] = acc;
        }
        return;
    }
    int nE = (int)min(cnt[2], (unsigned)CAP_E2);
    int total = nE * KH;
    int stride = (gridDim.x - STAGEB) * blockDim.x;
    for (int idx = (blockIdx.x - STAGEB) * blockDim.x + threadIdx.x; idx < total;
         idx += stride) {
        int e = idx / KH;
        int k = idx - e * KH;
        int row = e2r[e];
        int s2i = mark2[row] - 1;
        if (s2i < 0) continue;
        int cglob = s1g[e2s[e]];
        int cs2 = mark2[cglob] - 1;
        float norm = e2w[e] * rsqrtf(deg2[s2i] * deg2[cs2]);
        const float* sp = state + (size_t)s2i * KH;
        const float* wp = W1 + k * KH;
        float acc = 0.0f;
#pragma unroll
        for (int m = 0; m < KH; ++m) acc += sp[m] * wp[m];
        atomicAdd(&x1[e2s[e] * KH + k], acc * norm);
    }
}

// ---------------- K7: GCN layer 2 @ node 0 + decoder -----------------------
// R9: weight loads hoisted to kernel entry into named registers (23 loads
// issue as one deep-MLP burst; R8's VGPR_Count=64 showed the compiler was
// serializing them in shallow batches -> ~7GB/s effective prologue fetch).
// launch_bounds(640,1) gives ~170 VGPR budget; peak live ~115.
__global__ __launch_bounds__(640, 1) void k_dec(
    const unsigned* cnt, const int* l1r, const float* l1w,
    const int* mark1, const int* mark2, const float* deg2, const float* x1,
    const float* W2, const float* b2, const float* tpsf, const float* past,
    const _Float16* whh16, const float* dwh4, const float* gi0p,
    const float* dbih, const float* dbhh,
    const float* fcw, const float* fcb, float* out) {
    __shared__ __align__(16) float s_conc[G3];
    __shared__ __align__(16) _Float16 s_h16[2][G3];   // fp16 h, double-buffered
    __shared__ __align__(16) float s_hf[2][G3];       // f32 h for fc
    int t = threadIdx.x;
    int k = t >> 2, q = t & 3;
    // ---- hoisted weight loads: issue ALL before the conc phase ----
    h8_t wv[13];
    h4_t wv26 = (h4_t)(_Float16)0.0f;
    float4 dv[9];
    float bh[3] = {0.0f, 0.0f, 0.0f};
    float bi[3] = {0.0f, 0.0f, 0.0f};
#pragma unroll
    for (int c2 = 0; c2 < 13; ++c2) wv[c2] = (h8_t)(_Float16)0.0f;
#pragma unroll
    for (int j = 0; j < 9; ++j) dv[j] = make_float4(0.f, 0.f, 0.f, 0.f);
    if (t < 576) {
        const h8_t* wp8 = reinterpret_cast<const h8_t*>(whh16);
#pragma unroll
        for (int c2 = 0; c2 < 13; ++c2) wv[c2] = wp8[c2 * 576 + t];
        wv26 = reinterpret_cast<const h4_t*>(whh16)[(13 * 576 + t) * 2];
        const float4* dp = reinterpret_cast<const float4*>(dwh4);
#pragma unroll
        for (int j = 0; j < 9; ++j) dv[j] = dp[j * 576 + t];
        if (q == 0) {
#pragma unroll
            for (int g = 0; g < 3; ++g) {
                bh[g] = dbhh[g * G3 + k];
                bi[g] = dbih[g * G3 + k];
            }
        }
    }
    // fc wave preload (wave 9)
    float fw0[3] = {0, 0, 0}, fw1[3] = {0, 0, 0};
    float fcb0 = 0.0f, fcb1 = 0.0f, pres0 = 0.0f, pres1 = 0.0f;
    if (t >= 576) {
        int lane = t - 576;
#pragma unroll
        for (int j = 0; j < 3; ++j) {
            int m = lane + 64 * j;
            if (m < G3) { fw0[j] = fcw[m]; fw1[j] = fcw[G3 + m]; }
        }
        if (lane == 0) {
            fcb0 = fcb[0]; fcb1 = fcb[1];
            pres0 = past[38]; pres1 = past[39];
        }
    }
    if (t < 48) s_conc[t] = b2[t];
    else if (t < 96) s_conc[t] = tpsf[t - 48];
    else if (t < 144) s_conc[t] = tpsf[64 + t - 96];
    if (t < G3) {
        s_h16[0][t] = (_Float16)0.0f;
        s_hf[0][t] = 0.0f;
    }
    __syncthreads();
    // layer-2 message accumulation into s_conc[0..47] (overlaps weight fetch)
    int cl1 = (int)min(cnt[0], (unsigned)CAP_L1);
    float dinv0 = rsqrtf(deg2[mark2[0] - 1]);
    int items = (cl1 + 1) * KH;
    for (int idx = t; idx < items; idx += blockDim.x) {
        int e = idx / KH;
        int kk = idx - e * KH;
        int row; float norm;
        if (e == cl1) { row = 0; norm = dinv0 * dinv0; }
        else {
            row = l1r[e];
            int rs2 = mark2[row] - 1;
            if (rs2 < 0) continue;
            norm = l1w[e] * rsqrtf(deg2[rs2]) * dinv0;
        }
        int s1 = mark1[row] - 1;
        if (s1 < 0) continue;
        const float* xp = x1 + (size_t)s1 * KH;
        const float* wp = W2 + kk * KH;
        float acc = 0.0f;
#pragma unroll
        for (int m = 0; m < KH; ++m) acc += fmaxf(xp[m], 0.0f) * wp[m];
        atomicAdd(&s_conc[kk], acc * norm);
    }
    // unpack hoisted wv -> wh[54]
    h2_t wh[54];
    if (t < 576) {
#pragma unroll
        for (int c2 = 0; c2 < 13; ++c2) {
            h8_t v = wv[c2];
            int c0 = 2 * c2, c1 = 2 * c2 + 1;
            int g0 = c0 / 9, u0 = c0 - g0 * 9;
            int g1 = c1 / 9, u1 = c1 - g1 * 9;
            wh[g0 * 18 + 2 * u0]     = __builtin_shufflevector(v, v, 0, 1);
            wh[g0 * 18 + 2 * u0 + 1] = __builtin_shufflevector(v, v, 2, 3);
            wh[g1 * 18 + 2 * u1]     = __builtin_shufflevector(v, v, 4, 5);
            wh[g1 * 18 + 2 * u1 + 1] = __builtin_shufflevector(v, v, 6, 7);
        }
        wh[2 * 18 + 2 * 8]     = __builtin_shufflevector(wv26, wv26, 0, 1);
        wh[2 * 18 + 2 * 8 + 1] = __builtin_shufflevector(wv26, wv26, 2, 3);
    } else {
#pragma unroll
        for (int j = 0; j < 54; ++j) wh[j] = (h2_t)(_Float16)0.0f;
    }
    __syncthreads();   // s_conc complete
    // gi0 head: cols [q*12, q*12+12) x 3 gates from hoisted dv
    float gi0[3] = {0.0f, 0.0f, 0.0f};
    if (t < 576) {
        const float4* cc = reinterpret_cast<const float4*>(s_conc) + q * 3;
        float4 c0 = cc[0], c1 = cc[1], c2v = cc[2];
#pragma unroll
        for (int g = 0; g < 3; ++g) {
            float4 w0 = dv[g * 3 + 0];
            float4 w1 = dv[g * 3 + 1];
            float4 w2 = dv[g * 3 + 2];
            float acc = w0.x * c0.x + w0.y * c0.y + w0.z * c0.z + w0.w * c0.w;
            acc += w1.x * c1.x + w1.y * c1.y + w1.z * c1.z + w1.w * c1.w;
            acc += w2.x * c2v.x + w2.y * c2v.y + w2.z * c2v.z + w2.w * c2v.w;
            acc += __shfl_xor(acc, 1);
            acc += __shfl_xor(acc, 2);
            gi0[g] = acc + gi0p[g * G3 + k];
        }
    }
    float hk = 0.0f;   // h[k] carried in f32 (q==0 lanes)
    for (int i = 0; i < 40; ++i) {
        __syncthreads();
        int cur = i & 1, nxt = cur ^ 1;
        if (t < 576) {
            const h4_t* hp = reinterpret_cast<const h4_t*>(&s_h16[cur][0]) + q * 9;
            float a0 = bh[0], a1 = bh[1], a2 = bh[2];
#pragma unroll
            for (int j = 0; j < 9; ++j) {
                h4_t hv = hp[j];
                h2_t lo = __builtin_shufflevector(hv, hv, 0, 1);
                h2_t hi = __builtin_shufflevector(hv, hv, 2, 3);
                a0 = fdot2f(wh[2 * j], lo, a0);
                a1 = fdot2f(wh[18 + 2 * j], lo, a1);
                a2 = fdot2f(wh[36 + 2 * j], lo, a2);
                a0 = fdot2f(wh[2 * j + 1], hi, a0);
                a1 = fdot2f(wh[18 + 2 * j + 1], hi, a1);
                a2 = fdot2f(wh[36 + 2 * j + 1], hi, a2);
            }
            a0 += __shfl_xor(a0, 1); a0 += __shfl_xor(a0, 2);
            a1 += __shfl_xor(a1, 1); a1 += __shfl_xor(a1, 2);
            a2 += __shfl_xor(a2, 1); a2 += __shfl_xor(a2, 2);
            if (q == 0) {
                float gr = ((i == 0) ? gi0[0] : bi[0]) + a0;
                float gz = ((i == 0) ? gi0[1] : bi[1]) + a1;
                float gn = ((i == 0) ? gi0[2] : bi[2]);
                float r = sigmf(gr);
                float z = sigmf(gz);
                float n = tanhfast(gn + r * a2);
                hk = (1.0f - z) * n + z * hk;
                s_h16[nxt][k] = (_Float16)hk;
                s_hf[nxt][k] = hk;
            }
        } else if (i >= 1) {
            int lane = t - 576;
            const float* hsrc = s_hf[cur];
            float p0 = 0.0f, p1 = 0.0f;
#pragma unroll
            for (int j = 0; j < 3; ++j) {
                int m = lane + 64 * j;
                if (m < G3) { float h = hsrc[m]; p0 += h * fw0[j]; p1 += h * fw1[j]; }
            }
#pragma unroll
            for (int off = 32; off > 0; off >>= 1) {
                p0 += __shfl_down(p0, off);
                p1 += __shfl_down(p1, off);
            }
            if (lane == 0) {
                pres0 += p0 + fcb0; pres1 += p1 + fcb1;
                out[(i - 1) * 2 + 0] = pres0;
                out[(i - 1) * 2 + 1] = pres1;
            }
        }
    }
    __syncthreads();
    if (t >= 576) {   // final step's fc (h_40 in buffer 0)
        int lane = t - 576;
        const float* hsrc = s_hf[0];
        float p0 = 0.0f, p1 = 0.0f;
#pragma unroll
        for (int j = 0; j < 3; ++j) {
            int m = lane + 64 * j;
            if (m < G3) { float h = hsrc[m]; p0 += h * fw0[j]; p1 += h * fw1[j]; }
        }
#pragma unroll
        for (int off = 32; off > 0; off >>= 1) {
            p0 += __shfl_down(p0, off);
            p1 += __shfl_down(p1, off);
        }
        if (lane == 0) {
            pres0 += p0 + fcb0; pres1 += p1 + fcb1;
            out[39 * 2 + 0] = pres0;
            out[39 * 2 + 1] = pres1;
        }
    }
}

extern "C" void kernel_launch(void* const* d_in, const int* in_sizes, int n_in,
                              void* d_out, int out_size, void* d_ws, size_t ws_size,
                              hipStream_t stream) {
    (void)in_sizes; (void)n_in; (void)out_size; (void)ws_size;
    const float* past   = (const float*)d_in[0];
    const float* future = (const float*)d_in[1];
    const float* x      = (const float*)d_in[2];
    const int*   ei     = (const int*)d_in[3];
    const float* ew     = (const float*)d_in[4];
    const float* cpw    = (const float*)d_in[5];
    const float* cpb    = (const float*)d_in[6];
    const float* cfw    = (const float*)d_in[7];
    const float* cfb    = (const float*)d_in[8];
    const float* epWih  = (const float*)d_in[9];
    const float* epWhh  = (const float*)d_in[10];
    const float* epbih  = (const float*)d_in[11];
    const float* epbhh  = (const float*)d_in[12];
    const float* efWih  = (const float*)d_in[13];
    const float* efWhh  = (const float*)d_in[14];
    const float* efbih  = (const float*)d_in[15];
    const float* efbhh  = (const float*)d_in[16];
    const float* dWih   = (const float*)d_in[17];
    const float* dWhh   = (const float*)d_in[18];
    const float* dbih   = (const float*)d_in[19];
    const float* dbhh   = (const float*)d_in[20];
    const float* fcw    = (const float*)d_in[21];
    const float* fcb    = (const float*)d_in[22];
    const float* g1w    = (const float*)d_in[23];
    const float* g1b    = (const float*)d_in[24];
    const float* g2w    = (const float*)d_in[25];
    const float* g2b    = (const float*)d_in[26];

    char* ws = (char*)d_ws;
    int*      mark1 = (int*)(ws + OFF_MARK1);
    int*      mark2 = (int*)(ws + OFF_MARK2);
    unsigned* cnt   = (unsigned*)(ws + OFF_CNT);
    int*      l1r   = (int*)(ws + OFF_L1R);
    float*    l1w   = (float*)(ws + OFF_L1W);
    int*      s1g   = (int*)(ws + OFF_S1G);
    int*      e2r   = (int*)(ws + OFF_E2R);
    int*      e2s   = (int*)(ws + OFF_E2S);
    float*    e2w   = (float*)(ws + OFF_E2W);
    int*      s2    = (int*)(ws + OFF_S2);
    float*    deg2  = (float*)(ws + OFF_DEG2);
    float*    state = (float*)(ws + OFF_STATE);
    float*    x1    = (float*)(ws + OFF_X1);
    float*    tpsf  = (float*)(ws + OFF_TPSF);
    _Float16* whh16 = (_Float16*)(ws + OFF_WHH16);
    float*    gi0p  = (float*)(ws + OFF_GI0P);
    float*    giP   = (float*)(ws + OFF_GIP);
    float*    giF   = (float*)(ws + OFF_GIF);
    float*    dwh4  = (float*)(ws + OFF_DWH4);

    hipMemsetAsync(ws, 0, 524352, stream);  // mark1 | mark2 | cnt
    k_edges1<<<NE / 4 / 256 + PREPB, 256, 0, stream>>>(
        ei, ew, mark1, cnt, l1r, l1w,
        past, future, cpw, cpb, cfw, cfb,
        epWih, epbih, efWih, efbih, giP, giF);
    k_compact1<<<NN / 256, 256, 0, stream>>>(mark1, mark2, cnt, e2r, e2s, e2w, s1g, x1, g1b);
    k_edges2<<<NE / 4 / 256, 256, 0, stream>>>(ei, ew, mark1, mark2, cnt, e2r, e2s, e2w);
    k_compact2<<<NN / 256, 256, 0, stream>>>(mark2, cnt, s2, deg2);
    k_gru<<<DEGB + 2 + 512, 192, 0, stream>>>(x, cpw, cpb, epWih, epWhh, epbih, epbhh,
                                              efWhh, efbhh, giP, giF,
                                              ei, ew, mark2, deg2,
                                              s2, cnt, state, tpsf);
    k_acc1<<<STAGEB + 128, 256, 0, stream>>>(cnt, e2r, e2s, e2w, mark2, deg2, s1g,
                                             state, g1w, x1,
                                             dWhh, dWih, dbih, tpsf,
                                             whh16, dwh4, gi0p);
    k_dec<<<1, 640, 0, stream>>>(cnt, l1r, l1w, mark1, mark2, deg2, x1, g2w, g2b,
                                 tpsf, past, whh16, dwh4, gi0p, dbih, dbhh, fcw, fcb,
                                 (float*)d_out);
}

// Round 10
// 212.420 us; speedup vs baseline: 1.2002x; 1.0028x over previous
//
#include <hip/hip_runtime.h>
#include <math.h>

#define NN 65536
#define NE 1048576
#define KH 48
#define G3 144
#define DEGB 512
#define PREPB 15
#define E1B 1024      // edge-scan blocks (NE/4/256)
#define SB2 81        // staging blocks at head of k_edges2 (20736 ids)
#define GIB 2         // gi0p blocks at head of k_acc1

#define CAP_L1 8192
#define CAP_S1 4096
#define CAP_E2 65536
#define CAP_S2 8192

// ws byte offsets. First 524352 bytes (mark1|mark2|cnt) are zeroed by one
// hipMemsetAsync in kernel_launch.
#define OFF_MARK1  0u        // NN i32
#define OFF_MARK2  262144u   // NN i32
#define OFF_CNT    524288u   // 16 u32
#define OFF_L1R    524352u   // CAP_L1 i32
#define OFF_L1W    557120u   // CAP_L1 f32
#define OFF_S1G    589888u   // CAP_S1 i32
#define OFF_E2R    606272u   // CAP_E2 i32
#define OFF_E2S    868416u   // CAP_E2 i32
#define OFF_E2W    1130560u  // CAP_E2 f32
#define OFF_S2     1392704u  // CAP_S2 i32
#define OFF_DEG2   1425472u  // CAP_S2 f32
#define OFF_STATE  1458240u  // CAP_S2*48 f32
#define OFF_X1     3031104u  // CAP_S1*48 f32
#define OFF_TPSF   3817536u  // 128 f32
#define OFF_WHH16  3818048u  // paired fp16 dWhh: 14*576*2 h4 = 129024 B
#define OFF_GI0P   3947072u  // 432 f32
#define OFF_GIP    3948800u  // 20*144 f32
#define OFF_GIF    3960320u  // 40*144 f32
#define OFF_DWH4   3983360u  // 9*576 float4 (f32 dWih[:, :48] re-layout) = 82944 B

typedef _Float16 h2_t __attribute__((ext_vector_type(2)));
typedef _Float16 h4_t __attribute__((ext_vector_type(4)));
typedef _Float16 h8_t __attribute__((ext_vector_type(8)));

// fast gates: v_exp_f32-based; error ~1e-6 rel, negligible vs fp16 weights
__device__ __forceinline__ float sigmf(float x) { return 1.0f / (1.0f + __expf(-x)); }
__device__ __forceinline__ float tanhfast(float x) {
    float e = __expf(2.0f * x);
    return 1.0f - 2.0f / (e + 1.0f);
}

#if __has_builtin(__builtin_amdgcn_fdot2)
__device__ __forceinline__ float fdot2f(h2_t a, h2_t b, float c) {
    return __builtin_amdgcn_fdot2(a, b, c, false);
}
#else
__device__ __forceinline__ float fdot2f(h2_t a, h2_t b, float c) {
    return c + (float)a.x * (float)b.x + (float)a.y * (float)b.y;
}
#endif

// -------- inline compaction (replaces k_compact1/k_compact2) --------------
// CAS-claim: reserve index, then CAS the mark. Losers waste a slot (written
// with sentinel, skipped downstream) — slot waste ~O(races) << caps.
__device__ __forceinline__ void s2_append(int r, unsigned* cnt, int* mark2,
                                          int* s2, float* deg2) {
    if (mark2[r] != 0) return;            // benign stale-0 race: extra slot
    unsigned idx = atomicAdd(&cnt[3], 1u);
    if (idx >= CAP_S2) return;
    int old = atomicCAS(&mark2[r], 0, (int)idx + 1);
    deg2[idx] = 1.0f;
    s2[idx] = (old == 0) ? r : -1;        // -1: wasted slot, worker skips
}

__device__ __forceinline__ void s1_claim(int r, unsigned* cnt, int* mark1,
                                         int* mark2, int* s1g,
                                         int* e2r, int* e2s, float* e2w,
                                         float* x1, const float* g1b,
                                         int* s2, float* deg2) {
    if (mark1[r] != 0) return;
    unsigned idx = atomicAdd(&cnt[1], 1u);
    if (idx >= CAP_S1) return;
    int old = atomicCAS(&mark1[r], 0, (int)idx + 1);
    if (old != 0) return;                 // lost race; s1g[idx] stale, unread
    s1g[idx] = r;
    unsigned t2 = atomicAdd(&cnt[2], 1u); // self-loop E2 entry
    if (t2 < CAP_E2) { e2r[t2] = r; e2s[t2] = (int)idx; e2w[t2] = 1.0f; }
    for (int k = 0; k < KH; ++k) x1[idx * KH + k] = g1b[k];
    s2_append(r, cnt, mark2, s2, deg2);
}

// ---------------- K1: edges into node 0 + inline S1 compaction + prep ------
__global__ void k_edges1(const int* ei, const float* ew,
                         int* mark1, int* mark2, unsigned* cnt,
                         int* l1r, float* l1w, int* s1g,
                         int* e2r, int* e2s, float* e2w,
                         float* x1, const float* g1b, int* s2, float* deg2,
                         const float* past, const float* future,
                         const float* cpw, const float* cpb,
                         const float* cfw, const float* cfb,
                         const float* epWih, const float* epbih,
                         const float* efWih, const float* efbih,
                         float* giP, float* giF) {
    if (blockIdx.x >= E1B) {
        int p = blockIdx.x - E1B;   // 0..14
        const float* xs; const float* cw; const float* cb;
        const float* Wih; const float* bih; float* gout;
        int T, s0;
        if (p < 5) { xs = past;   cw = cpw; cb = cpb; Wih = epWih; bih = epbih;
                     gout = giP; T = 20; s0 = p * 4; }
        else       { xs = future; cw = cfw; cb = cfb; Wih = efWih; bih = efbih;
                     gout = giF; T = 40; s0 = (p - 5) * 4; }
        __shared__ __align__(16) float s_x[80];
        __shared__ __align__(16) float s_e[4 * KH];
        int t = threadIdx.x;
        if (t < T * 2) s_x[t] = xs[t];
        __syncthreads();
        for (int idx = t; idx < 4 * KH; idx += 256) {
            int lt = idx / KH;
            int k = idx - lt * KH;
            int tt = s0 + lt;
            float acc = cb[k];
#pragma unroll
            for (int d = 0; d < 3; ++d) {
                int tau = tt + d - 1;
                if (tau >= 0 && tau < T) {
                    acc += cw[k * 6 + d] * s_x[tau * 2 + 0];
                    acc += cw[k * 6 + 3 + d] * s_x[tau * 2 + 1];
                }
            }
            s_e[lt * KH + k] = fmaxf(acc, 0.0f);
        }
        __syncthreads();
        for (int idx = t; idx < 4 * G3; idx += 256) {
            int lt = idx / G3;
            int row = idx - lt * G3;
            const float4* wp = reinterpret_cast<const float4*>(Wih + row * KH);
            const float4* em = reinterpret_cast<const float4*>(s_e + lt * KH);
            float g = bih[row];
#pragma unroll
            for (int j = 0; j < 12; ++j) {
                float4 w4 = wp[j]; float4 e4 = em[j];
                g += w4.x * e4.x + w4.y * e4.y + w4.z * e4.z + w4.w * e4.w;
            }
            gout[(s0 + lt) * G3 + row] = g;
        }
        return;
    }
    int q = blockIdx.x * blockDim.x + threadIdx.x;
    if (q == 0)   // node 0 always in S1
        s1_claim(0, cnt, mark1, mark2, s1g, e2r, e2s, e2w, x1, g1b, s2, deg2);
    int4 c4 = reinterpret_cast<const int4*>(ei + NE)[q];
    int e = q * 4;
    int cc[4] = {c4.x, c4.y, c4.z, c4.w};
#pragma unroll
    for (int j = 0; j < 4; ++j) {
        if (cc[j] == 0) {
            int r = ei[e + j];
            float w = ew[e + j];
            unsigned s = atomicAdd(&cnt[0], 1u);
            if (s < CAP_L1) { l1r[s] = r; l1w[s] = w; }
            s1_claim(r, cnt, mark1, mark2, s1g, e2r, e2s, e2w, x1, g1b, s2, deg2);
        }
    }
}

// ---------------- K2: edges into S1 + inline S2 compaction + weight staging
// Head blocks [0, SB2): stage dWhh -> fp16 paired layout + dWih head f32
// re-layout (pure input transforms — no deps on earlier kernels).
__global__ void k_edges2(const int* ei, const float* ew,
                         const int* mark1, int* mark2, unsigned* cnt,
                         int* e2r, int* e2s, float* e2w, int* s2, float* deg2,
                         const float* dWhh, const float* dWih,
                         _Float16* whh16, float* dwh4) {
    if (blockIdx.x < SB2) {
        int id = blockIdx.x * blockDim.x + threadIdx.x;
        if (id < 27 * 576) {
            int c = id / 576, t = id - c * 576;
            int k = t >> 2, q = t & 3;
            int g = c / 9, u = c - g * 9;
            const float* src = dWhh + (size_t)(g * G3 + k) * G3 + q * 36 + 4 * u;
            float4 f = *reinterpret_cast<const float4*>(src);
            h2_t a, b;
            a.x = (_Float16)f.x; a.y = (_Float16)f.y;
            b.x = (_Float16)f.z; b.y = (_Float16)f.w;
            int pid = ((c >> 1) * 576 + t) * 2 + (c & 1);
            h2_t* o = reinterpret_cast<h2_t*>(whh16);
            o[2 * pid + 0] = a;
            o[2 * pid + 1] = b;
            return;
        }
        int id2 = id - 27 * 576;
        if (id2 < 9 * 576) {
            int c = id2 / 576, t = id2 - c * 576;
            int k = t >> 2, q = t & 3;
            int g = c / 3, j = c - g * 3;
            const float* src = dWih + (size_t)(g * G3 + k) * G3 + q * 12 + 4 * j;
            reinterpret_cast<float4*>(dwh4)[id2] =
                *reinterpret_cast<const float4*>(src);
        }
        return;
    }
    int q = (blockIdx.x - SB2) * blockDim.x + threadIdx.x;
    if (q >= NE / 4) return;
    int4 c4 = reinterpret_cast<const int4*>(ei + NE)[q];
    int e = q * 4;
    int cc[4] = {c4.x, c4.y, c4.z, c4.w};
#pragma unroll
    for (int j = 0; j < 4; ++j) {
        int m = mark1[cc[j]];
        if (m > 0) {
            int r = ei[e + j];
            float w = ew[e + j];
            unsigned s = atomicAdd(&cnt[2], 1u);
            if (s < CAP_E2) { e2r[s] = r; e2s[s] = m - 1; e2w[s] = w; }
            s2_append(r, cnt, mark2, s2, deg2);
        }
    }
}

// ---------------- conv1d(pad=1,k=3) + GRU over one sequence (S2 path) ------
__device__ void gru_seq(const float* xseq, int T,
                        const float* cw, const float* cb,
                        const float* Wih, const float* Whh,
                        const float* bih, const float* bhh,
                        float* out48,
                        float* s_x, float* s_embed, float* s_giA,
                        float* s_h /* [2][KH] */) {
    int t = threadIdx.x;
    int nt = blockDim.x;
    for (int i = t; i < T * 2; i += nt) s_x[i] = xseq[i];
    __syncthreads();
    for (int idx = t; idx < T * KH; idx += nt) {
        int tt = idx / KH;
        int k = idx - tt * KH;
        float acc = cb[k];
#pragma unroll
        for (int d = 0; d < 3; ++d) {
            int tau = tt + d - 1;
            if (tau >= 0 && tau < T) {
                acc += cw[k * 6 + d] * s_x[tau * 2 + 0];
                acc += cw[k * 6 + 3 + d] * s_x[tau * 2 + 1];
            }
        }
        s_embed[tt * KH + k] = fmaxf(acc, 0.0f);
    }
    __syncthreads();
    for (int idx = t; idx < T * G3; idx += nt) {
        int step = idx / G3;
        int row = idx - step * G3;
        const float4* wp = reinterpret_cast<const float4*>(Wih + row * KH);
        const float4* em = reinterpret_cast<const float4*>(s_embed + step * KH);
        float g = bih[row];
#pragma unroll
        for (int j = 0; j < 12; ++j) {
            float4 w4 = wp[j]; float4 e4 = em[j];
            g += w4.x * e4.x + w4.y * e4.y + w4.z * e4.z + w4.w * e4.w;
        }
        s_giA[idx] = g;
    }
    int k = t >> 1, hf = t & 1;
    float4 wr[18];
    float bh0 = 0.0f, bh1 = 0.0f, bh2 = 0.0f;
    if (t < 96) {
#pragma unroll
        for (int g = 0; g < 3; ++g) {
            const float4* q = reinterpret_cast<const float4*>(
                Whh + (g * KH + k) * KH + hf * 24);
#pragma unroll
            for (int j = 0; j < 6; ++j) wr[g * 6 + j] = q[j];
        }
        if (hf == 0) { bh0 = bhh[k]; bh1 = bhh[KH + k]; bh2 = bhh[2 * KH + k]; }
    }
    if (t < KH) s_h[t] = 0.0f;   // buffer 0
    float hk = 0.0f;
    for (int step = 0; step < T; ++step) {
        __syncthreads();
        int cur = step & 1, nxt = cur ^ 1;
        if (t < 96) {
            const float4* hp = reinterpret_cast<const float4*>(s_h + cur * KH)
                               + hf * 6;
            float a0 = bh0, a1 = bh1, a2 = bh2;
#pragma unroll
            for (int j = 0; j < 6; ++j) {
                float4 hv = hp[j];
                float4 w0 = wr[j], w1 = wr[6 + j], w2 = wr[12 + j];
                a0 += w0.x * hv.x + w0.y * hv.y + w0.z * hv.z + w0.w * hv.w;
                a1 += w1.x * hv.x + w1.y * hv.y + w1.z * hv.z + w1.w * hv.w;
                a2 += w2.x * hv.x + w2.y * hv.y + w2.z * hv.z + w2.w * hv.w;
            }
            a0 += __shfl_xor(a0, 1);
            a1 += __shfl_xor(a1, 1);
            a2 += __shfl_xor(a2, 1);
            if (hf == 0) {
                const float* gi = s_giA + step * G3;
                float r = sigmf(gi[k] + a0);
                float z = sigmf(gi[KH + k] + a1);
                float n = tanhfast(gi[2 * KH + k] + r * a2);
                hk = (1.0f - z) * n + z * hk;
                s_h[nxt * KH + k] = hk;
            }
        }
    }
    __syncthreads();
    if (t < KH) out48[t] = s_h[(T & 1) * KH + t];
}

// -------- recurrent-only GRU (gi precomputed in ws by k_edges1 prep) -------
__device__ void gru_rec(const float* giA /* [T][G3] global */, int T,
                        const float* Whh, const float* bhh,
                        float* out48, float* s_h /* [2][KH] */) {
    int t = threadIdx.x;
    int k = t >> 1, hf = t & 1;
    float4 wr[18];
    float bh0 = 0.0f, bh1 = 0.0f, bh2 = 0.0f;
    if (t < 96) {
#pragma unroll
        for (int g = 0; g < 3; ++g) {
            const float4* q = reinterpret_cast<const float4*>(
                Whh + (g * KH + k) * KH + hf * 24);
#pragma unroll
            for (int j = 0; j < 6; ++j) wr[g * 6 + j] = q[j];
        }
        if (hf == 0) { bh0 = bhh[k]; bh1 = bhh[KH + k]; bh2 = bhh[2 * KH + k]; }
    }
    if (t < KH) s_h[t] = 0.0f;
    float hk = 0.0f;
    for (int step = 0; step < T; ++step) {
        __syncthreads();
        int cur = step & 1, nxt = cur ^ 1;
        if (t < 96) {
            const float4* hp = reinterpret_cast<const float4*>(s_h + cur * KH)
                               + hf * 6;
            float a0 = bh0, a1 = bh1, a2 = bh2;
#pragma unroll
            for (int j = 0; j < 6; ++j) {
                float4 hv = hp[j];
                float4 w0 = wr[j], w1 = wr[6 + j], w2 = wr[12 + j];
                a0 += w0.x * hv.x + w0.y * hv.y + w0.z * hv.z + w0.w * hv.w;
                a1 += w1.x * hv.x + w1.y * hv.y + w1.z * hv.z + w1.w * hv.w;
                a2 += w2.x * hv.x + w2.y * hv.y + w2.z * hv.z + w2.w * hv.w;
            }
            a0 += __shfl_xor(a0, 1);
            a1 += __shfl_xor(a1, 1);
            a2 += __shfl_xor(a2, 1);
            if (hf == 0) {
                const float* gi = giA + step * G3;
                float r = sigmf(gi[k] + a0);
                float z = sigmf(gi[KH + k] + a1);
                float n = tanhfast(gi[2 * KH + k] + r * a2);
                hk = (1.0f - z) * n + z * hk;
                s_h[nxt * KH + k] = hk;
            }
        }
    }
    __syncthreads();
    if (t < KH) out48[t] = s_h[(T & 1) * KH + t];
}

// ---------------- K3: deg scan + all GRUs ----------------------------------
__global__ __launch_bounds__(192, 2) void k_gru(
    const float* x, const float* cpw, const float* cpb,
    const float* epWih, const float* epWhh, const float* epbih, const float* epbhh,
    const float* efWhh, const float* efbhh,
    const float* giP, const float* giF,
    const int* ei, const float* ew, const int* mark2, float* deg2,
    const int* s2, const unsigned* cnt, float* state, float* tpsf) {
    if (blockIdx.x < DEGB) {
        int per = NE / DEGB;
        int lo = blockIdx.x * per;
        for (int e = lo + threadIdx.x; e < lo + per; e += blockDim.x) {
            int c = ei[NE + e];
            int m = mark2[c];
            if (m > 0) atomicAdd(&deg2[m - 1], ew[e]);
        }
        return;
    }
    __shared__ __align__(16) float s_x[80];
    __shared__ __align__(16) float s_embed[40 * KH];
    __shared__ __align__(16) float s_giA[40 * G3];
    __shared__ __align__(16) float s_h[2 * KH];
    if (blockIdx.x == DEGB) {
        gru_rec(giP, 20, epWhh, epbhh, tpsf, s_h);
        return;
    }
    if (blockIdx.x == DEGB + 1) {
        gru_rec(giF, 40, efWhh, efbhh, tpsf + 64, s_h);
        return;
    }
    int b0 = blockIdx.x - (DEGB + 2);
    int nw = gridDim.x - (DEGB + 2);
    int cnt2 = (int)min(cnt[3], (unsigned)CAP_S2);
    for (int b = b0; b < cnt2; b += nw) {
        int node = s2[b];
        if (node < 0) continue;   // wasted CAS-loser slot
        gru_seq(x + (size_t)node * 40, 20, cpw, cpb, epWih, epWhh, epbih, epbhh,
                state + (size_t)b * KH, s_x, s_embed, s_giA, s_h);
    }
}

// ---------------- K4: gi0p (blocks 0..1, needs tpsf) + GCN L1 edge acc -----
__global__ void k_acc1(const unsigned* cnt, const int* e2r, const int* e2s,
                       const float* e2w, const int* mark2, const float* deg2,
                       const int* s1g, const float* state,
                       const float* W1, float* x1,
                       const float* dWih, const float* dbih, const float* tpsf,
                       float* gi0p) {
    if (blockIdx.x < GIB) {
        int row = blockIdx.x * blockDim.x + threadIdx.x;
        if (row < 432) {
            const float* wr = dWih + (size_t)row * G3;
            float acc = dbih[row];
#pragma unroll
            for (int m = 0; m < 48; ++m) acc += wr[48 + m] * tpsf[m];
#pragma unroll
            for (int m = 0; m < 48; ++m) acc += wr[96 + m] * tpsf[64 + m];
            gi0p[row] = acc;
        }
        return;
    }
    int nE = (int)min(cnt[2], (unsigned)CAP_E2);
    int total = nE * KH;
    int stride = (gridDim.x - GIB) * blockDim.x;
    for (int idx = (blockIdx.x - GIB) * blockDim.x + threadIdx.x; idx < total;
         idx += stride) {
        int e = idx / KH;
        int k = idx - e * KH;
        int row = e2r[e];
        int s2i = mark2[row] - 1;
        if (s2i < 0) continue;
        int cglob = s1g[e2s[e]];
        int cs2 = mark2[cglob] - 1;
        float norm = e2w[e] * rsqrtf(deg2[s2i] * deg2[cs2]);
        const float* sp = state + (size_t)s2i * KH;
        const float* wp = W1 + k * KH;
        float acc = 0.0f;
#pragma unroll
        for (int m = 0; m < KH; ++m) acc += sp[m] * wp[m];
        atomicAdd(&x1[e2s[e] * KH + k], acc * norm);
    }
}

// ---------------- K5: GCN layer 2 @ node 0 + decoder (R9 structure) --------
__global__ __launch_bounds__(640, 1) void k_dec(
    const unsigned* cnt, const int* l1r, const float* l1w,
    const int* mark1, const int* mark2, const float* deg2, const float* x1,
    const float* W2, const float* b2, const float* tpsf, const float* past,
    const _Float16* whh16, const float* dwh4, const float* gi0p,
    const float* dbih, const float* dbhh,
    const float* fcw, const float* fcb, float* out) {
    __shared__ __align__(16) float s_conc[G3];
    __shared__ __align__(16) _Float16 s_h16[2][G3];   // fp16 h, double-buffered
    __shared__ __align__(16) float s_hf[2][G3];       // f32 h for fc
    int t = threadIdx.x;
    int k = t >> 2, q = t & 3;
    // ---- hoisted weight loads: issue ALL before the conc phase ----
    h8_t wv[13];
    h4_t wv26 = (h4_t)(_Float16)0.0f;
    float4 dv[9];
    float bh[3] = {0.0f, 0.0f, 0.0f};
    float bi[3] = {0.0f, 0.0f, 0.0f};
#pragma unroll
    for (int c2 = 0; c2 < 13; ++c2) wv[c2] = (h8_t)(_Float16)0.0f;
#pragma unroll
    for (int j = 0; j < 9; ++j) dv[j] = make_float4(0.f, 0.f, 0.f, 0.f);
    if (t < 576) {
        const h8_t* wp8 = reinterpret_cast<const h8_t*>(whh16);
#pragma unroll
        for (int c2 = 0; c2 < 13; ++c2) wv[c2] = wp8[c2 * 576 + t];
        wv26 = reinterpret_cast<const h4_t*>(whh16)[(13 * 576 + t) * 2];
        const float4* dp = reinterpret_cast<const float4*>(dwh4);
#pragma unroll
        for (int j = 0; j < 9; ++j) dv[j] = dp[j * 576 + t];
        if (q == 0) {
#pragma unroll
            for (int g = 0; g < 3; ++g) {
                bh[g] = dbhh[g * G3 + k];
                bi[g] = dbih[g * G3 + k];
            }
        }
    }
    // fc wave preload (wave 9)
    float fw0[3] = {0, 0, 0}, fw1[3] = {0, 0, 0};
    float fcb0 = 0.0f, fcb1 = 0.0f, pres0 = 0.0f, pres1 = 0.0f;
    if (t >= 576) {
        int lane = t - 576;
#pragma unroll
        for (int j = 0; j < 3; ++j) {
            int m = lane + 64 * j;
            if (m < G3) { fw0[j] = fcw[m]; fw1[j] = fcw[G3 + m]; }
        }
        if (lane == 0) {
            fcb0 = fcb[0]; fcb1 = fcb[1];
            pres0 = past[38]; pres1 = past[39];
        }
    }
    if (t < 48) s_conc[t] = b2[t];
    else if (t < 96) s_conc[t] = tpsf[t - 48];
    else if (t < 144) s_conc[t] = tpsf[64 + t - 96];
    if (t < G3) {
        s_h16[0][t] = (_Float16)0.0f;
        s_hf[0][t] = 0.0f;
    }
    __syncthreads();
    // layer-2 message accumulation into s_conc[0..47] (overlaps weight fetch)
    int cl1 = (int)min(cnt[0], (unsigned)CAP_L1);
    float dinv0 = rsqrtf(deg2[mark2[0] - 1]);
    int items = (cl1 + 1) * KH;
    for (int idx = t; idx < items; idx += blockDim.x) {
        int e = idx / KH;
        int kk = idx - e * KH;
        int row; float norm;
        if (e == cl1) { row = 0; norm = dinv0 * dinv0; }
        else {
            row = l1r[e];
            int rs2 = mark2[row] - 1;
            if (rs2 < 0) continue;
            norm = l1w[e] * rsqrtf(deg2[rs2]) * dinv0;
        }
        int s1 = mark1[row] - 1;
        if (s1 < 0) continue;
        const float* xp = x1 + (size_t)s1 * KH;
        const float* wp = W2 + kk * KH;
        float acc = 0.0f;
#pragma unroll
        for (int m = 0; m < KH; ++m) acc += fmaxf(xp[m], 0.0f) * wp[m];
        atomicAdd(&s_conc[kk], acc * norm);
    }
    // unpack hoisted wv -> wh[54]
    h2_t wh[54];
    if (t < 576) {
#pragma unroll
        for (int c2 = 0; c2 < 13; ++c2) {
            h8_t v = wv[c2];
            int c0 = 2 * c2, c1 = 2 * c2 + 1;
            int g0 = c0 / 9, u0 = c0 - g0 * 9;
            int g1 = c1 / 9, u1 = c1 - g1 * 9;
            wh[g0 * 18 + 2 * u0]     = __builtin_shufflevector(v, v, 0, 1);
            wh[g0 * 18 + 2 * u0 + 1] = __builtin_shufflevector(v, v, 2, 3);
            wh[g1 * 18 + 2 * u1]     = __builtin_shufflevector(v, v, 4, 5);
            wh[g1 * 18 + 2 * u1 + 1] = __builtin_shufflevector(v, v, 6, 7);
        }
        wh[2 * 18 + 2 * 8]     = __builtin_shufflevector(wv26, wv26, 0, 1);
        wh[2 * 18 + 2 * 8 + 1] = __builtin_shufflevector(wv26, wv26, 2, 3);
    } else {
#pragma unroll
        for (int j = 0; j < 54; ++j) wh[j] = (h2_t)(_Float16)0.0f;
    }
    __syncthreads();   // s_conc complete
    // gi0 head: cols [q*12, q*12+12) x 3 gates from hoisted dv
    float gi0[3] = {0.0f, 0.0f, 0.0f};
    if (t < 576) {
        const float4* cc = reinterpret_cast<const float4*>(s_conc) + q * 3;
        float4 c0 = cc[0], c1 = cc[1], c2v = cc[2];
#pragma unroll
        for (int g = 0; g < 3; ++g) {
            float4 w0 = dv[g * 3 + 0];
            float4 w1 = dv[g * 3 + 1];
            float4 w2 = dv[g * 3 + 2];
            float acc = w0.x * c0.x + w0.y * c0.y + w0.z * c0.z + w0.w * c0.w;
            acc += w1.x * c1.x + w1.y * c1.y + w1.z * c1.z + w1.w * c1.w;
            acc += w2.x * c2v.x + w2.y * c2v.y + w2.z * c2v.z + w2.w * c2v.w;
            acc += __shfl_xor(acc, 1);
            acc += __shfl_xor(acc, 2);
            gi0[g] = acc + gi0p[g * G3 + k];
        }
    }
    float hk = 0.0f;   // h[k] carried in f32 (q==0 lanes)
    for (int i = 0; i < 40; ++i) {
        __syncthreads();
        int cur = i & 1, nxt = cur ^ 1;
        if (t < 576) {
            const h4_t* hp = reinterpret_cast<const h4_t*>(&s_h16[cur][0]) + q * 9;
            float a0 = bh[0], a1 = bh[1], a2 = bh[2];
#pragma unroll
            for (int j = 0; j < 9; ++j) {
                h4_t hv = hp[j];
                h2_t lo = __builtin_shufflevector(hv, hv, 0, 1);
                h2_t hi = __builtin_shufflevector(hv, hv, 2, 3);
                a0 = fdot2f(wh[2 * j], lo, a0);
                a1 = fdot2f(wh[18 + 2 * j], lo, a1);
                a2 = fdot2f(wh[36 + 2 * j], lo, a2);
                a0 = fdot2f(wh[2 * j + 1], hi, a0);
                a1 = fdot2f(wh[18 + 2 * j + 1], hi, a1);
                a2 = fdot2f(wh[36 + 2 * j + 1], hi, a2);
            }
            a0 += __shfl_xor(a0, 1); a0 += __shfl_xor(a0, 2);
            a1 += __shfl_xor(a1, 1); a1 += __shfl_xor(a1, 2);
            a2 += __shfl_xor(a2, 1); a2 += __shfl_xor(a2, 2);
            if (q == 0) {
                float gr = ((i == 0) ? gi0[0] : bi[0]) + a0;
                float gz = ((i == 0) ? gi0[1] : bi[1]) + a1;
                float gn = ((i == 0) ? gi0[2] : bi[2]);
                float r = sigmf(gr);
                float z = sigmf(gz);
                float n = tanhfast(gn + r * a2);
                hk = (1.0f - z) * n + z * hk;
                s_h16[nxt][k] = (_Float16)hk;
                s_hf[nxt][k] = hk;
            }
        } else if (i >= 1) {
            int lane = t - 576;
            const float* hsrc = s_hf[cur];
            float p0 = 0.0f, p1 = 0.0f;
#pragma unroll
            for (int j = 0; j < 3; ++j) {
                int m = lane + 64 * j;
                if (m < G3) { float h = hsrc[m]; p0 += h * fw0[j]; p1 += h * fw1[j]; }
            }
#pragma unroll
            for (int off = 32; off > 0; off >>= 1) {
                p0 += __shfl_down(p0, off);
                p1 += __shfl_down(p1, off);
            }
            if (lane == 0) {
                pres0 += p0 + fcb0; pres1 += p1 + fcb1;
                out[(i - 1) * 2 + 0] = pres0;
                out[(i - 1) * 2 + 1] = pres1;
            }
        }
    }
    __syncthreads();
    if (t >= 576) {   // final step's fc (h_40 in buffer 0)
        int lane = t - 576;
        const float* hsrc = s_hf[0];
        float p0 = 0.0f, p1 = 0.0f;
#pragma unroll
        for (int j = 0; j < 3; ++j) {
            int m = lane + 64 * j;
            if (m < G3) { float h = hsrc[m]; p0 += h * fw0[j]; p1 += h * fw1[j]; }
        }
#pragma unroll
        for (int off = 32; off > 0; off >>= 1) {
            p0 += __shfl_down(p0, off);
            p1 += __shfl_down(p1, off);
        }
        if (lane == 0) {
            pres0 += p0 + fcb0; pres1 += p1 + fcb1;
            out[39 * 2 + 0] = pres0;
            out[39 * 2 + 1] = pres1;
        }
    }
}

extern "C" void kernel_launch(void* const* d_in, const int* in_sizes, int n_in,
                              void* d_out, int out_size, void* d_ws, size_t ws_size,
                              hipStream_t stream) {
    (void)in_sizes; (void)n_in; (void)out_size; (void)ws_size;
    const float* past   = (const float*)d_in[0];
    const float* future = (const float*)d_in[1];
    const float* x      = (const float*)d_in[2];
    const int*   ei     = (const int*)d_in[3];
    const float* ew     = (const float*)d_in[4];
    const float* cpw    = (const float*)d_in[5];
    const float* cpb    = (const float*)d_in[6];
    const float* cfw    = (const float*)d_in[7];
    const float* cfb    = (const float*)d_in[8];
    const float* epWih  = (const float*)d_in[9];
    const float* epWhh  = (const float*)d_in[10];
    const float* epbih  = (const float*)d_in[11];
    const float* epbhh  = (const float*)d_in[12];
    const float* efWih  = (const float*)d_in[13];
    const float* efWhh  = (const float*)d_in[14];
    const float* efbih  = (const float*)d_in[15];
    const float* efbhh  = (const float*)d_in[16];
    const float* dWih   = (const float*)d_in[17];
    const float* dWhh   = (const float*)d_in[18];
    const float* dbih   = (const float*)d_in[19];
    const float* dbhh   = (const float*)d_in[20];
    const float* fcw    = (const float*)d_in[21];
    const float* fcb    = (const float*)d_in[22];
    const float* g1w    = (const float*)d_in[23];
    const float* g1b    = (const float*)d_in[24];
    const float* g2w    = (const float*)d_in[25];
    const float* g2b    = (const float*)d_in[26];

    char* ws = (char*)d_ws;
    int*      mark1 = (int*)(ws + OFF_MARK1);
    int*      mark2 = (int*)(ws + OFF_MARK2);
    unsigned* cnt   = (unsigned*)(ws + OFF_CNT);
    int*      l1r   = (int*)(ws + OFF_L1R);
    float*    l1w   = (float*)(ws + OFF_L1W);
    int*      s1g   = (int*)(ws + OFF_S1G);
    int*      e2r   = (int*)(ws + OFF_E2R);
    int*      e2s   = (int*)(ws + OFF_E2S);
    float*    e2w   = (float*)(ws + OFF_E2W);
    int*      s2    = (int*)(ws + OFF_S2);
    float*    deg2  = (float*)(ws + OFF_DEG2);
    float*    state = (float*)(ws + OFF_STATE);
    float*    x1    = (float*)(ws + OFF_X1);
    float*    tpsf  = (float*)(ws + OFF_TPSF);
    _Float16* whh16 = (_Float16*)(ws + OFF_WHH16);
    float*    gi0p  = (float*)(ws + OFF_GI0P);
    float*    giP   = (float*)(ws + OFF_GIP);
    float*    giF   = (float*)(ws + OFF_GIF);
    float*    dwh4  = (float*)(ws + OFF_DWH4);

    hipMemsetAsync(ws, 0, 524352, stream);  // mark1 | mark2 | cnt
    k_edges1<<<E1B + PREPB, 256, 0, stream>>>(
        ei, ew, mark1, mark2, cnt, l1r, l1w, s1g, e2r, e2s, e2w,
        x1, g1b, s2, deg2,
        past, future, cpw, cpb, cfw, cfb,
        epWih, epbih, efWih, efbih, giP, giF);
    k_edges2<<<SB2 + E1B, 256, 0, stream>>>(ei, ew, mark1, mark2, cnt,
                                            e2r, e2s, e2w, s2, deg2,
                                            dWhh, dWih, whh16, dwh4);
    k_gru<<<DEGB + 2 + 512, 192, 0, stream>>>(x, cpw, cpb, epWih, epWhh, epbih, epbhh,
                                              efWhh, efbhh, giP, giF,
                                              ei, ew, mark2, deg2,
                                              s2, cnt, state, tpsf);
    k_acc1<<<GIB + 128, 256, 0, stream>>>(cnt, e2r, e2s, e2w, mark2, deg2, s1g,
                                          state, g1w, x1,
                                          dWih, dbih, tpsf, gi0p);
    k_dec<<<1, 640, 0, stream>>>(cnt, l1r, l1w, mark1, mark2, deg2, x1, g2w, g2b,
                                 tpsf, past, whh16, dwh4, gi0p, dbih, dbhh, fcw, fcb,
                                 (float*)d_out);
}

// Round 11
// 207.299 us; speedup vs baseline: 1.2298x; 1.0247x over previous
//
#include <hip/hip_runtime.h>
#include <math.h>

#define NN 65536
#define NE 1048576
#define KH 48
#define G3 144
#define DEGB 512
#define PREPB 15
#define E1B 1024      // edge-scan blocks (NE/4/256)
#define SB2 81        // staging blocks at head of k_edges2 (20736 ids)
#define GIB 2         // gi0p blocks at head of k_acc1

#define CAP_L1 8192
#define CAP_S1 4096
#define CAP_E2 65536
#define CAP_S2 8192

// ws byte offsets. First 524352 bytes (mark1|mark2|cnt) are zeroed by one
// hipMemsetAsync in kernel_launch.
#define OFF_MARK1  0u        // NN i32
#define OFF_MARK2  262144u   // NN i32
#define OFF_CNT    524288u   // 16 u32
#define OFF_L1R    524352u   // CAP_L1 i32
#define OFF_L1W    557120u   // CAP_L1 f32
#define OFF_S1G    589888u   // CAP_S1 i32
#define OFF_E2R    606272u   // CAP_E2 i32
#define OFF_E2S    868416u   // CAP_E2 i32
#define OFF_E2W    1130560u  // CAP_E2 f32
#define OFF_S2     1392704u  // CAP_S2 i32
#define OFF_DEG2   1425472u  // CAP_S2 f32
#define OFF_STATE  1458240u  // CAP_S2*48 f32
#define OFF_X1     3031104u  // CAP_S1*48 f32
#define OFF_TPSF   3817536u  // 128 f32
#define OFF_WHH16  3818048u  // fp16 dWhh, 288-thread h8 layout: 15552 h4 = 124416 B
#define OFF_GI0P   3947072u  // 432 f32
#define OFF_GIP    3948800u  // 20*144 f32
#define OFF_GIF    3960320u  // 40*144 f32
#define OFF_DWH4   3983360u  // 18*288 float4 (f32 dWih[:, :48], 288-thr layout) = 82944 B

typedef _Float16 h2_t __attribute__((ext_vector_type(2)));
typedef _Float16 h4_t __attribute__((ext_vector_type(4)));
typedef _Float16 h8_t __attribute__((ext_vector_type(8)));

// fast gates: v_exp_f32-based; error ~1e-6 rel, negligible vs fp16 weights
__device__ __forceinline__ float sigmf(float x) { return 1.0f / (1.0f + __expf(-x)); }
__device__ __forceinline__ float tanhfast(float x) {
    float e = __expf(2.0f * x);
    return 1.0f - 2.0f / (e + 1.0f);
}

#if __has_builtin(__builtin_amdgcn_fdot2)
__device__ __forceinline__ float fdot2f(h2_t a, h2_t b, float c) {
    return __builtin_amdgcn_fdot2(a, b, c, false);
}
#else
__device__ __forceinline__ float fdot2f(h2_t a, h2_t b, float c) {
    return c + (float)a.x * (float)b.x + (float)a.y * (float)b.y;
}
#endif

// -------- inline compaction (replaces old k_compact1/k_compact2) ----------
__device__ __forceinline__ void s2_append(int r, unsigned* cnt, int* mark2,
                                          int* s2, float* deg2) {
    if (mark2[r] != 0) return;            // benign stale-0 race: extra slot
    unsigned idx = atomicAdd(&cnt[3], 1u);
    if (idx >= CAP_S2) return;
    int old = atomicCAS(&mark2[r], 0, (int)idx + 1);
    deg2[idx] = 1.0f;
    s2[idx] = (old == 0) ? r : -1;        // -1: wasted slot, worker skips
}

__device__ __forceinline__ void s1_claim(int r, unsigned* cnt, int* mark1,
                                         int* mark2, int* s1g,
                                         int* e2r, int* e2s, float* e2w,
                                         float* x1, const float* g1b,
                                         int* s2, float* deg2) {
    if (mark1[r] != 0) return;
    unsigned idx = atomicAdd(&cnt[1], 1u);
    if (idx >= CAP_S1) return;
    int old = atomicCAS(&mark1[r], 0, (int)idx + 1);
    if (old != 0) return;                 // lost race; s1g[idx] stale, unread
    s1g[idx] = r;
    unsigned t2 = atomicAdd(&cnt[2], 1u); // self-loop E2 entry
    if (t2 < CAP_E2) { e2r[t2] = r; e2s[t2] = (int)idx; e2w[t2] = 1.0f; }
    for (int k = 0; k < KH; ++k) x1[idx * KH + k] = g1b[k];
    s2_append(r, cnt, mark2, s2, deg2);
}

// ---------------- K1: edges into node 0 + inline S1 compaction + prep ------
__global__ void k_edges1(const int* ei, const float* ew,
                         int* mark1, int* mark2, unsigned* cnt,
                         int* l1r, float* l1w, int* s1g,
                         int* e2r, int* e2s, float* e2w,
                         float* x1, const float* g1b, int* s2, float* deg2,
                         const float* past, const float* future,
                         const float* cpw, const float* cpb,
                         const float* cfw, const float* cfb,
                         const float* epWih, const float* epbih,
                         const float* efWih, const float* efbih,
                         float* giP, float* giF) {
    if (blockIdx.x >= E1B) {
        int p = blockIdx.x - E1B;   // 0..14
        const float* xs; const float* cw; const float* cb;
        const float* Wih; const float* bih; float* gout;
        int T, s0;
        if (p < 5) { xs = past;   cw = cpw; cb = cpb; Wih = epWih; bih = epbih;
                     gout = giP; T = 20; s0 = p * 4; }
        else       { xs = future; cw = cfw; cb = cfb; Wih = efWih; bih = efbih;
                     gout = giF; T = 40; s0 = (p - 5) * 4; }
        __shared__ __align__(16) float s_x[80];
        __shared__ __align__(16) float s_e[4 * KH];
        int t = threadIdx.x;
        if (t < T * 2) s_x[t] = xs[t];
        __syncthreads();
        for (int idx = t; idx < 4 * KH; idx += 256) {
            int lt = idx / KH;
            int k = idx - lt * KH;
            int tt = s0 + lt;
            float acc = cb[k];
#pragma unroll
            for (int d = 0; d < 3; ++d) {
                int tau = tt + d - 1;
                if (tau >= 0 && tau < T) {
                    acc += cw[k * 6 + d] * s_x[tau * 2 + 0];
                    acc += cw[k * 6 + 3 + d] * s_x[tau * 2 + 1];
                }
            }
            s_e[lt * KH + k] = fmaxf(acc, 0.0f);
        }
        __syncthreads();
        for (int idx = t; idx < 4 * G3; idx += 256) {
            int lt = idx / G3;
            int row = idx - lt * G3;
            const float4* wp = reinterpret_cast<const float4*>(Wih + row * KH);
            const float4* em = reinterpret_cast<const float4*>(s_e + lt * KH);
            float g = bih[row];
#pragma unroll
            for (int j = 0; j < 12; ++j) {
                float4 w4 = wp[j]; float4 e4 = em[j];
                g += w4.x * e4.x + w4.y * e4.y + w4.z * e4.z + w4.w * e4.w;
            }
            gout[(s0 + lt) * G3 + row] = g;
        }
        return;
    }
    int q = blockIdx.x * blockDim.x + threadIdx.x;
    if (q == 0)   // node 0 always in S1
        s1_claim(0, cnt, mark1, mark2, s1g, e2r, e2s, e2w, x1, g1b, s2, deg2);
    int4 c4 = reinterpret_cast<const int4*>(ei + NE)[q];
    int e = q * 4;
    int cc[4] = {c4.x, c4.y, c4.z, c4.w};
#pragma unroll
    for (int j = 0; j < 4; ++j) {
        if (cc[j] == 0) {
            int r = ei[e + j];
            float w = ew[e + j];
            unsigned s = atomicAdd(&cnt[0], 1u);
            if (s < CAP_L1) { l1r[s] = r; l1w[s] = w; }
            s1_claim(r, cnt, mark1, mark2, s1g, e2r, e2s, e2w, x1, g1b, s2, deg2);
        }
    }
}

// ---------------- K2: edges into S1 + inline S2 compaction + weight staging
// Head blocks [0, SB2): stage dWhh -> fp16 (288-thread h8 layout) + dWih
// head f32 re-layout (pure input transforms).
//   whh16: h8 index c*288+t (c=0..26) = cols [hf*72+8u, +8) of row g*144+k,
//          where k=t>>1, hf=t&1, g=c/9, u=c%9. Staged as 2 h4 per h8.
//   dwh4 : float4 index c*288+t (c=0..17) = cols hf*24+4j.. of row g*144+k,
//          g=c/6, j=c%6.
__global__ void k_edges2(const int* ei, const float* ew,
                         const int* mark1, int* mark2, unsigned* cnt,
                         int* e2r, int* e2s, float* e2w, int* s2, float* deg2,
                         const float* dWhh, const float* dWih,
                         _Float16* whh16, float* dwh4) {
    if (blockIdx.x < SB2) {
        int id = blockIdx.x * blockDim.x + threadIdx.x;
        if (id < 27 * 288 * 2) {
            int pid = id >> 1, half = id & 1;
            int c = pid / 288, t = pid - c * 288;
            int k = t >> 1, hf = t & 1;
            int g = c / 9, u = c - g * 9;
            const float* src = dWhh + (size_t)(g * G3 + k) * G3
                               + hf * 72 + 8 * u + 4 * half;
            float4 f = *reinterpret_cast<const float4*>(src);
            h4_t o;
            o.x = (_Float16)f.x; o.y = (_Float16)f.y;
            o.z = (_Float16)f.z; o.w = (_Float16)f.w;
            reinterpret_cast<h4_t*>(whh16)[2 * pid + half] = o;
            return;
        }
        int id2 = id - 27 * 288 * 2;
        if (id2 < 18 * 288) {
            int c = id2 / 288, t = id2 - c * 288;
            int k = t >> 1, hf = t & 1;
            int g = c / 6, j = c - g * 6;
            const float* src = dWih + (size_t)(g * G3 + k) * G3 + hf * 24 + 4 * j;
            reinterpret_cast<float4*>(dwh4)[id2] =
                *reinterpret_cast<const float4*>(src);
        }
        return;
    }
    int q = (blockIdx.x - SB2) * blockDim.x + threadIdx.x;
    if (q >= NE / 4) return;
    int4 c4 = reinterpret_cast<const int4*>(ei + NE)[q];
    int e = q * 4;
    int cc[4] = {c4.x, c4.y, c4.z, c4.w};
#pragma unroll
    for (int j = 0; j < 4; ++j) {
        int m = mark1[cc[j]];
        if (m > 0) {
            int r = ei[e + j];
            float w = ew[e + j];
            unsigned s = atomicAdd(&cnt[2], 1u);
            if (s < CAP_E2) { e2r[s] = r; e2s[s] = m - 1; e2w[s] = w; }
            s2_append(r, cnt, mark2, s2, deg2);
        }
    }
}

// ---------------- conv1d(pad=1,k=3) + GRU over one sequence (S2 path) ------
__device__ void gru_seq(const float* xseq, int T,
                        const float* cw, const float* cb,
                        const float* Wih, const float* Whh,
                        const float* bih, const float* bhh,
                        float* out48,
                        float* s_x, float* s_embed, float* s_giA,
                        float* s_h /* [2][KH] */) {
    int t = threadIdx.x;
    int nt = blockDim.x;
    for (int i = t; i < T * 2; i += nt) s_x[i] = xseq[i];
    __syncthreads();
    for (int idx = t; idx < T * KH; idx += nt) {
        int tt = idx / KH;
        int k = idx - tt * KH;
        float acc = cb[k];
#pragma unroll
        for (int d = 0; d < 3; ++d) {
            int tau = tt + d - 1;
            if (tau >= 0 && tau < T) {
                acc += cw[k * 6 + d] * s_x[tau * 2 + 0];
                acc += cw[k * 6 + 3 + d] * s_x[tau * 2 + 1];
            }
        }
        s_embed[tt * KH + k] = fmaxf(acc, 0.0f);
    }
    __syncthreads();
    for (int idx = t; idx < T * G3; idx += nt) {
        int step = idx / G3;
        int row = idx - step * G3;
        const float4* wp = reinterpret_cast<const float4*>(Wih + row * KH);
        const float4* em = reinterpret_cast<const float4*>(s_embed + step * KH);
        float g = bih[row];
#pragma unroll
        for (int j = 0; j < 12; ++j) {
            float4 w4 = wp[j]; float4 e4 = em[j];
            g += w4.x * e4.x + w4.y * e4.y + w4.z * e4.z + w4.w * e4.w;
        }
        s_giA[idx] = g;
    }
    int k = t >> 1, hf = t & 1;
    float4 wr[18];
    float bh0 = 0.0f, bh1 = 0.0f, bh2 = 0.0f;
    if (t < 96) {
#pragma unroll
        for (int g = 0; g < 3; ++g) {
            const float4* q = reinterpret_cast<const float4*>(
                Whh + (g * KH + k) * KH + hf * 24);
#pragma unroll
            for (int j = 0; j < 6; ++j) wr[g * 6 + j] = q[j];
        }
        if (hf == 0) { bh0 = bhh[k]; bh1 = bhh[KH + k]; bh2 = bhh[2 * KH + k]; }
    }
    if (t < KH) s_h[t] = 0.0f;   // buffer 0
    float hk = 0.0f;
    for (int step = 0; step < T; ++step) {
        __syncthreads();
        int cur = step & 1, nxt = cur ^ 1;
        if (t < 96) {
            const float4* hp = reinterpret_cast<const float4*>(s_h + cur * KH)
                               + hf * 6;
            float a0 = bh0, a1 = bh1, a2 = bh2;
#pragma unroll
            for (int j = 0; j < 6; ++j) {
                float4 hv = hp[j];
                float4 w0 = wr[j], w1 = wr[6 + j], w2 = wr[12 + j];
                a0 += w0.x * hv.x + w0.y * hv.y + w0.z * hv.z + w0.w * hv.w;
                a1 += w1.x * hv.x + w1.y * hv.y + w1.z * hv.z + w1.w * hv.w;
                a2 += w2.x * hv.x + w2.y * hv.y + w2.z * hv.z + w2.w * hv.w;
            }
            a0 += __shfl_xor(a0, 1);
            a1 += __shfl_xor(a1, 1);
            a2 += __shfl_xor(a2, 1);
            if (hf == 0) {
                const float* gi = s_giA + step * G3;
                float r = sigmf(gi[k] + a0);
                float z = sigmf(gi[KH + k] + a1);
                float n = tanhfast(gi[2 * KH + k] + r * a2);
                hk = (1.0f - z) * n + z * hk;
                s_h[nxt * KH + k] = hk;
            }
        }
    }
    __syncthreads();
    if (t < KH) out48[t] = s_h[(T & 1) * KH + t];
}

// -------- recurrent-only GRU (gi precomputed in ws by k_edges1 prep) -------
__device__ void gru_rec(const float* giA /* [T][G3] global */, int T,
                        const float* Whh, const float* bhh,
                        float* out48, float* s_h /* [2][KH] */) {
    int t = threadIdx.x;
    int k = t >> 1, hf = t & 1;
    float4 wr[18];
    float bh0 = 0.0f, bh1 = 0.0f, bh2 = 0.0f;
    if (t < 96) {
#pragma unroll
        for (int g = 0; g < 3; ++g) {
            const float4* q = reinterpret_cast<const float4*>(
                Whh + (g * KH + k) * KH + hf * 24);
#pragma unroll
            for (int j = 0; j < 6; ++j) wr[g * 6 + j] = q[j];
        }
        if (hf == 0) { bh0 = bhh[k]; bh1 = bhh[KH + k]; bh2 = bhh[2 * KH + k]; }
    }
    if (t < KH) s_h[t] = 0.0f;
    float hk = 0.0f;
    for (int step = 0; step < T; ++step) {
        __syncthreads();
        int cur = step & 1, nxt = cur ^ 1;
        if (t < 96) {
            const float4* hp = reinterpret_cast<const float4*>(s_h + cur * KH)
                               + hf * 6;
            float a0 = bh0, a1 = bh1, a2 = bh2;
#pragma unroll
            for (int j = 0; j < 6; ++j) {
                float4 hv = hp[j];
                float4 w0 = wr[j], w1 = wr[6 + j], w2 = wr[12 + j];
                a0 += w0.x * hv.x + w0.y * hv.y + w0.z * hv.z + w0.w * hv.w;
                a1 += w1.x * hv.x + w1.y * hv.y + w1.z * hv.z + w1.w * hv.w;
                a2 += w2.x * hv.x + w2.y * hv.y + w2.z * hv.z + w2.w * hv.w;
            }
            a0 += __shfl_xor(a0, 1);
            a1 += __shfl_xor(a1, 1);
            a2 += __shfl_xor(a2, 1);
            if (hf == 0) {
                const float* gi = giA + step * G3;
                float r = sigmf(gi[k] + a0);
                float z = sigmf(gi[KH + k] + a1);
                float n = tanhfast(gi[2 * KH + k] + r * a2);
                hk = (1.0f - z) * n + z * hk;
                s_h[nxt * KH + k] = hk;
            }
        }
    }
    __syncthreads();
    if (t < KH) out48[t] = s_h[(T & 1) * KH + t];
}

// ---------------- K3: deg scan + all GRUs ----------------------------------
__global__ __launch_bounds__(192, 2) void k_gru(
    const float* x, const float* cpw, const float* cpb,
    const float* epWih, const float* epWhh, const float* epbih, const float* epbhh,
    const float* efWhh, const float* efbhh,
    const float* giP, const float* giF,
    const int* ei, const float* ew, const int* mark2, float* deg2,
    const int* s2, const unsigned* cnt, float* state, float* tpsf) {
    if (blockIdx.x < DEGB) {
        int per = NE / DEGB;
        int lo = blockIdx.x * per;
        for (int e = lo + threadIdx.x; e < lo + per; e += blockDim.x) {
            int c = ei[NE + e];
            int m = mark2[c];
            if (m > 0) atomicAdd(&deg2[m - 1], ew[e]);
        }
        return;
    }
    __shared__ __align__(16) float s_x[80];
    __shared__ __align__(16) float s_embed[40 * KH];
    __shared__ __align__(16) float s_giA[40 * G3];
    __shared__ __align__(16) float s_h[2 * KH];
    if (blockIdx.x == DEGB) {
        gru_rec(giP, 20, epWhh, epbhh, tpsf, s_h);
        return;
    }
    if (blockIdx.x == DEGB + 1) {
        gru_rec(giF, 40, efWhh, efbhh, tpsf + 64, s_h);
        return;
    }
    int b0 = blockIdx.x - (DEGB + 2);
    int nw = gridDim.x - (DEGB + 2);
    int cnt2 = (int)min(cnt[3], (unsigned)CAP_S2);
    for (int b = b0; b < cnt2; b += nw) {
        int node = s2[b];
        if (node < 0) continue;   // wasted CAS-loser slot
        gru_seq(x + (size_t)node * 40, 20, cpw, cpb, epWih, epWhh, epbih, epbhh,
                state + (size_t)b * KH, s_x, s_embed, s_giA, s_h);
    }
}

// ---------------- K4: gi0p (blocks 0..1, needs tpsf) + GCN L1 edge acc -----
__global__ void k_acc1(const unsigned* cnt, const int* e2r, const int* e2s,
                       const float* e2w, const int* mark2, const float* deg2,
                       const int* s1g, const float* state,
                       const float* W1, float* x1,
                       const float* dWih, const float* dbih, const float* tpsf,
                       float* gi0p) {
    if (blockIdx.x < GIB) {
        int row = blockIdx.x * blockDim.x + threadIdx.x;
        if (row < 432) {
            const float* wr = dWih + (size_t)row * G3;
            float acc = dbih[row];
#pragma unroll
            for (int m = 0; m < 48; ++m) acc += wr[48 + m] * tpsf[m];
#pragma unroll
            for (int m = 0; m < 48; ++m) acc += wr[96 + m] * tpsf[64 + m];
            gi0p[row] = acc;
        }
        return;
    }
    int nE = (int)min(cnt[2], (unsigned)CAP_E2);
    int total = nE * KH;
    int stride = (gridDim.x - GIB) * blockDim.x;
    for (int idx = (blockIdx.x - GIB) * blockDim.x + threadIdx.x; idx < total;
         idx += stride) {
        int e = idx / KH;
        int k = idx - e * KH;
        int row = e2r[e];
        int s2i = mark2[row] - 1;
        if (s2i < 0) continue;
        int cglob = s1g[e2s[e]];
        int cs2 = mark2[cglob] - 1;
        float norm = e2w[e] * rsqrtf(deg2[s2i] * deg2[cs2]);
        const float* sp = state + (size_t)s2i * KH;
        const float* wp = W1 + k * KH;
        float acc = 0.0f;
#pragma unroll
        for (int m = 0; m < KH; ++m) acc += sp[m] * wp[m];
        atomicAdd(&x1[e2s[e] * KH + k], acc * norm);
    }
}

// ---------------- K5: GCN layer 2 @ node 0 + decoder -----------------------
// R11: 2-lane row split (k=t>>1, hf=t&1): 288 matvec threads own 108 h2
// weight regs each (R0's layout, now WITHOUT the 128-VGPR cap that spilled
// it: launch_bounds(384,1) -> 256 cap, peak live ~210). Halves matvec wave
// count (9->4.5), shfl levels (2->1), and doubles prologue load depth
// (45 independent 16B loads/thread in one burst).
__global__ __launch_bounds__(384, 1) void k_dec(
    const unsigned* cnt, const int* l1r, const float* l1w,
    const int* mark1, const int* mark2, const float* deg2, const float* x1,
    const float* W2, const float* b2, const float* tpsf, const float* past,
    const _Float16* whh16, const float* dwh4, const float* gi0p,
    const float* dbih, const float* dbhh,
    const float* fcw, const float* fcb, float* out) {
    __shared__ __align__(16) float s_conc[G3];
    __shared__ __align__(16) _Float16 s_h16[2][G3];   // fp16 h, double-buffered
    __shared__ __align__(16) float s_hf[2][G3];       // f32 h for fc
    int t = threadIdx.x;
    int k = t >> 1, hf = t & 1;
    // ---- hoisted weight loads: one burst, consumed after conc phase ----
    h8_t wv[27];
    float4 dv[18];
    float bh[3] = {0.0f, 0.0f, 0.0f};
    float bi[3] = {0.0f, 0.0f, 0.0f};
#pragma unroll
    for (int c = 0; c < 27; ++c) wv[c] = (h8_t)(_Float16)0.0f;
#pragma unroll
    for (int c = 0; c < 18; ++c) dv[c] = make_float4(0.f, 0.f, 0.f, 0.f);
    if (t < 288) {
        const h8_t* wp8 = reinterpret_cast<const h8_t*>(whh16);
#pragma unroll
        for (int c = 0; c < 27; ++c) wv[c] = wp8[c * 288 + t];
        const float4* dp = reinterpret_cast<const float4*>(dwh4);
#pragma unroll
        for (int c = 0; c < 18; ++c) dv[c] = dp[c * 288 + t];
        if (hf == 0) {
#pragma unroll
            for (int g = 0; g < 3; ++g) {
                bh[g] = dbhh[g * G3 + k];
                bi[g] = dbih[g * G3 + k];
            }
        }
    }
    // fc wave preload (wave 5: threads 320..383)
    float fw0[3] = {0, 0, 0}, fw1[3] = {0, 0, 0};
    float fcb0 = 0.0f, fcb1 = 0.0f, pres0 = 0.0f, pres1 = 0.0f;
    if (t >= 320) {
        int lane = t - 320;
#pragma unroll
        for (int j = 0; j < 3; ++j) {
            int m = lane + 64 * j;
            if (m < G3) { fw0[j] = fcw[m]; fw1[j] = fcw[G3 + m]; }
        }
        if (lane == 0) {
            fcb0 = fcb[0]; fcb1 = fcb[1];
            pres0 = past[38]; pres1 = past[39];
        }
    }
    if (t < 48) s_conc[t] = b2[t];
    else if (t < 96) s_conc[t] = tpsf[t - 48];
    else if (t < 144) s_conc[t] = tpsf[64 + t - 96];
    if (t < G3) {
        s_h16[0][t] = (_Float16)0.0f;
        s_hf[0][t] = 0.0f;
    }
    __syncthreads();
    // layer-2 message accumulation into s_conc[0..47] (overlaps weight fetch)
    int cl1 = (int)min(cnt[0], (unsigned)CAP_L1);
    float dinv0 = rsqrtf(deg2[mark2[0] - 1]);
    int items = (cl1 + 1) * KH;
    for (int idx = t; idx < items; idx += blockDim.x) {
        int e = idx / KH;
        int kk = idx - e * KH;
        int row; float norm;
        if (e == cl1) { row = 0; norm = dinv0 * dinv0; }
        else {
            row = l1r[e];
            int rs2 = mark2[row] - 1;
            if (rs2 < 0) continue;
            norm = l1w[e] * rsqrtf(deg2[rs2]) * dinv0;
        }
        int s1 = mark1[row] - 1;
        if (s1 < 0) continue;
        const float* xp = x1 + (size_t)s1 * KH;
        const float* wp = W2 + kk * KH;
        float acc = 0.0f;
#pragma unroll
        for (int m = 0; m < KH; ++m) acc += fmaxf(xp[m], 0.0f) * wp[m];
        atomicAdd(&s_conc[kk], acc * norm);
    }
    __syncthreads();   // s_conc complete
    // gi0: cols [hf*24, +24) x 3 gates from hoisted dv + shfl_xor(1)
    float gi0[3] = {0.0f, 0.0f, 0.0f};
    if (t < 288) {
        const float4* ccp = reinterpret_cast<const float4*>(s_conc) + hf * 6;
        float4 c0 = ccp[0], c1 = ccp[1], c2 = ccp[2];
        float4 c3 = ccp[3], c4 = ccp[4], c5 = ccp[5];
#pragma unroll
        for (int g = 0; g < 3; ++g) {
            float4 w0 = dv[g * 6 + 0], w1 = dv[g * 6 + 1], w2 = dv[g * 6 + 2];
            float4 w3 = dv[g * 6 + 3], w4 = dv[g * 6 + 4], w5 = dv[g * 6 + 5];
            float acc = w0.x * c0.x + w0.y * c0.y + w0.z * c0.z + w0.w * c0.w;
            acc += w1.x * c1.x + w1.y * c1.y + w1.z * c1.z + w1.w * c1.w;
            acc += w2.x * c2.x + w2.y * c2.y + w2.z * c2.z + w2.w * c2.w;
            acc += w3.x * c3.x + w3.y * c3.y + w3.z * c3.z + w3.w * c3.w;
            acc += w4.x * c4.x + w4.y * c4.y + w4.z * c4.z + w4.w * c4.w;
            acc += w5.x * c5.x + w5.y * c5.y + w5.z * c5.z + w5.w * c5.w;
            acc += __shfl_xor(acc, 1);
            gi0[g] = acc + gi0p[g * G3 + k];
        }
    }
    float hk = 0.0f;   // h[k] carried in f32 (hf==0 lanes)
    for (int i = 0; i < 40; ++i) {
        __syncthreads();
        int cur = i & 1, nxt = cur ^ 1;
        if (t < 288) {
            // h half: 9 x ds_read_b128 (h8), weights consumed via subregister
            const h8_t* hp = reinterpret_cast<const h8_t*>(&s_h16[cur][0]) + hf * 9;
            float a0 = bh[0], a1 = bh[1], a2 = bh[2];
#pragma unroll
            for (int j = 0; j < 9; ++j) {
                h8_t hv = hp[j];
                h2_t h0 = __builtin_shufflevector(hv, hv, 0, 1);
                h2_t h1 = __builtin_shufflevector(hv, hv, 2, 3);
                h2_t h2v = __builtin_shufflevector(hv, hv, 4, 5);
                h2_t h3 = __builtin_shufflevector(hv, hv, 6, 7);
                h8_t w0v = wv[j], w1v = wv[9 + j], w2v = wv[18 + j];
                a0 = fdot2f(__builtin_shufflevector(w0v, w0v, 0, 1), h0, a0);
                a1 = fdot2f(__builtin_shufflevector(w1v, w1v, 0, 1), h0, a1);
                a2 = fdot2f(__builtin_shufflevector(w2v, w2v, 0, 1), h0, a2);
                a0 = fdot2f(__builtin_shufflevector(w0v, w0v, 2, 3), h1, a0);
                a1 = fdot2f(__builtin_shufflevector(w1v, w1v, 2, 3), h1, a1);
                a2 = fdot2f(__builtin_shufflevector(w2v, w2v, 2, 3), h1, a2);
                a0 = fdot2f(__builtin_shufflevector(w0v, w0v, 4, 5), h2v, a0);
                a1 = fdot2f(__builtin_shufflevector(w1v, w1v, 4, 5), h2v, a1);
                a2 = fdot2f(__builtin_shufflevector(w2v, w2v, 4, 5), h2v, a2);
                a0 = fdot2f(__builtin_shufflevector(w0v, w0v, 6, 7), h3, a0);
                a1 = fdot2f(__builtin_shufflevector(w1v, w1v, 6, 7), h3, a1);
                a2 = fdot2f(__builtin_shufflevector(w2v, w2v, 6, 7), h3, a2);
            }
            a0 += __shfl_xor(a0, 1);
            a1 += __shfl_xor(a1, 1);
            a2 += __shfl_xor(a2, 1);
            if (hf == 0) {
                float gr = ((i == 0) ? gi0[0] : bi[0]) + a0;
                float gz = ((i == 0) ? gi0[1] : bi[1]) + a1;
                float gn = ((i == 0) ? gi0[2] : bi[2]);
                float r = sigmf(gr);
                float z = sigmf(gz);
                float n = tanhfast(gn + r * a2);
                hk = (1.0f - z) * n + z * hk;
                s_h16[nxt][k] = (_Float16)hk;
                s_hf[nxt][k] = hk;
            }
        } else if (t >= 320 && i >= 1) {
            int lane = t - 320;
            const float* hsrc = s_hf[cur];
            float p0 = 0.0f, p1 = 0.0f;
#pragma unroll
            for (int j = 0; j < 3; ++j) {
                int m = lane + 64 * j;
                if (m < G3) { float h = hsrc[m]; p0 += h * fw0[j]; p1 += h * fw1[j]; }
            }
#pragma unroll
            for (int off = 32; off > 0; off >>= 1) {
                p0 += __shfl_down(p0, off);
                p1 += __shfl_down(p1, off);
            }
            if (lane == 0) {
                pres0 += p0 + fcb0; pres1 += p1 + fcb1;
                out[(i - 1) * 2 + 0] = pres0;
                out[(i - 1) * 2 + 1] = pres1;
            }
        }
    }
    __syncthreads();
    if (t >= 320) {   // final step's fc (h_40 in buffer 0)
        int lane = t - 320;
        const float* hsrc = s_hf[0];
        float p0 = 0.0f, p1 = 0.0f;
#pragma unroll
        for (int j = 0; j < 3; ++j) {
            int m = lane + 64 * j;
            if (m < G3) { float h = hsrc[m]; p0 += h * fw0[j]; p1 += h * fw1[j]; }
        }
#pragma unroll
        for (int off = 32; off > 0; off >>= 1) {
            p0 += __shfl_down(p0, off);
            p1 += __shfl_down(p1, off);
        }
        if (lane == 0) {
            pres0 += p0 + fcb0; pres1 += p1 + fcb1;
            out[39 * 2 + 0] = pres0;
            out[39 * 2 + 1] = pres1;
        }
    }
}

extern "C" void kernel_launch(void* const* d_in, const int* in_sizes, int n_in,
                              void* d_out, int out_size, void* d_ws, size_t ws_size,
                              hipStream_t stream) {
    (void)in_sizes; (void)n_in; (void)out_size; (void)ws_size;
    const float* past   = (const float*)d_in[0];
    const float* future = (const float*)d_in[1];
    const float* x      = (const float*)d_in[2];
    const int*   ei     = (const int*)d_in[3];
    const float* ew     = (const float*)d_in[4];
    const float* cpw    = (const float*)d_in[5];
    const float* cpb    = (const float*)d_in[6];
    const float* cfw    = (const float*)d_in[7];
    const float* cfb    = (const float*)d_in[8];
    const float* epWih  = (const float*)d_in[9];
    const float* epWhh  = (const float*)d_in[10];
    const float* epbih  = (const float*)d_in[11];
    const float* epbhh  = (const float*)d_in[12];
    const float* efWih  = (const float*)d_in[13];
    const float* efWhh  = (const float*)d_in[14];
    const float* efbih  = (const float*)d_in[15];
    const float* efbhh  = (const float*)d_in[16];
    const float* dWih   = (const float*)d_in[17];
    const float* dWhh   = (const float*)d_in[18];
    const float* dbih   = (const float*)d_in[19];
    const float* dbhh   = (const float*)d_in[20];
    const float* fcw    = (const float*)d_in[21];
    const float* fcb    = (const float*)d_in[22];
    const float* g1w    = (const float*)d_in[23];
    const float* g1b    = (const float*)d_in[24];
    const float* g2w    = (const float*)d_in[25];
    const float* g2b    = (const float*)d_in[26];

    char* ws = (char*)d_ws;
    int*      mark1 = (int*)(ws + OFF_MARK1);
    int*      mark2 = (int*)(ws + OFF_MARK2);
    unsigned* cnt   = (unsigned*)(ws + OFF_CNT);
    int*      l1r   = (int*)(ws + OFF_L1R);
    float*    l1w   = (float*)(ws + OFF_L1W);
    int*      s1g   = (int*)(ws + OFF_S1G);
    int*      e2r   = (int*)(ws + OFF_E2R);
    int*      e2s   = (int*)(ws + OFF_E2S);
    float*    e2w   = (float*)(ws + OFF_E2W);
    int*      s2    = (int*)(ws + OFF_S2);
    float*    deg2  = (float*)(ws + OFF_DEG2);
    float*    state = (float*)(ws + OFF_STATE);
    float*    x1    = (float*)(ws + OFF_X1);
    float*    tpsf  = (float*)(ws + OFF_TPSF);
    _Float16* whh16 = (_Float16*)(ws + OFF_WHH16);
    float*    gi0p  = (float*)(ws + OFF_GI0P);
    float*    giP   = (float*)(ws + OFF_GIP);
    float*    giF   = (float*)(ws + OFF_GIF);
    float*    dwh4  = (float*)(ws + OFF_DWH4);

    hipMemsetAsync(ws, 0, 524352, stream);  // mark1 | mark2 | cnt
    k_edges1<<<E1B + PREPB, 256, 0, stream>>>(
        ei, ew, mark1, mark2, cnt, l1r, l1w, s1g, e2r, e2s, e2w,
        x1, g1b, s2, deg2,
        past, future, cpw, cpb, cfw, cfb,
        epWih, epbih, efWih, efbih, giP, giF);
    k_edges2<<<SB2 + E1B, 256, 0, stream>>>(ei, ew, mark1, mark2, cnt,
                                            e2r, e2s, e2w, s2, deg2,
                                            dWhh, dWih, whh16, dwh4);
    k_gru<<<DEGB + 2 + 512, 192, 0, stream>>>(x, cpw, cpb, epWih, epWhh, epbih, epbhh,
                                              efWhh, efbhh, giP, giF,
                                              ei, ew, mark2, deg2,
                                              s2, cnt, state, tpsf);
    k_acc1<<<GIB + 128, 256, 0, stream>>>(cnt, e2r, e2s, e2w, mark2, deg2, s1g,
                                          state, g1w, x1,
                                          dWih, dbih, tpsf, gi0p);
    k_dec<<<1, 384, 0, stream>>>(cnt, l1r, l1w, mark1, mark2, deg2, x1, g2w, g2b,
                                 tpsf, past, whh16, dwh4, gi0p, dbih, dbhh, fcw, fcb,
                                 (float*)d_out);
}